// Round 1
// baseline (766.082 us; speedup 1.0000x reference)
//
#include <hip/hip_runtime.h>
#include <cmath>

#define NEGV -1e10f

// ---------- generic projection GEMM: Y[M,768] = X[M,768] @ W[woff..woff+767, :]^T + bias ----------
// SPLIT=1: rows >= 4096 use weight rows 768..1535 (type-1 slice)
template<int SPLIT>
__global__ __launch_bounds__(256)
void proj_gemm(const float* __restrict__ X, const float* __restrict__ W,
               const float* __restrict__ bias, float* __restrict__ Y) {
  __shared__ float Xs[16][68];
  __shared__ float Ws[16][68];
  const int bn = blockIdx.x;            // 12 col tiles
  const int bm = blockIdx.y;            // row tiles
  const int tid = threadIdx.x;
  const int tx = tid & 15, ty = tid >> 4;
  const int woff = (SPLIT && bm >= 64) ? 768 : 0;
  const int row0 = bm * 64, col0 = bn * 64;
  const int lrow = tid >> 2;            // 0..63
  const int lk4  = (tid & 3) * 4;       // 0,4,8,12
  const float* Xp = X + (size_t)(row0 + lrow) * 768 + lk4;
  const float* Wp = W + (size_t)(col0 + woff + lrow) * 768 + lk4;
  float acc[4][4] = {};
  for (int k0 = 0; k0 < 768; k0 += 16) {
    float4 xa = *(const float4*)(Xp + k0);
    float4 wa = *(const float4*)(Wp + k0);
    __syncthreads();
    Xs[lk4+0][lrow] = xa.x; Xs[lk4+1][lrow] = xa.y; Xs[lk4+2][lrow] = xa.z; Xs[lk4+3][lrow] = xa.w;
    Ws[lk4+0][lrow] = wa.x; Ws[lk4+1][lrow] = wa.y; Ws[lk4+2][lrow] = wa.z; Ws[lk4+3][lrow] = wa.w;
    __syncthreads();
    #pragma unroll
    for (int k = 0; k < 16; ++k) {
      float4 a = *(const float4*)&Xs[k][ty*4];
      float4 b = *(const float4*)&Ws[k][tx*4];
      acc[0][0] += a.x*b.x; acc[0][1] += a.x*b.y; acc[0][2] += a.x*b.z; acc[0][3] += a.x*b.w;
      acc[1][0] += a.y*b.x; acc[1][1] += a.y*b.y; acc[1][2] += a.y*b.z; acc[1][3] += a.y*b.w;
      acc[2][0] += a.z*b.x; acc[2][1] += a.z*b.y; acc[2][2] += a.z*b.z; acc[2][3] += a.z*b.w;
      acc[3][0] += a.w*b.x; acc[3][1] += a.w*b.y; acc[3][2] += a.w*b.z; acc[3][3] += a.w*b.w;
    }
  }
  const float b0 = bias[col0+woff+tx*4+0];
  const float b1 = bias[col0+woff+tx*4+1];
  const float b2 = bias[col0+woff+tx*4+2];
  const float b3 = bias[col0+woff+tx*4+3];
  #pragma unroll
  for (int i = 0; i < 4; ++i) {
    float4 o;
    o.x = acc[i][0]+b0; o.y = acc[i][1]+b1; o.z = acc[i][2]+b2; o.w = acc[i][3]+b3;
    *(float4*)(Y + (size_t)(row0+ty*4+i)*768 + col0 + tx*4) = o;
  }
}

// ---------- qe[e,h,b,l,d] = (sum_f q[b,l,h,f] * ra[re,h,d,f]) * pri[re,h]/8 ----------
__global__ __launch_bounds__(256)
void qe_kernel(const float* __restrict__ q, const float* __restrict__ ratt,
               const float* __restrict__ pri, float* __restrict__ qe) {
  const int eh = blockIdx.x, b = blockIdx.y;
  const int e = eh / 12, h = eh - e*12;
  const int re = (e==0) ? 0 : (e==1 ? 4 : 5);
  const float scale = pri[re*12 + h] * 0.125f;
  __shared__ float qs[64][68];
  __shared__ float ras[64][68];
  const int tid = threadIdx.x, tx = tid & 15, ty = tid >> 4;
  for (int r = 0; r < 4; ++r) {
    int idx = r*256 + tid; int row = idx >> 4; int c4 = (idx & 15) * 4;
    *(float4*)&qs[row][c4]  = *(const float4*)(q + ((size_t)(b*64+row))*768 + h*64 + c4);
    *(float4*)&ras[row][c4] = *(const float4*)(ratt + (((size_t)(re*12+h))*64 + row)*64 + c4);
  }
  __syncthreads();
  float acc[4][4] = {};
  for (int f0 = 0; f0 < 64; f0 += 4) {
    float4 bv[4];
    #pragma unroll
    for (int j = 0; j < 4; ++j) bv[j] = *(const float4*)&ras[tx + 16*j][f0];
    #pragma unroll
    for (int i = 0; i < 4; ++i) {
      float4 av = *(const float4*)&qs[ty*4+i][f0];
      #pragma unroll
      for (int j = 0; j < 4; ++j)
        acc[i][j] += av.x*bv[j].x + av.y*bv[j].y + av.z*bv[j].z + av.w*bv[j].w;
    }
  }
  #pragma unroll
  for (int i = 0; i < 4; ++i)
    #pragma unroll
    for (int j = 0; j < 4; ++j)
      qe[(((size_t)(e*12+h))*4096 + b*64 + ty*4+i)*64 + tx + 16*j] = acc[i][j] * scale;
}

// ---------- mask closure: 64-bit bitmask algebra per batch ----------
__global__ __launch_bounds__(256)
void mask_kernel(const int* __restrict__ ids, const float* __restrict__ pre,
                 const float* __restrict__ back, const float* __restrict__ click,
                 unsigned char* __restrict__ mout) {
  const int b = blockIdx.x, tid = threadIdx.x;
  __shared__ float pm[64][68], bmm[64][68], cm[64][68];
  __shared__ unsigned long long sbits[64];
  __shared__ unsigned long long colbits[384];
  __shared__ int sid[64];
  __shared__ unsigned char srep[64];
  for (int r = 0; r < 4; ++r) {
    int idx = r*256 + tid; int row = idx >> 4; int c4 = (idx & 15) * 4;
    *(float4*)&pm[row][c4]  = *(const float4*)(pre   + (size_t)b*4096 + row*64 + c4);
    *(float4*)&bmm[row][c4] = *(const float4*)(back  + (size_t)b*4096 + row*64 + c4);
    *(float4*)&cm[row][c4]  = *(const float4*)(click + (size_t)b*4096 + row*64 + c4);
  }
  if (tid < 64) sid[tid] = ids[b*64 + tid];
  __syncthreads();
  if (tid < 64) {
    int myid = sid[tid];
    unsigned long long bits = 0ull; int rep = 0;
    for (int l = 0; l < 64; ++l) {
      bool eq = (sid[l] == myid);
      bits |= ((unsigned long long)eq) << l;
      rep |= (eq && (l < tid)) ? 1 : 0;
    }
    sbits[tid] = bits; srep[tid] = (unsigned char)rep;
  }
  for (int j = tid; j < 384; j += 256) {
    int t = j / 3, e = j - t*3;
    unsigned long long cb = 0ull;
    if (e == 0) {
      if (t >= 64) { int tt = t - 64; for (int l = 0; l < 64; ++l) cb |= ((unsigned long long)(cm[l][tt] > 0.0f)) << l; }
    } else if (e == 1) {
      if (t < 64) { for (int l = 0; l < 64; ++l) cb |= ((unsigned long long)(bmm[l][t] > 0.0f)) << l; }
    } else {
      if (t < 64) { for (int l = 0; l < 64; ++l) cb |= ((unsigned long long)(pm[l][t] > 0.0f)) << l; }
    }
    colbits[j] = cb;
  }
  __syncthreads();
  // same[i,i]==1 => (sbits[i] & colbits[j]) already includes base mask | add
  for (int r = 0; r < 96; ++r) {
    int idx = r*256 + tid;
    int i = idx / 384, j = idx - i*384;
    unsigned char mv = (((sbits[i] & colbits[j]) != 0ull) && !srep[i]) ? 1 : 0;
    mout[(size_t)(b*64 + i)*384 + j] = mv;
  }
}

// ---------- scores: A[h,b,l,t*3+e] = qe[e,h,b,l,:] . k4[h,b,t,:] ----------
#define QE_OFF 4360   // 64*68 + 8 -> per-e bank offset of 8
__global__ __launch_bounds__(256)
void scores_kernel(const float* __restrict__ qe, const float* __restrict__ k,
                   float* __restrict__ A) {
  const int h = blockIdx.x, b = blockIdx.y;
  __shared__ float sq[2*QE_OFF + 64*68];
  __shared__ float ks[64][68];
  const int tid = threadIdx.x, tx = tid & 15, ty = tid >> 4;
  for (int r = 0; r < 12; ++r) {
    int idx = r*256 + tid;          // float4 index over 3*1024
    int e = idx >> 10;
    int li = (idx & 1023) >> 4;
    int d4 = (idx & 15) * 4;
    *(float4*)&sq[e*QE_OFF + li*68 + d4] =
      *(const float4*)(qe + (((size_t)(e*12+h))*4096 + b*64 + li)*64 + d4);
  }
  float* Ab = A + ((size_t)(h*64+b))*64*384;
  for (int s = 0; s < 2; ++s) {
    __syncthreads();
    for (int r = 0; r < 4; ++r) {
      int idx = r*256 + tid; int t = idx >> 4; int d4 = (idx & 15) * 4;
      *(float4*)&ks[t][d4] =
        *(const float4*)(k + ((size_t)(s*4096 + b*64 + t))*768 + h*64 + d4);
    }
    __syncthreads();
    float acc[4][4][3] = {};
    for (int d0 = 0; d0 < 64; d0 += 4) {
      float4 bv[4];
      #pragma unroll
      for (int tb = 0; tb < 4; ++tb) bv[tb] = *(const float4*)&ks[tx + 16*tb][d0];
      #pragma unroll
      for (int e = 0; e < 3; ++e)
        #pragma unroll
        for (int i = 0; i < 4; ++i) {
          float4 av = *(const float4*)&sq[e*QE_OFF + (ty*4+i)*68 + d0];
          #pragma unroll
          for (int tb = 0; tb < 4; ++tb)
            acc[i][tb][e] += av.x*bv[tb].x + av.y*bv[tb].y + av.z*bv[tb].z + av.w*bv[tb].w;
        }
    }
    #pragma unroll
    for (int i = 0; i < 4; ++i) {
      int l = ty*4 + i;
      #pragma unroll
      for (int tb = 0; tb < 4; ++tb) {
        int t = tx + 16*tb;
        float* p = Ab + (size_t)l*384 + (s*64 + t)*3;
        p[0] = acc[i][tb][0]; p[1] = acc[i][tb][1]; p[2] = acc[i][tb][2];
      }
    }
  }
}

// ---------- masked softmax over 384, in-place, one wave per row ----------
__global__ __launch_bounds__(256)
void softmax_kernel(float* __restrict__ A, const unsigned char* __restrict__ msk) {
  const int row  = blockIdx.x*4 + (threadIdx.x >> 6);   // (h*64+b)*64 + l
  const int lane = threadIdx.x & 63;
  const int hb = row >> 6;
  const int bl = (hb & 63)*64 + (row & 63);
  float* Ar = A + (size_t)row*384;
  const unsigned char* mr = msk + (size_t)bl*384;
  float s[6]; unsigned char m[6];
  float mx = -INFINITY;
  #pragma unroll
  for (int c = 0; c < 6; ++c) {
    int j = lane + 64*c;
    m[c] = mr[j];
    float a = Ar[j];
    s[c] = m[c] ? a : NEGV;
    mx = fmaxf(mx, s[c]);
  }
  #pragma unroll
  for (int off = 1; off < 64; off <<= 1) mx = fmaxf(mx, __shfl_xor(mx, off, 64));
  float sum = 0.0f;
  #pragma unroll
  for (int c = 0; c < 6; ++c) { s[c] = expf(s[c] - mx); sum += s[c]; }
  #pragma unroll
  for (int off = 1; off < 64; off <<= 1) sum += __shfl_xor(sum, off, 64);
  float inv = 1.0f / sum;
  #pragma unroll
  for (int c = 0; c < 6; ++c) {
    int j = lane + 64*c;
    Ar[j] = m[c] ? s[c]*inv : 0.0f;
  }
}

// ---------- PV: u_e = p_e @ v4 ; neigh += u_e @ rm[e,h] ; gelu ----------
__global__ __launch_bounds__(256)
void pv_kernel(const float* __restrict__ p, const float* __restrict__ v,
               const float* __restrict__ rmsg, float* __restrict__ neigh) {
  const int h = blockIdx.x, b = blockIdx.y;
  __shared__ float vs[128][65];
  __shared__ float ps[64][130];
  __shared__ float rs[64][65];
  __shared__ float us[64][65];
  const int tid = threadIdx.x, tx = tid & 15, ty = tid >> 4;
  for (int r = 0; r < 8; ++r) {
    int idx = r*256 + tid; int t = idx >> 4; int d4 = (idx & 15) * 4;
    int s = t >> 6, tt = t & 63;
    *(float4*)&vs[t][d4] =
      *(const float4*)(v + ((size_t)(s*4096 + b*64 + tt))*768 + h*64 + d4);
  }
  float accN[4][4] = {};
  const float* pbase = p + ((size_t)(h*64+b))*64*384;
  for (int e = 0; e < 3; ++e) {
    const int re = (e==0) ? 0 : (e==1 ? 4 : 5);
    __syncthreads();
    for (int r = 0; r < 32; ++r) {
      int idx = r*256 + tid; int l = idx >> 7; int t = idx & 127;
      ps[l][t] = pbase[(size_t)l*384 + t*3 + e];
    }
    for (int r = 0; r < 4; ++r) {
      int idx = r*256 + tid; int d = idx >> 4; int f4 = (idx & 15) * 4;
      *(float4*)&rs[d][f4] = *(const float4*)(rmsg + (((size_t)(re*12+h))*64 + d)*64 + f4);
    }
    __syncthreads();
    float accU[4][4] = {};
    for (int t = 0; t < 128; ++t) {
      float pv0 = ps[ty*4+0][t], pv1 = ps[ty*4+1][t], pv2 = ps[ty*4+2][t], pv3 = ps[ty*4+3][t];
      #pragma unroll
      for (int j = 0; j < 4; ++j) {
        float vv = vs[t][tx + 16*j];
        accU[0][j] += pv0*vv; accU[1][j] += pv1*vv; accU[2][j] += pv2*vv; accU[3][j] += pv3*vv;
      }
    }
    #pragma unroll
    for (int i = 0; i < 4; ++i)
      #pragma unroll
      for (int j = 0; j < 4; ++j)
        us[ty*4+i][tx + 16*j] = accU[i][j];
    __syncthreads();
    for (int d = 0; d < 64; ++d) {
      float u0 = us[ty*4+0][d], u1 = us[ty*4+1][d], u2 = us[ty*4+2][d], u3 = us[ty*4+3][d];
      #pragma unroll
      for (int j = 0; j < 4; ++j) {
        float rv = rs[d][tx + 16*j];
        accN[0][j] += u0*rv; accN[1][j] += u1*rv; accN[2][j] += u2*rv; accN[3][j] += u3*rv;
      }
    }
  }
  #pragma unroll
  for (int i = 0; i < 4; ++i)
    #pragma unroll
    for (int j = 0; j < 4; ++j) {
      float x = accN[i][j];
      float g = 0.5f * x * (1.0f + erff(x * 0.70710678118654752f));
      neigh[((size_t)(b*64 + ty*4+i))*768 + h*64 + tx + 16*j] = g;
    }
}

// ---------- skip-mix + LayerNorm, one wave per row ----------
__global__ __launch_bounds__(256)
void ln_kernel(const float* __restrict__ rt, const float* __restrict__ centers,
               const float* __restrict__ skip, const float* __restrict__ gamma,
               const float* __restrict__ beta, float* __restrict__ out) {
  const int row  = blockIdx.x*4 + (threadIdx.x >> 6);
  const int lane = threadIdx.x & 63;
  const float alpha = 1.0f / (1.0f + expf(-skip[0]));
  const float* rp = rt + (size_t)row*768;
  const float* cp = centers + (size_t)row*768;
  float r[12];
  float sum = 0.0f;
  #pragma unroll
  for (int c = 0; c < 12; ++c) {
    int j = lane + 64*c;
    float x = alpha*rp[j] + (1.0f - alpha)*cp[j];
    r[c] = x; sum += x;
  }
  #pragma unroll
  for (int off = 1; off < 64; off <<= 1) sum += __shfl_xor(sum, off, 64);
  float mean = sum * (1.0f/768.0f);
  float vsum = 0.0f;
  #pragma unroll
  for (int c = 0; c < 12; ++c) { float d = r[c] - mean; vsum += d*d; }
  #pragma unroll
  for (int off = 1; off < 64; off <<= 1) vsum += __shfl_xor(vsum, off, 64);
  float inv = 1.0f / sqrtf(vsum * (1.0f/768.0f) + 1e-5f);
  #pragma unroll
  for (int c = 0; c < 12; ++c) {
    int j = lane + 64*c;
    out[(size_t)row*768 + j] = gamma[j]*(r[c] - mean)*inv + beta[j];
  }
}

extern "C" void kernel_launch(void* const* d_in, const int* in_sizes, int n_in,
                              void* d_out, int out_size, void* d_ws, size_t ws_size,
                              hipStream_t stream) {
  const int*   ids     = (const int*)  d_in[0];
  const float* centers = (const float*)d_in[1];
  const float* allemb  = (const float*)d_in[2];
  const float* pre     = (const float*)d_in[3];
  const float* back    = (const float*)d_in[4];
  const float* click   = (const float*)d_in[5];
  // d_in[6] = blank (all zeros) -> contributes no mask bits, ignored
  const float* Wq = (const float*)d_in[7];
  const float* bq = (const float*)d_in[8];
  const float* Wk = (const float*)d_in[9];
  const float* bk = (const float*)d_in[10];
  const float* Wv = (const float*)d_in[11];
  const float* bv = (const float*)d_in[12];
  const float* Wa = (const float*)d_in[13];
  const float* ba = (const float*)d_in[14];
  const float* pri  = (const float*)d_in[15];
  const float* ratt = (const float*)d_in[16];
  const float* rmsg = (const float*)d_in[17];
  const float* skip = (const float*)d_in[18];
  const float* gam  = (const float*)d_in[19];
  const float* bet  = (const float*)d_in[20];
  float* out = (float*)d_out;

  float* ws   = (float*)d_ws;
  float* q    = ws;                       // 4096*768
  float* kbuf = ws + 3145728;             // 8192*768
  float* vbuf = ws + 9437184;             // 8192*768
  float* qe   = ws + 15728640;            // 3*12*4096*64
  float* A    = ws + 25165824;            // 12*4096*384  (scores, then p in-place)
  unsigned char* msk = (unsigned char*)(ws + 44040192);  // 4096*384 bytes
  float* neigh = ws + 44433408;           // 4096*768
  float* rt = q;                          // reuse q buffer for retype

  proj_gemm<0><<<dim3(12, 64), 256, 0, stream>>>(centers, Wq, bq, q);
  proj_gemm<1><<<dim3(12,128), 256, 0, stream>>>(allemb,  Wk, bk, kbuf);
  proj_gemm<1><<<dim3(12,128), 256, 0, stream>>>(allemb,  Wv, bv, vbuf);
  qe_kernel   <<<dim3(36, 64), 256, 0, stream>>>(q, ratt, pri, qe);
  mask_kernel <<<dim3(64),     256, 0, stream>>>(ids, pre, back, click, msk);
  scores_kernel<<<dim3(12,64), 256, 0, stream>>>(qe, kbuf, A);
  softmax_kernel<<<dim3(12288),256, 0, stream>>>(A, msk);
  pv_kernel   <<<dim3(12, 64), 256, 0, stream>>>(A, vbuf, rmsg, neigh);
  proj_gemm<0><<<dim3(12, 64), 256, 0, stream>>>(neigh, Wa, ba, rt);
  ln_kernel   <<<dim3(1024),   256, 0, stream>>>(rt, centers, skip, gam, bet, out);
}

// Round 3
// 507.031 us; speedup vs baseline: 1.5109x; 1.5109x over previous
//
#include <hip/hip_runtime.h>
#include <cmath>

#define NEGV -1e10f

typedef __bf16 bf16_t;
typedef bf16_t bf16x8 __attribute__((ext_vector_type(8)));
typedef bf16_t bf16x4 __attribute__((ext_vector_type(4)));
typedef float f32x4 __attribute__((ext_vector_type(4)));

typedef const __attribute__((address_space(1))) void* gas1p;
typedef __attribute__((address_space(3))) void* las3p;

// ---------- fp32 -> bf16 (RNE) vectorized cast ----------
__global__ __launch_bounds__(256)
void f2b_kernel(const float* __restrict__ in, bf16_t* __restrict__ out, int n4) {
  int i = blockIdx.x * 256 + threadIdx.x;
  const int stride = gridDim.x * 256;
  for (; i < n4; i += stride) {
    float4 v = *(const float4*)(in + (size_t)i * 4);
    bf16x4 o = { (bf16_t)v.x, (bf16_t)v.y, (bf16_t)v.z, (bf16_t)v.w };
    *(bf16x4*)(out + (size_t)i * 4) = o;
  }
}

// ---------- MFMA projection GEMM: Y[M,768] = Xbf[M,768] @ Wbf[woff+col,:]^T + bias ----------
// 128x128 tile, BK=32, 4 waves, each wave 64x64 (4x4 fragments of 16x16x32 bf16)
template<int SPLIT>
__global__ __launch_bounds__(256)
void proj_mfma(const bf16_t* __restrict__ X, const bf16_t* __restrict__ W,
               const float* __restrict__ bias, float* __restrict__ Y) {
  __shared__ bf16_t As[128 * 32];
  __shared__ bf16_t Bs[128 * 32];
  const int bn = blockIdx.x;            // 6 col tiles
  const int bm = blockIdx.y;            // M/128 row tiles
  const int woff = (SPLIT && bm >= 32) ? 768 : 0;
  const int row0 = bm * 128, col0 = bn * 128;
  const int tid = threadIdx.x;
  const int wave = tid >> 6, lane = tid & 63;
  const int wr = wave >> 1, wc = wave & 1;

  f32x4 acc[4][4] = {};

  const int arow = wr * 64 + (lane & 15);
  const int bcol = wc * 64 + (lane & 15);
  const int koff = (lane >> 4) * 8;

  for (int k0 = 0; k0 < 768; k0 += 32) {
    __syncthreads();
    #pragma unroll
    for (int i = 0; i < 2; ++i) {
      int c = i * 256 + tid;            // 0..511 chunks of 16B
      int r = c >> 2;
      int c8 = (c & 3) * 8;
      __builtin_amdgcn_global_load_lds(
          (gas1p)(X + (size_t)(row0 + r) * 768 + k0 + c8),
          (las3p)(As + c * 8), 16, 0, 0);
      __builtin_amdgcn_global_load_lds(
          (gas1p)(W + (size_t)(col0 + woff + r) * 768 + k0 + c8),
          (las3p)(Bs + c * 8), 16, 0, 0);
    }
    __syncthreads();
    bf16x8 af[4], bfr[4];
    #pragma unroll
    for (int m = 0; m < 4; ++m)
      af[m] = *(const bf16x8*)(As + (arow + m * 16) * 32 + koff);
    #pragma unroll
    for (int n = 0; n < 4; ++n)
      bfr[n] = *(const bf16x8*)(Bs + (bcol + n * 16) * 32 + koff);
    #pragma unroll
    for (int m = 0; m < 4; ++m)
      #pragma unroll
      for (int n = 0; n < 4; ++n)
        acc[m][n] = __builtin_amdgcn_mfma_f32_16x16x32_bf16(af[m], bfr[n], acc[m][n], 0, 0, 0);
  }

  const int ocol0 = col0 + wc * 64 + (lane & 15);
  const int orow0 = row0 + wr * 64 + (lane >> 4) * 4;
  #pragma unroll
  for (int n = 0; n < 4; ++n) {
    const int col = ocol0 + n * 16;
    const float bv = bias[woff + col];
    #pragma unroll
    for (int m = 0; m < 4; ++m) {
      #pragma unroll
      for (int r = 0; r < 4; ++r)
        Y[(size_t)(orow0 + m * 16 + r) * 768 + col] = acc[m][n][r] + bv;
    }
  }
}

// ---------- fp32 projection GEMM (kept for retype; output-sensitive path) ----------
template<int SPLIT>
__global__ __launch_bounds__(256)
void proj_gemm(const float* __restrict__ X, const float* __restrict__ W,
               const float* __restrict__ bias, float* __restrict__ Y) {
  __shared__ float Xs[16][68];
  __shared__ float Ws[16][68];
  const int bn = blockIdx.x;
  const int bm = blockIdx.y;
  const int tid = threadIdx.x;
  const int tx = tid & 15, ty = tid >> 4;
  const int woff = (SPLIT && bm >= 64) ? 768 : 0;
  const int row0 = bm * 64, col0 = bn * 64;
  const int lrow = tid >> 2;
  const int lk4  = (tid & 3) * 4;
  const float* Xp = X + (size_t)(row0 + lrow) * 768 + lk4;
  const float* Wp = W + (size_t)(col0 + woff + lrow) * 768 + lk4;
  float acc[4][4] = {};
  for (int k0 = 0; k0 < 768; k0 += 16) {
    float4 xa = *(const float4*)(Xp + k0);
    float4 wa = *(const float4*)(Wp + k0);
    __syncthreads();
    Xs[lk4+0][lrow] = xa.x; Xs[lk4+1][lrow] = xa.y; Xs[lk4+2][lrow] = xa.z; Xs[lk4+3][lrow] = xa.w;
    Ws[lk4+0][lrow] = wa.x; Ws[lk4+1][lrow] = wa.y; Ws[lk4+2][lrow] = wa.z; Ws[lk4+3][lrow] = wa.w;
    __syncthreads();
    #pragma unroll
    for (int k = 0; k < 16; ++k) {
      float4 a = *(const float4*)&Xs[k][ty*4];
      float4 b = *(const float4*)&Ws[k][tx*4];
      acc[0][0] += a.x*b.x; acc[0][1] += a.x*b.y; acc[0][2] += a.x*b.z; acc[0][3] += a.x*b.w;
      acc[1][0] += a.y*b.x; acc[1][1] += a.y*b.y; acc[1][2] += a.y*b.z; acc[1][3] += a.y*b.w;
      acc[2][0] += a.z*b.x; acc[2][1] += a.z*b.y; acc[2][2] += a.z*b.z; acc[2][3] += a.z*b.w;
      acc[3][0] += a.w*b.x; acc[3][1] += a.w*b.y; acc[3][2] += a.w*b.z; acc[3][3] += a.w*b.w;
    }
  }
  const float b0 = bias[col0+woff+tx*4+0];
  const float b1 = bias[col0+woff+tx*4+1];
  const float b2 = bias[col0+woff+tx*4+2];
  const float b3 = bias[col0+woff+tx*4+3];
  #pragma unroll
  for (int i = 0; i < 4; ++i) {
    float4 o;
    o.x = acc[i][0]+b0; o.y = acc[i][1]+b1; o.z = acc[i][2]+b2; o.w = acc[i][3]+b3;
    *(float4*)(Y + (size_t)(row0+ty*4+i)*768 + col0 + tx*4) = o;
  }
}

// ---------- qe[e,h,b,l,d] = (sum_f q[b,l,h,f] * ra[re,h,d,f]) * pri[re,h]/8 ----------
__global__ __launch_bounds__(256)
void qe_kernel(const float* __restrict__ q, const float* __restrict__ ratt,
               const float* __restrict__ pri, float* __restrict__ qe) {
  const int eh = blockIdx.x, b = blockIdx.y;
  const int e = eh / 12, h = eh - e*12;
  const int re = (e==0) ? 0 : (e==1 ? 4 : 5);
  const float scale = pri[re*12 + h] * 0.125f;
  __shared__ float qs[64][68];
  __shared__ float ras[64][68];
  const int tid = threadIdx.x, tx = tid & 15, ty = tid >> 4;
  for (int r = 0; r < 4; ++r) {
    int idx = r*256 + tid; int row = idx >> 4; int c4 = (idx & 15) * 4;
    *(float4*)&qs[row][c4]  = *(const float4*)(q + ((size_t)(b*64+row))*768 + h*64 + c4);
    *(float4*)&ras[row][c4] = *(const float4*)(ratt + (((size_t)(re*12+h))*64 + row)*64 + c4);
  }
  __syncthreads();
  float acc[4][4] = {};
  for (int f0 = 0; f0 < 64; f0 += 4) {
    float4 bv[4];
    #pragma unroll
    for (int j = 0; j < 4; ++j) bv[j] = *(const float4*)&ras[tx + 16*j][f0];
    #pragma unroll
    for (int i = 0; i < 4; ++i) {
      float4 av = *(const float4*)&qs[ty*4+i][f0];
      #pragma unroll
      for (int j = 0; j < 4; ++j)
        acc[i][j] += av.x*bv[j].x + av.y*bv[j].y + av.z*bv[j].z + av.w*bv[j].w;
    }
  }
  #pragma unroll
  for (int i = 0; i < 4; ++i)
    #pragma unroll
    for (int j = 0; j < 4; ++j)
      qe[(((size_t)(e*12+h))*4096 + b*64 + ty*4+i)*64 + tx + 16*j] = acc[i][j] * scale;
}

// ---------- mask closure: 64-bit bitmask algebra per batch ----------
__global__ __launch_bounds__(256)
void mask_kernel(const int* __restrict__ ids, const float* __restrict__ pre,
                 const float* __restrict__ back, const float* __restrict__ click,
                 unsigned char* __restrict__ mout) {
  const int b = blockIdx.x, tid = threadIdx.x;
  __shared__ float pm[64][68], bmm[64][68], cm[64][68];
  __shared__ unsigned long long sbits[64];
  __shared__ unsigned long long colbits[384];
  __shared__ int sid[64];
  __shared__ unsigned char srep[64];
  for (int r = 0; r < 4; ++r) {
    int idx = r*256 + tid; int row = idx >> 4; int c4 = (idx & 15) * 4;
    *(float4*)&pm[row][c4]  = *(const float4*)(pre   + (size_t)b*4096 + row*64 + c4);
    *(float4*)&bmm[row][c4] = *(const float4*)(back  + (size_t)b*4096 + row*64 + c4);
    *(float4*)&cm[row][c4]  = *(const float4*)(click + (size_t)b*4096 + row*64 + c4);
  }
  if (tid < 64) sid[tid] = ids[b*64 + tid];
  __syncthreads();
  if (tid < 64) {
    int myid = sid[tid];
    unsigned long long bits = 0ull; int rep = 0;
    for (int l = 0; l < 64; ++l) {
      bool eq = (sid[l] == myid);
      bits |= ((unsigned long long)eq) << l;
      rep |= (eq && (l < tid)) ? 1 : 0;
    }
    sbits[tid] = bits; srep[tid] = (unsigned char)rep;
  }
  for (int j = tid; j < 384; j += 256) {
    int t = j / 3, e = j - t*3;
    unsigned long long cb = 0ull;
    if (e == 0) {
      if (t >= 64) { int tt = t - 64; for (int l = 0; l < 64; ++l) cb |= ((unsigned long long)(cm[l][tt] > 0.0f)) << l; }
    } else if (e == 1) {
      if (t < 64) { for (int l = 0; l < 64; ++l) cb |= ((unsigned long long)(bmm[l][t] > 0.0f)) << l; }
    } else {
      if (t < 64) { for (int l = 0; l < 64; ++l) cb |= ((unsigned long long)(pm[l][t] > 0.0f)) << l; }
    }
    colbits[j] = cb;
  }
  __syncthreads();
  for (int r = 0; r < 96; ++r) {
    int idx = r*256 + tid;
    int i = idx / 384, j = idx - i*384;
    unsigned char mv = (((sbits[i] & colbits[j]) != 0ull) && !srep[i]) ? 1 : 0;
    mout[(size_t)(b*64 + i)*384 + j] = mv;
  }
}

// ---------- scores: A[h,b,l,t*3+e] = qe[e,h,b,l,:] . k4[h,b,t,:] ----------
#define QE_OFF 4360
__global__ __launch_bounds__(256)
void scores_kernel(const float* __restrict__ qe, const float* __restrict__ k,
                   float* __restrict__ A) {
  const int h = blockIdx.x, b = blockIdx.y;
  __shared__ float sq[2*QE_OFF + 64*68];
  __shared__ float ks[64][68];
  const int tid = threadIdx.x, tx = tid & 15, ty = tid >> 4;
  for (int r = 0; r < 12; ++r) {
    int idx = r*256 + tid;
    int e = idx >> 10;
    int li = (idx & 1023) >> 4;
    int d4 = (idx & 15) * 4;
    *(float4*)&sq[e*QE_OFF + li*68 + d4] =
      *(const float4*)(qe + (((size_t)(e*12+h))*4096 + b*64 + li)*64 + d4);
  }
  float* Ab = A + ((size_t)(h*64+b))*64*384;
  for (int s = 0; s < 2; ++s) {
    __syncthreads();
    for (int r = 0; r < 4; ++r) {
      int idx = r*256 + tid; int t = idx >> 4; int d4 = (idx & 15) * 4;
      *(float4*)&ks[t][d4] =
        *(const float4*)(k + ((size_t)(s*4096 + b*64 + t))*768 + h*64 + d4);
    }
    __syncthreads();
    float acc[4][4][3] = {};
    for (int d0 = 0; d0 < 64; d0 += 4) {
      float4 bv[4];
      #pragma unroll
      for (int tb = 0; tb < 4; ++tb) bv[tb] = *(const float4*)&ks[tx + 16*tb][d0];
      #pragma unroll
      for (int e = 0; e < 3; ++e)
        #pragma unroll
        for (int i = 0; i < 4; ++i) {
          float4 av = *(const float4*)&sq[e*QE_OFF + (ty*4+i)*68 + d0];
          #pragma unroll
          for (int tb = 0; tb < 4; ++tb)
            acc[i][tb][e] += av.x*bv[tb].x + av.y*bv[tb].y + av.z*bv[tb].z + av.w*bv[tb].w;
        }
    }
    #pragma unroll
    for (int i = 0; i < 4; ++i) {
      int l = ty*4 + i;
      #pragma unroll
      for (int tb = 0; tb < 4; ++tb) {
        int t = tx + 16*tb;
        float* p = Ab + (size_t)l*384 + (s*64 + t)*3;
        p[0] = acc[i][tb][0]; p[1] = acc[i][tb][1]; p[2] = acc[i][tb][2];
      }
    }
  }
}

// ---------- masked softmax over 384, in-place, one wave per row ----------
__global__ __launch_bounds__(256)
void softmax_kernel(float* __restrict__ A, const unsigned char* __restrict__ msk) {
  const int row  = blockIdx.x*4 + (threadIdx.x >> 6);
  const int lane = threadIdx.x & 63;
  const int hb = row >> 6;
  const int bl = (hb & 63)*64 + (row & 63);
  float* Ar = A + (size_t)row*384;
  const unsigned char* mr = msk + (size_t)bl*384;
  float s[6]; unsigned char m[6];
  float mx = -INFINITY;
  #pragma unroll
  for (int c = 0; c < 6; ++c) {
    int j = lane + 64*c;
    m[c] = mr[j];
    float a = Ar[j];
    s[c] = m[c] ? a : NEGV;
    mx = fmaxf(mx, s[c]);
  }
  #pragma unroll
  for (int off = 1; off < 64; off <<= 1) mx = fmaxf(mx, __shfl_xor(mx, off, 64));
  float sum = 0.0f;
  #pragma unroll
  for (int c = 0; c < 6; ++c) { s[c] = expf(s[c] - mx); sum += s[c]; }
  #pragma unroll
  for (int off = 1; off < 64; off <<= 1) sum += __shfl_xor(sum, off, 64);
  float inv = 1.0f / sum;
  #pragma unroll
  for (int c = 0; c < 6; ++c) {
    int j = lane + 64*c;
    Ar[j] = m[c] ? s[c]*inv : 0.0f;
  }
}

// ---------- PV: u_e = p_e @ v4 ; neigh += u_e @ rm[e,h] ; gelu ----------
__global__ __launch_bounds__(256)
void pv_kernel(const float* __restrict__ p, const float* __restrict__ v,
               const float* __restrict__ rmsg, float* __restrict__ neigh) {
  const int h = blockIdx.x, b = blockIdx.y;
  __shared__ float vs[128][65];
  __shared__ float ps[64][130];
  __shared__ float rs[64][65];
  __shared__ float us[64][65];
  const int tid = threadIdx.x, tx = tid & 15, ty = tid >> 4;
  for (int r = 0; r < 8; ++r) {
    int idx = r*256 + tid; int t = idx >> 4; int d4 = (idx & 15) * 4;
    int s = t >> 6, tt = t & 63;
    *(float4*)&vs[t][d4] =
      *(const float4*)(v + ((size_t)(s*4096 + b*64 + tt))*768 + h*64 + d4);
  }
  float accN[4][4] = {};
  const float* pbase = p + ((size_t)(h*64+b))*64*384;
  for (int e = 0; e < 3; ++e) {
    const int re = (e==0) ? 0 : (e==1 ? 4 : 5);
    __syncthreads();
    for (int r = 0; r < 32; ++r) {
      int idx = r*256 + tid; int l = idx >> 7; int t = idx & 127;
      ps[l][t] = pbase[(size_t)l*384 + t*3 + e];
    }
    for (int r = 0; r < 4; ++r) {
      int idx = r*256 + tid; int d = idx >> 4; int f4 = (idx & 15) * 4;
      *(float4*)&rs[d][f4] = *(const float4*)(rmsg + (((size_t)(re*12+h))*64 + d)*64 + f4);
    }
    __syncthreads();
    float accU[4][4] = {};
    for (int t = 0; t < 128; ++t) {
      float pv0 = ps[ty*4+0][t], pv1 = ps[ty*4+1][t], pv2 = ps[ty*4+2][t], pv3 = ps[ty*4+3][t];
      #pragma unroll
      for (int j = 0; j < 4; ++j) {
        float vv = vs[t][tx + 16*j];
        accU[0][j] += pv0*vv; accU[1][j] += pv1*vv; accU[2][j] += pv2*vv; accU[3][j] += pv3*vv;
      }
    }
    #pragma unroll
    for (int i = 0; i < 4; ++i)
      #pragma unroll
      for (int j = 0; j < 4; ++j)
        us[ty*4+i][tx + 16*j] = accU[i][j];
    __syncthreads();
    for (int d = 0; d < 64; ++d) {
      float u0 = us[ty*4+0][d], u1 = us[ty*4+1][d], u2 = us[ty*4+2][d], u3 = us[ty*4+3][d];
      #pragma unroll
      for (int j = 0; j < 4; ++j) {
        float rv = rs[d][tx + 16*j];
        accN[0][j] += u0*rv; accN[1][j] += u1*rv; accN[2][j] += u2*rv; accN[3][j] += u3*rv;
      }
    }
  }
  #pragma unroll
  for (int i = 0; i < 4; ++i)
    #pragma unroll
    for (int j = 0; j < 4; ++j) {
      float x = accN[i][j];
      float g = 0.5f * x * (1.0f + erff(x * 0.70710678118654752f));
      neigh[((size_t)(b*64 + ty*4+i))*768 + h*64 + tx + 16*j] = g;
    }
}

// ---------- skip-mix + LayerNorm, one wave per row ----------
__global__ __launch_bounds__(256)
void ln_kernel(const float* __restrict__ rt, const float* __restrict__ centers,
               const float* __restrict__ skip, const float* __restrict__ gamma,
               const float* __restrict__ beta, float* __restrict__ out) {
  const int row  = blockIdx.x*4 + (threadIdx.x >> 6);
  const int lane = threadIdx.x & 63;
  const float alpha = 1.0f / (1.0f + expf(-skip[0]));
  const float* rp = rt + (size_t)row*768;
  const float* cp = centers + (size_t)row*768;
  float r[12];
  float sum = 0.0f;
  #pragma unroll
  for (int c = 0; c < 12; ++c) {
    int j = lane + 64*c;
    float x = alpha*rp[j] + (1.0f - alpha)*cp[j];
    r[c] = x; sum += x;
  }
  #pragma unroll
  for (int off = 1; off < 64; off <<= 1) sum += __shfl_xor(sum, off, 64);
  float mean = sum * (1.0f/768.0f);
  float vsum = 0.0f;
  #pragma unroll
  for (int c = 0; c < 12; ++c) { float d = r[c] - mean; vsum += d*d; }
  #pragma unroll
  for (int off = 1; off < 64; off <<= 1) vsum += __shfl_xor(vsum, off, 64);
  float inv = 1.0f / sqrtf(vsum * (1.0f/768.0f) + 1e-5f);
  #pragma unroll
  for (int c = 0; c < 12; ++c) {
    int j = lane + 64*c;
    out[(size_t)row*768 + j] = gamma[j]*(r[c] - mean)*inv + beta[j];
  }
}

extern "C" void kernel_launch(void* const* d_in, const int* in_sizes, int n_in,
                              void* d_out, int out_size, void* d_ws, size_t ws_size,
                              hipStream_t stream) {
  const int*   ids     = (const int*)  d_in[0];
  const float* centers = (const float*)d_in[1];
  const float* allemb  = (const float*)d_in[2];
  const float* pre     = (const float*)d_in[3];
  const float* back    = (const float*)d_in[4];
  const float* click   = (const float*)d_in[5];
  const float* Wq = (const float*)d_in[7];
  const float* bq = (const float*)d_in[8];
  const float* Wk = (const float*)d_in[9];
  const float* bk = (const float*)d_in[10];
  const float* Wv = (const float*)d_in[11];
  const float* bv = (const float*)d_in[12];
  const float* Wa = (const float*)d_in[13];
  const float* ba = (const float*)d_in[14];
  const float* pri  = (const float*)d_in[15];
  const float* ratt = (const float*)d_in[16];
  const float* rmsg = (const float*)d_in[17];
  const float* skip = (const float*)d_in[18];
  const float* gam  = (const float*)d_in[19];
  const float* bet  = (const float*)d_in[20];
  float* out = (float*)d_out;

  float* ws   = (float*)d_ws;
  float* q    = ws;                       // 4096*768
  float* kbuf = ws + 3145728;             // 8192*768
  float* vbuf = ws + 9437184;             // 8192*768
  float* qe   = ws + 15728640;            // 3*12*4096*64
  float* A    = ws + 25165824;            // 12*4096*384  (scores, then p in-place)
  unsigned char* msk = (unsigned char*)(ws + 44040192);  // 4096*384 bytes
  float* neigh = ws + 44433408;           // 4096*768
  float* rt = q;                          // reuse q buffer for retype

  // bf16 staging buffers live inside the A region (dead until scores_kernel)
  bf16_t* cen_bf = (bf16_t*)A;            // 3145728
  bf16_t* all_bf = cen_bf + 3145728;      // 6291456
  bf16_t* Wq_bf  = all_bf + 6291456;      // 1179648
  bf16_t* Wk_bf  = Wq_bf + 1179648;       // 1179648
  bf16_t* Wv_bf  = Wk_bf + 1179648;       // 1179648

  f2b_kernel<<<dim3(2048), 256, 0, stream>>>(centers, cen_bf, 786432);
  f2b_kernel<<<dim3(2048), 256, 0, stream>>>(allemb,  all_bf, 1572864);
  f2b_kernel<<<dim3(1152), 256, 0, stream>>>(Wq, Wq_bf, 294912);
  f2b_kernel<<<dim3(1152), 256, 0, stream>>>(Wk, Wk_bf, 294912);
  f2b_kernel<<<dim3(1152), 256, 0, stream>>>(Wv, Wv_bf, 294912);

  proj_mfma<0><<<dim3(6, 32), 256, 0, stream>>>(cen_bf, Wq_bf, bq, q);
  proj_mfma<1><<<dim3(6, 64), 256, 0, stream>>>(all_bf, Wk_bf, bk, kbuf);
  proj_mfma<1><<<dim3(6, 64), 256, 0, stream>>>(all_bf, Wv_bf, bv, vbuf);

  qe_kernel   <<<dim3(36, 64), 256, 0, stream>>>(q, ratt, pri, qe);
  mask_kernel <<<dim3(64),     256, 0, stream>>>(ids, pre, back, click, msk);
  scores_kernel<<<dim3(12,64), 256, 0, stream>>>(qe, kbuf, A);
  softmax_kernel<<<dim3(12288),256, 0, stream>>>(A, msk);
  pv_kernel   <<<dim3(12, 64), 256, 0, stream>>>(A, vbuf, rmsg, neigh);
  proj_gemm<0><<<dim3(12, 64), 256, 0, stream>>>(neigh, Wa, ba, rt);
  ln_kernel   <<<dim3(1024),   256, 0, stream>>>(rt, centers, skip, gam, bet, out);
}

// Round 4
// 420.508 us; speedup vs baseline: 1.8218x; 1.2058x over previous
//
#include <hip/hip_runtime.h>
#include <cmath>

#define NEGV -1e10f

typedef __bf16 bf16_t;
typedef bf16_t bf16x8 __attribute__((ext_vector_type(8)));
typedef bf16_t bf16x4 __attribute__((ext_vector_type(4)));
typedef float f32x4 __attribute__((ext_vector_type(4)));

typedef const __attribute__((address_space(1))) void* gas1p;
typedef __attribute__((address_space(3))) void* las3p;

// ---------- fp32 -> bf16 (RNE) vectorized cast ----------
__global__ __launch_bounds__(256)
void f2b_kernel(const float* __restrict__ in, bf16_t* __restrict__ out, int n4) {
  int i = blockIdx.x * 256 + threadIdx.x;
  const int stride = gridDim.x * 256;
  for (; i < n4; i += stride) {
    float4 v = *(const float4*)(in + (size_t)i * 4);
    bf16x4 o = { (bf16_t)v.x, (bf16_t)v.y, (bf16_t)v.z, (bf16_t)v.w };
    *(bf16x4*)(out + (size_t)i * 4) = o;
  }
}

// ---------- fold ra (and pri/sqrt_dk) into Wq: Wqp[(e,h,d)][c] = scale*sum_f ra[d,f]*Wq[h*64+f][c] ----------
__global__ __launch_bounds__(256)
void fold_q(const bf16_t* __restrict__ Wqb, const float* __restrict__ bq,
            const float* __restrict__ ratt, const float* __restrict__ pri,
            bf16_t* __restrict__ Wqp, float* __restrict__ bqp) {
  const int eh = blockIdx.x; const int e = eh / 12, h = eh - e*12;
  const int re = (e==0) ? 0 : (e==1 ? 4 : 5);
  const float scale = pri[re*12 + h] * 0.125f;
  const int c0 = blockIdx.y * 256;
  __shared__ float raS[64][64];
  __shared__ bf16_t WS[64][256];
  const int tid = threadIdx.x;
  for (int i = 0; i < 16; ++i) {
    int idx = i*256 + tid;
    raS[idx>>6][idx&63] = ratt[((size_t)(re*12+h)*64 + (idx>>6))*64 + (idx&63)];
  }
  for (int i = 0; i < 8; ++i) {
    int idx = i*256 + tid; int f = idx>>5, c8 = (idx&31)*8;
    *(bf16x8*)&WS[f][c8] = *(const bf16x8*)(Wqb + (size_t)(h*64+f)*768 + c0 + c8);
  }
  __syncthreads();
  const int c = tid;
  for (int d = 0; d < 64; ++d) {
    float acc = 0.0f;
    for (int f = 0; f < 64; ++f) acc += raS[d][f] * (float)WS[f][c];
    Wqp[((size_t)(e*12+h)*64 + d)*768 + c0 + c] = (bf16_t)(scale * acc);
  }
  if (blockIdx.y == 0 && tid < 64) {
    float acc = 0.0f;
    for (int f = 0; f < 64; ++f) acc += raS[tid][f] * bq[h*64+f];
    bqp[(e*12+h)*64 + tid] = scale * acc;
  }
}

// ---------- fold rm into Wv: Wvp[s][(e,h,d)][c] = sum_f rm[f,d]*Wv[s*768+h*64+f][c] ----------
__global__ __launch_bounds__(256)
void fold_v(const bf16_t* __restrict__ Wvb, const float* __restrict__ bv,
            const float* __restrict__ rmsg, bf16_t* __restrict__ Wvp, float* __restrict__ bvp) {
  const int s = blockIdx.x / 36;
  const int eh = blockIdx.x - s*36; const int e = eh / 12, h = eh - e*12;
  const int re = (e==0) ? 0 : (e==1 ? 4 : 5);
  const int c0 = blockIdx.y * 256;
  __shared__ float rmS[64][64];   // [f][d]
  __shared__ bf16_t WS[64][256];
  const int tid = threadIdx.x;
  for (int i = 0; i < 16; ++i) {
    int idx = i*256 + tid;
    rmS[idx>>6][idx&63] = rmsg[((size_t)(re*12+h)*64 + (idx>>6))*64 + (idx&63)];
  }
  for (int i = 0; i < 8; ++i) {
    int idx = i*256 + tid; int f = idx>>5, c8 = (idx&31)*8;
    *(bf16x8*)&WS[f][c8] = *(const bf16x8*)(Wvb + (size_t)(s*768 + h*64 + f)*768 + c0 + c8);
  }
  __syncthreads();
  const int c = tid;
  for (int d = 0; d < 64; ++d) {
    float acc = 0.0f;
    for (int f = 0; f < 64; ++f) acc += rmS[f][d] * (float)WS[f][c];
    Wvp[(size_t)s*2304*768 + ((size_t)(e*12+h)*64 + d)*768 + c0 + c] = (bf16_t)acc;
  }
  if (blockIdx.y == 0 && tid < 64) {
    float acc = 0.0f;
    for (int f = 0; f < 64; ++f) acc += rmS[f][tid] * bv[s*768 + h*64 + f];
    bvp[s*2304 + (e*12+h)*64 + tid] = acc;
  }
}

// ---------- MFMA GEMM, bf16 out: Y[M,NCOLS] = X[M,768] @ W[s-slice][768]^T + bias ----------
template<int NCOLS, int WSTRIDE, int BSTRIDE, int MHALF>
__global__ __launch_bounds__(256)
void proj_mfmaB(const bf16_t* __restrict__ X, const bf16_t* __restrict__ W,
                const float* __restrict__ bias, bf16_t* __restrict__ Y) {
  __shared__ bf16_t As[128 * 32];
  __shared__ bf16_t Bs[128 * 32];
  const int bn = blockIdx.x, bm = blockIdx.y;
  const int s = (MHALF && bm >= MHALF) ? 1 : 0;
  const int row0 = bm * 128, col0 = bn * 128;
  const int tid = threadIdx.x, wave = tid >> 6, lane = tid & 63;
  const int wr = wave >> 1, wc = wave & 1;
  f32x4 acc[4][4] = {};
  const int arow = wr * 64 + (lane & 15);
  const int bcol = wc * 64 + (lane & 15);
  const int koff = (lane >> 4) * 8;
  const bf16_t* Wb = W + (size_t)s * WSTRIDE;
  for (int k0 = 0; k0 < 768; k0 += 32) {
    __syncthreads();
    #pragma unroll
    for (int i = 0; i < 2; ++i) {
      int c = i * 256 + tid; int r = c >> 2; int c8 = (c & 3) * 8;
      __builtin_amdgcn_global_load_lds((gas1p)(X  + (size_t)(row0 + r) * 768 + k0 + c8),
                                       (las3p)(As + c * 8), 16, 0, 0);
      __builtin_amdgcn_global_load_lds((gas1p)(Wb + (size_t)(col0 + r) * 768 + k0 + c8),
                                       (las3p)(Bs + c * 8), 16, 0, 0);
    }
    __syncthreads();
    bf16x8 af[4], bfr[4];
    #pragma unroll
    for (int m = 0; m < 4; ++m) af[m]  = *(const bf16x8*)(As + (arow + m * 16) * 32 + koff);
    #pragma unroll
    for (int n = 0; n < 4; ++n) bfr[n] = *(const bf16x8*)(Bs + (bcol + n * 16) * 32 + koff);
    #pragma unroll
    for (int m = 0; m < 4; ++m)
      #pragma unroll
      for (int n = 0; n < 4; ++n)
        acc[m][n] = __builtin_amdgcn_mfma_f32_16x16x32_bf16(af[m], bfr[n], acc[m][n], 0, 0, 0);
  }
  const int ocol0 = col0 + wc * 64 + (lane & 15);
  const int orow0 = row0 + wr * 64 + (lane >> 4) * 4;
  #pragma unroll
  for (int n = 0; n < 4; ++n) {
    const int col = ocol0 + n * 16;
    const float bvl = bias[s * BSTRIDE + col];
    #pragma unroll
    for (int m = 0; m < 4; ++m)
      #pragma unroll
      for (int r = 0; r < 4; ++r)
        Y[(size_t)(orow0 + m * 16 + r) * NCOLS + col] = (bf16_t)(acc[m][n][r] + bvl);
  }
}

// ---------- msg projection with TRANSPOSED output: YT[(e,h,d)][token] ----------
__global__ __launch_bounds__(256)
void msg_projT(const bf16_t* __restrict__ X, const bf16_t* __restrict__ W,
               const float* __restrict__ bias, bf16_t* __restrict__ YT) {
  __shared__ bf16_t As[128 * 32];
  __shared__ bf16_t Bs[128 * 32];
  __shared__ char tl[128 * 256];   // [col][token] bf16, byte=(c*256+t*2)^((c&7)<<4)
  const int bn = blockIdx.x, bm = blockIdx.y;
  const int s = (bm >= 32) ? 1 : 0;
  const int row0 = bm * 128, col0 = bn * 128;
  const int tid = threadIdx.x, wave = tid >> 6, lane = tid & 63;
  const int wr = wave >> 1, wc = wave & 1;
  f32x4 acc[4][4] = {};
  const int arow = wr * 64 + (lane & 15);
  const int bcol = wc * 64 + (lane & 15);
  const int koff = (lane >> 4) * 8;
  const bf16_t* Wb = W + (size_t)s * 2304 * 768;
  for (int k0 = 0; k0 < 768; k0 += 32) {
    __syncthreads();
    #pragma unroll
    for (int i = 0; i < 2; ++i) {
      int c = i * 256 + tid; int r = c >> 2; int c8 = (c & 3) * 8;
      __builtin_amdgcn_global_load_lds((gas1p)(X  + (size_t)(row0 + r) * 768 + k0 + c8),
                                       (las3p)(As + c * 8), 16, 0, 0);
      __builtin_amdgcn_global_load_lds((gas1p)(Wb + (size_t)(col0 + r) * 768 + k0 + c8),
                                       (las3p)(Bs + c * 8), 16, 0, 0);
    }
    __syncthreads();
    bf16x8 af[4], bfr[4];
    #pragma unroll
    for (int m = 0; m < 4; ++m) af[m]  = *(const bf16x8*)(As + (arow + m * 16) * 32 + koff);
    #pragma unroll
    for (int n = 0; n < 4; ++n) bfr[n] = *(const bf16x8*)(Bs + (bcol + n * 16) * 32 + koff);
    #pragma unroll
    for (int m = 0; m < 4; ++m)
      #pragma unroll
      for (int n = 0; n < 4; ++n)
        acc[m][n] = __builtin_amdgcn_mfma_f32_16x16x32_bf16(af[m], bfr[n], acc[m][n], 0, 0, 0);
  }
  __syncthreads();
  #pragma unroll
  for (int n = 0; n < 4; ++n) {
    const int cl = wc * 64 + n * 16 + (lane & 15);
    const float bvl = bias[s * 2304 + col0 + cl];
    #pragma unroll
    for (int m = 0; m < 4; ++m)
      #pragma unroll
      for (int r = 0; r < 4; ++r) {
        const int rl = wr * 64 + m * 16 + (lane >> 4) * 4 + r;
        *(bf16_t*)(tl + ((cl * 256 + rl * 2) ^ ((cl & 7) << 4))) = (bf16_t)(acc[m][n][r] + bvl);
      }
  }
  __syncthreads();
  for (int i = 0; i < 8; ++i) {
    int idx = i * 256 + tid; int c = idx >> 4; int t0 = (idx & 15) * 8;
    bf16x8 v = *(const bf16x8*)(tl + ((c * 256 + t0 * 2) ^ ((c & 7) << 4)));
    *(bf16x8*)(YT + (size_t)(col0 + c) * 8192 + row0 + t0) = v;
  }
}

// ---------- mask closure -> packed 64-bit rowmasks: msk64[b*64+l][w], te' = w*64+bit, te' = e*128+t ----------
__global__ __launch_bounds__(256)
void mask_kernel(const int* __restrict__ ids, const float* __restrict__ pre,
                 const float* __restrict__ back, const float* __restrict__ click,
                 unsigned long long* __restrict__ msk64) {
  const int b = blockIdx.x, tid = threadIdx.x;
  __shared__ float pm[64][68], bmm[64][68], cm[64][68];
  __shared__ unsigned long long sbits[64];
  __shared__ unsigned long long colbits[384];
  __shared__ int sid[64];
  __shared__ unsigned char srep[64];
  for (int r = 0; r < 4; ++r) {
    int idx = r*256 + tid; int row = idx >> 4; int c4 = (idx & 15) * 4;
    *(float4*)&pm[row][c4]  = *(const float4*)(pre   + (size_t)b*4096 + row*64 + c4);
    *(float4*)&bmm[row][c4] = *(const float4*)(back  + (size_t)b*4096 + row*64 + c4);
    *(float4*)&cm[row][c4]  = *(const float4*)(click + (size_t)b*4096 + row*64 + c4);
  }
  if (tid < 64) sid[tid] = ids[b*64 + tid];
  __syncthreads();
  if (tid < 64) {
    int myid = sid[tid];
    unsigned long long bits = 0ull; int rep = 0;
    for (int l = 0; l < 64; ++l) {
      bool eq = (sid[l] == myid);
      bits |= ((unsigned long long)eq) << l;
      rep |= (eq && (l < tid)) ? 1 : 0;
    }
    sbits[tid] = bits; srep[tid] = (unsigned char)rep;
  }
  for (int j = tid; j < 384; j += 256) {
    int e = j >> 7, t = j & 127;
    unsigned long long cb = 0ull;
    if (e == 0) {
      if (t >= 64) { int tt = t - 64; for (int l = 0; l < 64; ++l) cb |= ((unsigned long long)(cm[l][tt] > 0.0f)) << l; }
    } else if (e == 1) {
      if (t < 64) { for (int l = 0; l < 64; ++l) cb |= ((unsigned long long)(bmm[l][t] > 0.0f)) << l; }
    } else {
      if (t < 64) { for (int l = 0; l < 64; ++l) cb |= ((unsigned long long)(pm[l][t] > 0.0f)) << l; }
    }
    colbits[j] = cb;
  }
  __syncthreads();
  for (int idx = tid; idx < 384; idx += 256) {
    int l = idx / 6, w = idx - l*6;
    unsigned long long r = 0ull;
    if (!srep[l]) {
      unsigned long long sb = sbits[l];
      const int base = w*64;
      for (int jj = 0; jj < 64; ++jj)
        r |= (unsigned long long)((sb & colbits[base + jj]) != 0ull) << jj;
    }
    msk64[((size_t)(b*64) + l)*6 + w] = r;
  }
}

// ---------- fused scores + masked softmax -> P bf16 [hb*64+l][384] (te' = e*128 + t) ----------
__global__ __launch_bounds__(256)
void scores_fused(const bf16_t* __restrict__ qeb, const bf16_t* __restrict__ kb,
                  const unsigned long long* __restrict__ msk64, bf16_t* __restrict__ P) {
  const int h = blockIdx.x, b = blockIdx.y;
  __shared__ char kls[128 * 128];   // K[t][d] bf16, byte=(t*128+d*2)^((t&7)<<4)
  const int tid = threadIdx.x, wave = tid >> 6, lane = tid & 63;
  for (int i = 0; i < 4; ++i) {
    int idx = i*256 + tid;
    int t = idx >> 3, c8 = (idx & 7) * 8;
    int srow = (t >> 6)*4096 + b*64 + (t & 63);
    bf16x8 v = *(const bf16x8*)(kb + (size_t)srow*768 + h*64 + c8);
    *(bf16x8*)(kls + ((t*128 + c8*2) ^ ((t & 7) << 4))) = v;
  }
  const int band = wave * 16;
  bf16x8 af[3][2];
  #pragma unroll
  for (int e = 0; e < 3; ++e)
    #pragma unroll
    for (int ks = 0; ks < 2; ++ks)
      af[e][ks] = *(const bf16x8*)(qeb + (size_t)(b*64 + band + (lane & 15))*2304
                                   + (e*12 + h)*64 + ks*32 + (lane >> 4)*8);
  __syncthreads();
  f32x4 acc[3][8] = {};
  #pragma unroll
  for (int ks = 0; ks < 2; ++ks) {
    bf16x8 bfr[8];
    #pragma unroll
    for (int n = 0; n < 8; ++n) {
      int t = n*16 + (lane & 15);
      bfr[n] = *(const bf16x8*)(kls + ((t*128 + (ks*32 + (lane >> 4)*8)*2) ^ ((t & 7) << 4)));
    }
    #pragma unroll
    for (int e = 0; e < 3; ++e)
      #pragma unroll
      for (int n = 0; n < 8; ++n)
        acc[e][n] = __builtin_amdgcn_mfma_f32_16x16x32_bf16(af[e][ks], bfr[n], acc[e][n], 0, 0, 0);
  }
  const int colb = lane & 15;
  float mx[4], inv[4];
  #pragma unroll
  for (int r = 0; r < 4; ++r) {
    const int l = band + (lane >> 4)*4 + r;
    const unsigned long long* mr = msk64 + (size_t)(b*64 + l)*6;
    #pragma unroll
    for (int e = 0; e < 3; ++e) {
      unsigned long long w0 = mr[e*2], w1 = mr[e*2 + 1];
      #pragma unroll
      for (int n = 0; n < 8; ++n) {
        unsigned long long w = (n < 4) ? w0 : w1;
        int bitpos = (n*16 + colb) & 63;
        if (!((w >> bitpos) & 1ull)) acc[e][n][r] = NEGV;
      }
    }
  }
  #pragma unroll
  for (int r = 0; r < 4; ++r) {
    float m = NEGV;
    #pragma unroll
    for (int e = 0; e < 3; ++e)
      #pragma unroll
      for (int n = 0; n < 8; ++n) m = fmaxf(m, acc[e][n][r]);
    #pragma unroll
    for (int off = 1; off < 16; off <<= 1) m = fmaxf(m, __shfl_xor(m, off, 64));
    mx[r] = m;
  }
  #pragma unroll
  for (int r = 0; r < 4; ++r) {
    float s = 0.0f;
    #pragma unroll
    for (int e = 0; e < 3; ++e)
      #pragma unroll
      for (int n = 0; n < 8; ++n) {
        float v = __expf(acc[e][n][r] - mx[r]);
        acc[e][n][r] = v; s += v;
      }
    #pragma unroll
    for (int off = 1; off < 16; off <<= 1) s += __shfl_xor(s, off, 64);
    inv[r] = (mx[r] < -5e9f) ? 0.0f : 1.0f / s;
  }
  const size_t prow = ((size_t)(h*64 + b))*64;
  #pragma unroll
  for (int e = 0; e < 3; ++e)
    #pragma unroll
    for (int n = 0; n < 8; ++n)
      #pragma unroll
      for (int r = 0; r < 4; ++r) {
        int l = band + (lane >> 4)*4 + r;
        P[(prow + l)*384 + e*128 + n*16 + colb] = (bf16_t)(acc[e][n][r] * inv[r]);
      }
}

// ---------- PV: neigh[l][(h,d)] = gelu( P[l][te'] @ MsgT[d][te'] ) via MFMA ----------
__global__ __launch_bounds__(256)
void pv_mfma(const bf16_t* __restrict__ P, const bf16_t* __restrict__ msgbT,
             float* __restrict__ neigh) {
  const int h = blockIdx.x, b = blockIdx.y;
  __shared__ char pls[64 * 768];   // P[l][te'] byte=(l*768+te*2)^((l&7)<<4)
  __shared__ char mls[64 * 768];   // MsgT[d][te'] same swizzle
  const int tid = threadIdx.x, wave = tid >> 6, lane = tid & 63;
  const size_t prow = ((size_t)(h*64 + b))*64;
  for (int i = 0; i < 12; ++i) {
    int idx = i*256 + tid;
    int l = idx / 48, cw = idx - l*48;
    bf16x8 v = *(const bf16x8*)(P + (prow + l)*384 + cw*8);
    *(bf16x8*)(pls + ((l*768 + cw*16) ^ ((l & 7) << 4))) = v;
  }
  for (int i = 0; i < 12; ++i) {
    int idx = i*256 + tid;
    int d = idx / 48, cw = idx - d*48;
    int te0 = cw*8;
    int e = te0 >> 7, rem = te0 & 127, s = rem >> 6, tt0 = rem & 63;
    bf16x8 v = *(const bf16x8*)(msgbT + (size_t)((e*12 + h)*64 + d)*8192 + s*4096 + b*64 + tt0);
    *(bf16x8*)(mls + ((d*768 + te0*2) ^ ((d & 7) << 4))) = v;
  }
  __syncthreads();
  const int band = wave * 16;
  f32x4 acc[4] = {};
  for (int kstep = 0; kstep < 12; ++kstep) {
    const int kb2 = (kstep*32 + (lane >> 4)*8)*2;
    const int la = band + (lane & 15);
    bf16x8 a = *(const bf16x8*)(pls + ((la*768 + kb2) ^ ((la & 7) << 4)));
    #pragma unroll
    for (int n = 0; n < 4; ++n) {
      int d = n*16 + (lane & 15);
      bf16x8 bfr = *(const bf16x8*)(mls + ((d*768 + kb2) ^ ((d & 7) << 4)));
      acc[n] = __builtin_amdgcn_mfma_f32_16x16x32_bf16(a, bfr, acc[n], 0, 0, 0);
    }
  }
  #pragma unroll
  for (int n = 0; n < 4; ++n)
    #pragma unroll
    for (int r = 0; r < 4; ++r) {
      int l = band + (lane >> 4)*4 + r;
      int d = n*16 + (lane & 15);
      float x = acc[n][r];
      float g = 0.5f * x * (1.0f + erff(x * 0.70710678118654752f));
      neigh[(size_t)(b*64 + l)*768 + h*64 + d] = g;
    }
}

// ---------- fp32 projection GEMM (retype; output-sensitive path) ----------
template<int SPLIT>
__global__ __launch_bounds__(256)
void proj_gemm(const float* __restrict__ X, const float* __restrict__ W,
               const float* __restrict__ bias, float* __restrict__ Y) {
  __shared__ float Xs[16][68];
  __shared__ float Ws[16][68];
  const int bn = blockIdx.x;
  const int bm = blockIdx.y;
  const int tid = threadIdx.x;
  const int tx = tid & 15, ty = tid >> 4;
  const int woff = (SPLIT && bm >= 64) ? 768 : 0;
  const int row0 = bm * 64, col0 = bn * 64;
  const int lrow = tid >> 2;
  const int lk4  = (tid & 3) * 4;
  const float* Xp = X + (size_t)(row0 + lrow) * 768 + lk4;
  const float* Wp = W + (size_t)(col0 + woff + lrow) * 768 + lk4;
  float acc[4][4] = {};
  for (int k0 = 0; k0 < 768; k0 += 16) {
    float4 xa = *(const float4*)(Xp + k0);
    float4 wa = *(const float4*)(Wp + k0);
    __syncthreads();
    Xs[lk4+0][lrow] = xa.x; Xs[lk4+1][lrow] = xa.y; Xs[lk4+2][lrow] = xa.z; Xs[lk4+3][lrow] = xa.w;
    Ws[lk4+0][lrow] = wa.x; Ws[lk4+1][lrow] = wa.y; Ws[lk4+2][lrow] = wa.z; Ws[lk4+3][lrow] = wa.w;
    __syncthreads();
    #pragma unroll
    for (int k = 0; k < 16; ++k) {
      float4 a = *(const float4*)&Xs[k][ty*4];
      float4 b = *(const float4*)&Ws[k][tx*4];
      acc[0][0] += a.x*b.x; acc[0][1] += a.x*b.y; acc[0][2] += a.x*b.z; acc[0][3] += a.x*b.w;
      acc[1][0] += a.y*b.x; acc[1][1] += a.y*b.y; acc[1][2] += a.y*b.z; acc[1][3] += a.y*b.w;
      acc[2][0] += a.z*b.x; acc[2][1] += a.z*b.y; acc[2][2] += a.z*b.z; acc[2][3] += a.z*b.w;
      acc[3][0] += a.w*b.x; acc[3][1] += a.w*b.y; acc[3][2] += a.w*b.z; acc[3][3] += a.w*b.w;
    }
  }
  const float b0 = bias[col0+woff+tx*4+0];
  const float b1 = bias[col0+woff+tx*4+1];
  const float b2 = bias[col0+woff+tx*4+2];
  const float b3 = bias[col0+woff+tx*4+3];
  #pragma unroll
  for (int i = 0; i < 4; ++i) {
    float4 o;
    o.x = acc[i][0]+b0; o.y = acc[i][1]+b1; o.z = acc[i][2]+b2; o.w = acc[i][3]+b3;
    *(float4*)(Y + (size_t)(row0+ty*4+i)*768 + col0 + tx*4) = o;
  }
}

// ---------- skip-mix + LayerNorm, one wave per row ----------
__global__ __launch_bounds__(256)
void ln_kernel(const float* __restrict__ rt, const float* __restrict__ centers,
               const float* __restrict__ skip, const float* __restrict__ gamma,
               const float* __restrict__ beta, float* __restrict__ out) {
  const int row  = blockIdx.x*4 + (threadIdx.x >> 6);
  const int lane = threadIdx.x & 63;
  const float alpha = 1.0f / (1.0f + expf(-skip[0]));
  const float* rp = rt + (size_t)row*768;
  const float* cp = centers + (size_t)row*768;
  float r[12];
  float sum = 0.0f;
  #pragma unroll
  for (int c = 0; c < 12; ++c) {
    int j = lane + 64*c;
    float x = alpha*rp[j] + (1.0f - alpha)*cp[j];
    r[c] = x; sum += x;
  }
  #pragma unroll
  for (int off = 1; off < 64; off <<= 1) sum += __shfl_xor(sum, off, 64);
  float mean = sum * (1.0f/768.0f);
  float vsum = 0.0f;
  #pragma unroll
  for (int c = 0; c < 12; ++c) { float d = r[c] - mean; vsum += d*d; }
  #pragma unroll
  for (int off = 1; off < 64; off <<= 1) vsum += __shfl_xor(vsum, off, 64);
  float inv = 1.0f / sqrtf(vsum * (1.0f/768.0f) + 1e-5f);
  #pragma unroll
  for (int c = 0; c < 12; ++c) {
    int j = lane + 64*c;
    out[(size_t)row*768 + j] = gamma[j]*(r[c] - mean)*inv + beta[j];
  }
}

extern "C" void kernel_launch(void* const* d_in, const int* in_sizes, int n_in,
                              void* d_out, int out_size, void* d_ws, size_t ws_size,
                              hipStream_t stream) {
  const int*   ids     = (const int*)  d_in[0];
  const float* centers = (const float*)d_in[1];
  const float* allemb  = (const float*)d_in[2];
  const float* pre     = (const float*)d_in[3];
  const float* back    = (const float*)d_in[4];
  const float* click   = (const float*)d_in[5];
  const float* Wq = (const float*)d_in[7];
  const float* bq = (const float*)d_in[8];
  const float* Wk = (const float*)d_in[9];
  const float* bk = (const float*)d_in[10];
  const float* Wv = (const float*)d_in[11];
  const float* bv = (const float*)d_in[12];
  const float* Wa = (const float*)d_in[13];
  const float* ba = (const float*)d_in[14];
  const float* pri  = (const float*)d_in[15];
  const float* ratt = (const float*)d_in[16];
  const float* rmsg = (const float*)d_in[17];
  const float* skip = (const float*)d_in[18];
  const float* gam  = (const float*)d_in[19];
  const float* bet  = (const float*)d_in[20];
  float* out = (float*)d_out;

  char* wp = (char*)d_ws;
  bf16_t* cen_bf = (bf16_t*)wp;  wp += 6291456;    // 4096*768
  bf16_t* all_bf = (bf16_t*)wp;  wp += 12582912;   // 8192*768
  bf16_t* Wq_bf  = (bf16_t*)wp;  wp += 1179648;    // 768*768
  bf16_t* Wk_bf  = (bf16_t*)wp;  wp += 2359296;    // 1536*768
  bf16_t* Wv_bf  = (bf16_t*)wp;  wp += 2359296;    // 1536*768
  bf16_t* Wqp    = (bf16_t*)wp;  wp += 3538944;    // 2304*768
  float*  bqp    = (float*)wp;   wp += 9216;       // 2304
  bf16_t* Wvp    = (bf16_t*)wp;  wp += 7077888;    // 2*2304*768
  float*  bvp    = (float*)wp;   wp += 18432;      // 2*2304
  bf16_t* qeb    = (bf16_t*)wp;  wp += 18874368;   // 4096*2304
  bf16_t* kb     = (bf16_t*)wp;  wp += 12582912;   // 8192*768
  bf16_t* msgbT  = (bf16_t*)wp;  wp += 37748736;   // 2304*8192
  unsigned long long* msk64 = (unsigned long long*)wp; wp += 196608;  // 4096*6
  bf16_t* P      = (bf16_t*)wp;  wp += 37748736;   // 768*64*384
  float*  neigh  = (float*)wp;   wp += 12582912;   // 4096*768
  float*  rt     = (float*)wp;   wp += 12582912;   // 4096*768

  f2b_kernel<<<dim3(2048), 256, 0, stream>>>(centers, cen_bf, 786432);
  f2b_kernel<<<dim3(2048), 256, 0, stream>>>(allemb,  all_bf, 1572864);
  f2b_kernel<<<dim3(576),  256, 0, stream>>>(Wq, Wq_bf, 147456);
  f2b_kernel<<<dim3(1152), 256, 0, stream>>>(Wk, Wk_bf, 294912);
  f2b_kernel<<<dim3(1152), 256, 0, stream>>>(Wv, Wv_bf, 294912);

  fold_q<<<dim3(36, 3), 256, 0, stream>>>(Wq_bf, bq, ratt, pri, Wqp, bqp);
  fold_v<<<dim3(72, 3), 256, 0, stream>>>(Wv_bf, bv, rmsg, Wvp, bvp);

  proj_mfmaB<2304, 0, 0, 0>      <<<dim3(18, 32), 256, 0, stream>>>(cen_bf, Wqp, bqp, qeb);
  proj_mfmaB<768, 768*768, 768, 32><<<dim3(6, 64), 256, 0, stream>>>(all_bf, Wk_bf, bk, kb);
  msg_projT<<<dim3(18, 64), 256, 0, stream>>>(all_bf, Wvp, bvp, msgbT);

  mask_kernel<<<dim3(64), 256, 0, stream>>>(ids, pre, back, click, msk64);
  scores_fused<<<dim3(12, 64), 256, 0, stream>>>(qeb, kb, msk64, P);
  pv_mfma<<<dim3(12, 64), 256, 0, stream>>>(P, msgbT, neigh);

  proj_gemm<0><<<dim3(12, 64), 256, 0, stream>>>(neigh, Wa, ba, rt);
  ln_kernel<<<dim3(1024), 256, 0, stream>>>(rt, centers, skip, gam, bet, out);
}

// Round 5
// 372.607 us; speedup vs baseline: 2.0560x; 1.1286x over previous
//
#include <hip/hip_runtime.h>
#include <cmath>

#define NEGV -1e10f

typedef __bf16 bf16_t;
typedef bf16_t bf16x8 __attribute__((ext_vector_type(8)));
typedef bf16_t bf16x4 __attribute__((ext_vector_type(4)));
typedef float f32x4 __attribute__((ext_vector_type(4)));

typedef const __attribute__((address_space(1))) void* gas1p;
typedef __attribute__((address_space(3))) void* las3p;

// ---------- fp32 -> bf16 (RNE) vectorized cast ----------
__global__ __launch_bounds__(256)
void f2b_kernel(const float* __restrict__ in, bf16_t* __restrict__ out, int n4) {
  int i = blockIdx.x * 256 + threadIdx.x;
  const int stride = gridDim.x * 256;
  for (; i < n4; i += stride) {
    float4 v = *(const float4*)(in + (size_t)i * 4);
    bf16x4 o = { (bf16_t)v.x, (bf16_t)v.y, (bf16_t)v.z, (bf16_t)v.w };
    *(bf16x4*)(out + (size_t)i * 4) = o;
  }
}

// ---------- fold ra (and pri/sqrt_dk) into Wq ----------
__global__ __launch_bounds__(256)
void fold_q(const bf16_t* __restrict__ Wqb, const float* __restrict__ bq,
            const float* __restrict__ ratt, const float* __restrict__ pri,
            bf16_t* __restrict__ Wqp, float* __restrict__ bqp) {
  const int eh = blockIdx.x; const int e = eh / 12, h = eh - e*12;
  const int re = (e==0) ? 0 : (e==1 ? 4 : 5);
  const float scale = pri[re*12 + h] * 0.125f;
  const int c0 = blockIdx.y * 256;
  __shared__ float raS[64][64];
  __shared__ bf16_t WS[64][256];
  const int tid = threadIdx.x;
  for (int i = 0; i < 16; ++i) {
    int idx = i*256 + tid;
    raS[idx>>6][idx&63] = ratt[((size_t)(re*12+h)*64 + (idx>>6))*64 + (idx&63)];
  }
  for (int i = 0; i < 8; ++i) {
    int idx = i*256 + tid; int f = idx>>5, c8 = (idx&31)*8;
    *(bf16x8*)&WS[f][c8] = *(const bf16x8*)(Wqb + (size_t)(h*64+f)*768 + c0 + c8);
  }
  __syncthreads();
  const int c = tid;
  for (int d = 0; d < 64; ++d) {
    float acc = 0.0f;
    for (int f = 0; f < 64; ++f) acc += raS[d][f] * (float)WS[f][c];
    Wqp[((size_t)(e*12+h)*64 + d)*768 + c0 + c] = (bf16_t)(scale * acc);
  }
  if (blockIdx.y == 0 && tid < 64) {
    float acc = 0.0f;
    for (int f = 0; f < 64; ++f) acc += raS[tid][f] * bq[h*64+f];
    bqp[(e*12+h)*64 + tid] = scale * acc;
  }
}

// ---------- fold rm into Wv ----------
__global__ __launch_bounds__(256)
void fold_v(const bf16_t* __restrict__ Wvb, const float* __restrict__ bv,
            const float* __restrict__ rmsg, bf16_t* __restrict__ Wvp, float* __restrict__ bvp) {
  const int s = blockIdx.x / 36;
  const int eh = blockIdx.x - s*36; const int e = eh / 12, h = eh - e*12;
  const int re = (e==0) ? 0 : (e==1 ? 4 : 5);
  const int c0 = blockIdx.y * 256;
  __shared__ float rmS[64][64];   // [f][d]
  __shared__ bf16_t WS[64][256];
  const int tid = threadIdx.x;
  for (int i = 0; i < 16; ++i) {
    int idx = i*256 + tid;
    rmS[idx>>6][idx&63] = rmsg[((size_t)(re*12+h)*64 + (idx>>6))*64 + (idx&63)];
  }
  for (int i = 0; i < 8; ++i) {
    int idx = i*256 + tid; int f = idx>>5, c8 = (idx&31)*8;
    *(bf16x8*)&WS[f][c8] = *(const bf16x8*)(Wvb + (size_t)(s*768 + h*64 + f)*768 + c0 + c8);
  }
  __syncthreads();
  const int c = tid;
  for (int d = 0; d < 64; ++d) {
    float acc = 0.0f;
    for (int f = 0; f < 64; ++f) acc += rmS[f][d] * (float)WS[f][c];
    Wvp[(size_t)s*2304*768 + ((size_t)(e*12+h)*64 + d)*768 + c0 + c] = (bf16_t)acc;
  }
  if (blockIdx.y == 0 && tid < 64) {
    float acc = 0.0f;
    for (int f = 0; f < 64; ++f) acc += rmS[f][tid] * bv[s*768 + h*64 + f];
    bvp[s*2304 + (e*12+h)*64 + tid] = acc;
  }
}

// ---------- MFMA GEMM, bf16 out: Y[M,NCOLS] = X[M,768] @ W[s-slice][768]^T + bias ----------
template<int NCOLS, int WSTRIDE, int BSTRIDE, int MHALF>
__global__ __launch_bounds__(256)
void proj_mfmaB(const bf16_t* __restrict__ X, const bf16_t* __restrict__ W,
                const float* __restrict__ bias, bf16_t* __restrict__ Y) {
  __shared__ bf16_t As[128 * 32];
  __shared__ bf16_t Bs[128 * 32];
  const int bn = blockIdx.x, bm = blockIdx.y;
  const int s = (MHALF && bm >= MHALF) ? 1 : 0;
  const int row0 = bm * 128, col0 = bn * 128;
  const int tid = threadIdx.x, wave = tid >> 6, lane = tid & 63;
  const int wr = wave >> 1, wc = wave & 1;
  f32x4 acc[4][4] = {};
  const int arow = wr * 64 + (lane & 15);
  const int bcol = wc * 64 + (lane & 15);
  const int koff = (lane >> 4) * 8;
  const bf16_t* Wb = W + (size_t)s * WSTRIDE;
  for (int k0 = 0; k0 < 768; k0 += 32) {
    __syncthreads();
    #pragma unroll
    for (int i = 0; i < 2; ++i) {
      int c = i * 256 + tid; int r = c >> 2; int c8 = (c & 3) * 8;
      __builtin_amdgcn_global_load_lds((gas1p)(X  + (size_t)(row0 + r) * 768 + k0 + c8),
                                       (las3p)(As + c * 8), 16, 0, 0);
      __builtin_amdgcn_global_load_lds((gas1p)(Wb + (size_t)(col0 + r) * 768 + k0 + c8),
                                       (las3p)(Bs + c * 8), 16, 0, 0);
    }
    __syncthreads();
    bf16x8 af[4], bfr[4];
    #pragma unroll
    for (int m = 0; m < 4; ++m) af[m]  = *(const bf16x8*)(As + (arow + m * 16) * 32 + koff);
    #pragma unroll
    for (int n = 0; n < 4; ++n) bfr[n] = *(const bf16x8*)(Bs + (bcol + n * 16) * 32 + koff);
    #pragma unroll
    for (int m = 0; m < 4; ++m)
      #pragma unroll
      for (int n = 0; n < 4; ++n)
        acc[m][n] = __builtin_amdgcn_mfma_f32_16x16x32_bf16(af[m], bfr[n], acc[m][n], 0, 0, 0);
  }
  const int ocol0 = col0 + wc * 64 + (lane & 15);
  const int orow0 = row0 + wr * 64 + (lane >> 4) * 4;
  #pragma unroll
  for (int n = 0; n < 4; ++n) {
    const int col = ocol0 + n * 16;
    const float bvl = bias[s * BSTRIDE + col];
    #pragma unroll
    for (int m = 0; m < 4; ++m)
      #pragma unroll
      for (int r = 0; r < 4; ++r)
        Y[(size_t)(orow0 + m * 16 + r) * NCOLS + col] = (bf16_t)(acc[m][n][r] + bvl);
  }
}

// ---------- MFMA GEMM, fp32 out (retype): Y[M,768] = X[M,768] @ W[768,768]^T + bias ----------
__global__ __launch_bounds__(256)
void proj_mfmaF(const bf16_t* __restrict__ X, const bf16_t* __restrict__ W,
                const float* __restrict__ bias, float* __restrict__ Y) {
  __shared__ bf16_t As[128 * 32];
  __shared__ bf16_t Bs[128 * 32];
  const int bn = blockIdx.x, bm = blockIdx.y;
  const int row0 = bm * 128, col0 = bn * 128;
  const int tid = threadIdx.x, wave = tid >> 6, lane = tid & 63;
  const int wr = wave >> 1, wc = wave & 1;
  f32x4 acc[4][4] = {};
  const int arow = wr * 64 + (lane & 15);
  const int bcol = wc * 64 + (lane & 15);
  const int koff = (lane >> 4) * 8;
  for (int k0 = 0; k0 < 768; k0 += 32) {
    __syncthreads();
    #pragma unroll
    for (int i = 0; i < 2; ++i) {
      int c = i * 256 + tid; int r = c >> 2; int c8 = (c & 3) * 8;
      __builtin_amdgcn_global_load_lds((gas1p)(X + (size_t)(row0 + r) * 768 + k0 + c8),
                                       (las3p)(As + c * 8), 16, 0, 0);
      __builtin_amdgcn_global_load_lds((gas1p)(W + (size_t)(col0 + r) * 768 + k0 + c8),
                                       (las3p)(Bs + c * 8), 16, 0, 0);
    }
    __syncthreads();
    bf16x8 af[4], bfr[4];
    #pragma unroll
    for (int m = 0; m < 4; ++m) af[m]  = *(const bf16x8*)(As + (arow + m * 16) * 32 + koff);
    #pragma unroll
    for (int n = 0; n < 4; ++n) bfr[n] = *(const bf16x8*)(Bs + (bcol + n * 16) * 32 + koff);
    #pragma unroll
    for (int m = 0; m < 4; ++m)
      #pragma unroll
      for (int n = 0; n < 4; ++n)
        acc[m][n] = __builtin_amdgcn_mfma_f32_16x16x32_bf16(af[m], bfr[n], acc[m][n], 0, 0, 0);
  }
  const int ocol0 = col0 + wc * 64 + (lane & 15);
  const int orow0 = row0 + wr * 64 + (lane >> 4) * 4;
  #pragma unroll
  for (int n = 0; n < 4; ++n) {
    const int col = ocol0 + n * 16;
    const float bvl = bias[col];
    #pragma unroll
    for (int m = 0; m < 4; ++m)
      #pragma unroll
      for (int r = 0; r < 4; ++r)
        Y[(size_t)(orow0 + m * 16 + r) * 768 + col] = acc[m][n][r] + bvl;
  }
}

// ---------- msg projection with TRANSPOSED output: YT[(e,h,d)][token] ----------
__global__ __launch_bounds__(256)
void msg_projT(const bf16_t* __restrict__ X, const bf16_t* __restrict__ W,
               const float* __restrict__ bias, bf16_t* __restrict__ YT) {
  __shared__ bf16_t As[128 * 32];
  __shared__ bf16_t Bs[128 * 32];
  __shared__ char tl[128 * 256];   // [col][token] bf16, byte=(c*256+t*2)^((c&7)<<4)
  const int bn = blockIdx.x, bm = blockIdx.y;
  const int s = (bm >= 32) ? 1 : 0;
  const int row0 = bm * 128, col0 = bn * 128;
  const int tid = threadIdx.x, wave = tid >> 6, lane = tid & 63;
  const int wr = wave >> 1, wc = wave & 1;
  f32x4 acc[4][4] = {};
  const int arow = wr * 64 + (lane & 15);
  const int bcol = wc * 64 + (lane & 15);
  const int koff = (lane >> 4) * 8;
  const bf16_t* Wb = W + (size_t)s * 2304 * 768;
  for (int k0 = 0; k0 < 768; k0 += 32) {
    __syncthreads();
    #pragma unroll
    for (int i = 0; i < 2; ++i) {
      int c = i * 256 + tid; int r = c >> 2; int c8 = (c & 3) * 8;
      __builtin_amdgcn_global_load_lds((gas1p)(X  + (size_t)(row0 + r) * 768 + k0 + c8),
                                       (las3p)(As + c * 8), 16, 0, 0);
      __builtin_amdgcn_global_load_lds((gas1p)(Wb + (size_t)(col0 + r) * 768 + k0 + c8),
                                       (las3p)(Bs + c * 8), 16, 0, 0);
    }
    __syncthreads();
    bf16x8 af[4], bfr[4];
    #pragma unroll
    for (int m = 0; m < 4; ++m) af[m]  = *(const bf16x8*)(As + (arow + m * 16) * 32 + koff);
    #pragma unroll
    for (int n = 0; n < 4; ++n) bfr[n] = *(const bf16x8*)(Bs + (bcol + n * 16) * 32 + koff);
    #pragma unroll
    for (int m = 0; m < 4; ++m)
      #pragma unroll
      for (int n = 0; n < 4; ++n)
        acc[m][n] = __builtin_amdgcn_mfma_f32_16x16x32_bf16(af[m], bfr[n], acc[m][n], 0, 0, 0);
  }
  __syncthreads();
  #pragma unroll
  for (int n = 0; n < 4; ++n) {
    const int cl = wc * 64 + n * 16 + (lane & 15);
    const float bvl = bias[s * 2304 + col0 + cl];
    #pragma unroll
    for (int m = 0; m < 4; ++m)
      #pragma unroll
      for (int r = 0; r < 4; ++r) {
        const int rl = wr * 64 + m * 16 + (lane >> 4) * 4 + r;
        *(bf16_t*)(tl + ((cl * 256 + rl * 2) ^ ((cl & 7) << 4))) = (bf16_t)(acc[m][n][r] + bvl);
      }
  }
  __syncthreads();
  for (int i = 0; i < 8; ++i) {
    int idx = i * 256 + tid; int c = idx >> 4; int t0 = (idx & 15) * 8;
    bf16x8 v = *(const bf16x8*)(tl + ((c * 256 + t0 * 2) ^ ((c & 7) << 4)));
    *(bf16x8*)(YT + (size_t)(col0 + c) * 8192 + row0 + t0) = v;
  }
}

// ---------- mask closure -> packed 64-bit rowmasks ----------
__global__ __launch_bounds__(256)
void mask_kernel(const int* __restrict__ ids, const float* __restrict__ pre,
                 const float* __restrict__ back, const float* __restrict__ click,
                 unsigned long long* __restrict__ msk64) {
  const int b = blockIdx.x, tid = threadIdx.x;
  __shared__ float pm[64][68], bmm[64][68], cm[64][68];
  __shared__ unsigned long long sbits[64];
  __shared__ unsigned long long colbits[384];
  __shared__ int sid[64];
  __shared__ unsigned char srep[64];
  for (int r = 0; r < 4; ++r) {
    int idx = r*256 + tid; int row = idx >> 4; int c4 = (idx & 15) * 4;
    *(float4*)&pm[row][c4]  = *(const float4*)(pre   + (size_t)b*4096 + row*64 + c4);
    *(float4*)&bmm[row][c4] = *(const float4*)(back  + (size_t)b*4096 + row*64 + c4);
    *(float4*)&cm[row][c4]  = *(const float4*)(click + (size_t)b*4096 + row*64 + c4);
  }
  if (tid < 64) sid[tid] = ids[b*64 + tid];
  __syncthreads();
  if (tid < 64) {
    int myid = sid[tid];
    unsigned long long bits = 0ull; int rep = 0;
    for (int l = 0; l < 64; ++l) {
      bool eq = (sid[l] == myid);
      bits |= ((unsigned long long)eq) << l;
      rep |= (eq && (l < tid)) ? 1 : 0;
    }
    sbits[tid] = bits; srep[tid] = (unsigned char)rep;
  }
  for (int j = tid; j < 384; j += 256) {
    int e = j >> 7, t = j & 127;
    unsigned long long cb = 0ull;
    if (e == 0) {
      if (t >= 64) { int tt = t - 64; for (int l = 0; l < 64; ++l) cb |= ((unsigned long long)(cm[l][tt] > 0.0f)) << l; }
    } else if (e == 1) {
      if (t < 64) { for (int l = 0; l < 64; ++l) cb |= ((unsigned long long)(bmm[l][t] > 0.0f)) << l; }
    } else {
      if (t < 64) { for (int l = 0; l < 64; ++l) cb |= ((unsigned long long)(pm[l][t] > 0.0f)) << l; }
    }
    colbits[j] = cb;
  }
  __syncthreads();
  for (int idx = tid; idx < 384; idx += 256) {
    int l = idx / 6, w = idx - l*6;
    unsigned long long r = 0ull;
    if (!srep[l]) {
      unsigned long long sb = sbits[l];
      const int base = w*64;
      for (int jj = 0; jj < 64; ++jj)
        r |= (unsigned long long)((sb & colbits[base + jj]) != 0ull) << jj;
    }
    msk64[((size_t)(b*64) + l)*6 + w] = r;
  }
}

// ---------- fused scores + masked softmax -> P bf16 [hb*64+l][384] (te' = e*128 + t) ----------
__global__ __launch_bounds__(256)
void scores_fused(const bf16_t* __restrict__ qeb, const bf16_t* __restrict__ kb,
                  const unsigned long long* __restrict__ msk64, bf16_t* __restrict__ P) {
  const int h = blockIdx.x, b = blockIdx.y;
  __shared__ char kls[128 * 128];   // K[t][d] bf16, byte=(t*128+d*2)^((t&7)<<4)
  const int tid = threadIdx.x, wave = tid >> 6, lane = tid & 63;
  for (int i = 0; i < 4; ++i) {
    int idx = i*256 + tid;
    int t = idx >> 3, c8 = (idx & 7) * 8;
    int srow = (t >> 6)*4096 + b*64 + (t & 63);
    bf16x8 v = *(const bf16x8*)(kb + (size_t)srow*768 + h*64 + c8);
    *(bf16x8*)(kls + ((t*128 + c8*2) ^ ((t & 7) << 4))) = v;
  }
  const int band = wave * 16;
  bf16x8 af[3][2];
  #pragma unroll
  for (int e = 0; e < 3; ++e)
    #pragma unroll
    for (int ks = 0; ks < 2; ++ks)
      af[e][ks] = *(const bf16x8*)(qeb + (size_t)(b*64 + band + (lane & 15))*2304
                                   + (e*12 + h)*64 + ks*32 + (lane >> 4)*8);
  __syncthreads();
  f32x4 acc[3][8] = {};
  #pragma unroll
  for (int ks = 0; ks < 2; ++ks) {
    bf16x8 bfr[8];
    #pragma unroll
    for (int n = 0; n < 8; ++n) {
      int t = n*16 + (lane & 15);
      bfr[n] = *(const bf16x8*)(kls + ((t*128 + (ks*32 + (lane >> 4)*8)*2) ^ ((t & 7) << 4)));
    }
    #pragma unroll
    for (int e = 0; e < 3; ++e)
      #pragma unroll
      for (int n = 0; n < 8; ++n)
        acc[e][n] = __builtin_amdgcn_mfma_f32_16x16x32_bf16(af[e][ks], bfr[n], acc[e][n], 0, 0, 0);
  }
  const int colb = lane & 15;
  float mx[4], inv[4];
  #pragma unroll
  for (int r = 0; r < 4; ++r) {
    const int l = band + (lane >> 4)*4 + r;
    const unsigned long long* mr = msk64 + (size_t)(b*64 + l)*6;
    #pragma unroll
    for (int e = 0; e < 3; ++e) {
      unsigned long long w0 = mr[e*2], w1 = mr[e*2 + 1];
      #pragma unroll
      for (int n = 0; n < 8; ++n) {
        unsigned long long w = (n < 4) ? w0 : w1;
        int bitpos = (n*16 + colb) & 63;
        if (!((w >> bitpos) & 1ull)) acc[e][n][r] = NEGV;
      }
    }
  }
  #pragma unroll
  for (int r = 0; r < 4; ++r) {
    float m = NEGV;
    #pragma unroll
    for (int e = 0; e < 3; ++e)
      #pragma unroll
      for (int n = 0; n < 8; ++n) m = fmaxf(m, acc[e][n][r]);
    #pragma unroll
    for (int off = 1; off < 16; off <<= 1) m = fmaxf(m, __shfl_xor(m, off, 64));
    mx[r] = m;
  }
  #pragma unroll
  for (int r = 0; r < 4; ++r) {
    float s = 0.0f;
    #pragma unroll
    for (int e = 0; e < 3; ++e)
      #pragma unroll
      for (int n = 0; n < 8; ++n) {
        float v = __expf(acc[e][n][r] - mx[r]);
        acc[e][n][r] = v; s += v;
      }
    #pragma unroll
    for (int off = 1; off < 16; off <<= 1) s += __shfl_xor(s, off, 64);
    inv[r] = (mx[r] < -5e9f) ? 0.0f : 1.0f / s;
  }
  const size_t prow = ((size_t)(h*64 + b))*64;
  #pragma unroll
  for (int e = 0; e < 3; ++e)
    #pragma unroll
    for (int n = 0; n < 8; ++n)
      #pragma unroll
      for (int r = 0; r < 4; ++r) {
        int l = band + (lane >> 4)*4 + r;
        P[(prow + l)*384 + e*128 + n*16 + colb] = (bf16_t)(acc[e][n][r] * inv[r]);
      }
}

// ---------- PV: neigh_bf[l][(h,d)] = gelu( P[l][te'] @ MsgT[d][te'] ) via MFMA, bf16 out ----------
__global__ __launch_bounds__(256)
void pv_mfma(const bf16_t* __restrict__ P, const bf16_t* __restrict__ msgbT,
             bf16_t* __restrict__ neigh) {
  const int h = blockIdx.x, b = blockIdx.y;
  __shared__ char pls[64 * 768];   // P[l][te'] byte=(l*768+te*2)^((l&7)<<4)
  __shared__ char mls[64 * 768];   // MsgT[d][te'] same swizzle
  const int tid = threadIdx.x, wave = tid >> 6, lane = tid & 63;
  const size_t prow = ((size_t)(h*64 + b))*64;
  for (int i = 0; i < 12; ++i) {
    int idx = i*256 + tid;
    int l = idx / 48, cw = idx - l*48;
    bf16x8 v = *(const bf16x8*)(P + (prow + l)*384 + cw*8);
    *(bf16x8*)(pls + ((l*768 + cw*16) ^ ((l & 7) << 4))) = v;
  }
  for (int i = 0; i < 12; ++i) {
    int idx = i*256 + tid;
    int d = idx / 48, cw = idx - d*48;
    int te0 = cw*8;
    int e = te0 >> 7, rem = te0 & 127, s = rem >> 6, tt0 = rem & 63;
    bf16x8 v = *(const bf16x8*)(msgbT + (size_t)((e*12 + h)*64 + d)*8192 + s*4096 + b*64 + tt0);
    *(bf16x8*)(mls + ((d*768 + te0*2) ^ ((d & 7) << 4))) = v;
  }
  __syncthreads();
  const int band = wave * 16;
  f32x4 acc[4] = {};
  for (int kstep = 0; kstep < 12; ++kstep) {
    const int kb2 = (kstep*32 + (lane >> 4)*8)*2;
    const int la = band + (lane & 15);
    bf16x8 a = *(const bf16x8*)(pls + ((la*768 + kb2) ^ ((la & 7) << 4)));
    #pragma unroll
    for (int n = 0; n < 4; ++n) {
      int d = n*16 + (lane & 15);
      bf16x8 bfr = *(const bf16x8*)(mls + ((d*768 + kb2) ^ ((d & 7) << 4)));
      acc[n] = __builtin_amdgcn_mfma_f32_16x16x32_bf16(a, bfr, acc[n], 0, 0, 0);
    }
  }
  #pragma unroll
  for (int n = 0; n < 4; ++n)
    #pragma unroll
    for (int r = 0; r < 4; ++r) {
      int l = band + (lane >> 4)*4 + r;
      int d = n*16 + (lane & 15);
      float x = acc[n][r];
      float g = 0.5f * x * (1.0f + erff(x * 0.70710678118654752f));
      neigh[(size_t)(b*64 + l)*768 + h*64 + d] = (bf16_t)g;
    }
}

// ---------- skip-mix + LayerNorm, one wave per row ----------
__global__ __launch_bounds__(256)
void ln_kernel(const float* __restrict__ rt, const float* __restrict__ centers,
               const float* __restrict__ skip, const float* __restrict__ gamma,
               const float* __restrict__ beta, float* __restrict__ out) {
  const int row  = blockIdx.x*4 + (threadIdx.x >> 6);
  const int lane = threadIdx.x & 63;
  const float alpha = 1.0f / (1.0f + expf(-skip[0]));
  const float* rp = rt + (size_t)row*768;
  const float* cp = centers + (size_t)row*768;
  float r[12];
  float sum = 0.0f;
  #pragma unroll
  for (int c = 0; c < 12; ++c) {
    int j = lane + 64*c;
    float x = alpha*rp[j] + (1.0f - alpha)*cp[j];
    r[c] = x; sum += x;
  }
  #pragma unroll
  for (int off = 1; off < 64; off <<= 1) sum += __shfl_xor(sum, off, 64);
  float mean = sum * (1.0f/768.0f);
  float vsum = 0.0f;
  #pragma unroll
  for (int c = 0; c < 12; ++c) { float d = r[c] - mean; vsum += d*d; }
  #pragma unroll
  for (int off = 1; off < 64; off <<= 1) vsum += __shfl_xor(vsum, off, 64);
  float inv = 1.0f / sqrtf(vsum * (1.0f/768.0f) + 1e-5f);
  #pragma unroll
  for (int c = 0; c < 12; ++c) {
    int j = lane + 64*c;
    out[(size_t)row*768 + j] = gamma[j]*(r[c] - mean)*inv + beta[j];
  }
}

extern "C" void kernel_launch(void* const* d_in, const int* in_sizes, int n_in,
                              void* d_out, int out_size, void* d_ws, size_t ws_size,
                              hipStream_t stream) {
  const int*   ids     = (const int*)  d_in[0];
  const float* centers = (const float*)d_in[1];
  const float* allemb  = (const float*)d_in[2];
  const float* pre     = (const float*)d_in[3];
  const float* back    = (const float*)d_in[4];
  const float* click   = (const float*)d_in[5];
  const float* Wq = (const float*)d_in[7];
  const float* bq = (const float*)d_in[8];
  const float* Wk = (const float*)d_in[9];
  const float* bk = (const float*)d_in[10];
  const float* Wv = (const float*)d_in[11];
  const float* bv = (const float*)d_in[12];
  const float* Wa = (const float*)d_in[13];
  const float* ba = (const float*)d_in[14];
  const float* pri  = (const float*)d_in[15];
  const float* ratt = (const float*)d_in[16];
  const float* rmsg = (const float*)d_in[17];
  const float* skip = (const float*)d_in[18];
  const float* gam  = (const float*)d_in[19];
  const float* bet  = (const float*)d_in[20];
  float* out = (float*)d_out;

  char* wp = (char*)d_ws;
  bf16_t* cen_bf = (bf16_t*)wp;  wp += 6291456;    // 4096*768
  bf16_t* all_bf = (bf16_t*)wp;  wp += 12582912;   // 8192*768
  bf16_t* Wq_bf  = (bf16_t*)wp;  wp += 1179648;    // 768*768
  bf16_t* Wk_bf  = (bf16_t*)wp;  wp += 2359296;    // 1536*768
  bf16_t* Wv_bf  = (bf16_t*)wp;  wp += 2359296;    // 1536*768
  bf16_t* Wa_bf  = (bf16_t*)wp;  wp += 1179648;    // 768*768 (type-0 slice)
  bf16_t* Wqp    = (bf16_t*)wp;  wp += 3538944;    // 2304*768
  float*  bqp    = (float*)wp;   wp += 9216;       // 2304
  bf16_t* Wvp    = (bf16_t*)wp;  wp += 7077888;    // 2*2304*768
  float*  bvp    = (float*)wp;   wp += 18432;      // 2*2304
  bf16_t* qeb    = (bf16_t*)wp;  wp += 18874368;   // 4096*2304
  bf16_t* kb     = (bf16_t*)wp;  wp += 12582912;   // 8192*768
  bf16_t* msgbT  = (bf16_t*)wp;  wp += 37748736;   // 2304*8192
  unsigned long long* msk64 = (unsigned long long*)wp; wp += 196608;  // 4096*6
  bf16_t* P      = (bf16_t*)wp;  wp += 37748736;   // 768*64*384
  bf16_t* neighb = (bf16_t*)wp;  wp += 6291456;    // 4096*768 bf16
  float*  rt     = (float*)wp;   wp += 12582912;   // 4096*768

  f2b_kernel<<<dim3(2048), 256, 0, stream>>>(centers, cen_bf, 786432);
  f2b_kernel<<<dim3(2048), 256, 0, stream>>>(allemb,  all_bf, 1572864);
  f2b_kernel<<<dim3(576),  256, 0, stream>>>(Wq, Wq_bf, 147456);
  f2b_kernel<<<dim3(1152), 256, 0, stream>>>(Wk, Wk_bf, 294912);
  f2b_kernel<<<dim3(1152), 256, 0, stream>>>(Wv, Wv_bf, 294912);
  f2b_kernel<<<dim3(576),  256, 0, stream>>>(Wa, Wa_bf, 147456);

  fold_q<<<dim3(36, 3), 256, 0, stream>>>(Wq_bf, bq, ratt, pri, Wqp, bqp);
  fold_v<<<dim3(72, 3), 256, 0, stream>>>(Wv_bf, bv, rmsg, Wvp, bvp);

  proj_mfmaB<2304, 0, 0, 0>      <<<dim3(18, 32), 256, 0, stream>>>(cen_bf, Wqp, bqp, qeb);
  proj_mfmaB<768, 768*768, 768, 32><<<dim3(6, 64), 256, 0, stream>>>(all_bf, Wk_bf, bk, kb);
  msg_projT<<<dim3(18, 64), 256, 0, stream>>>(all_bf, Wvp, bvp, msgbT);

  mask_kernel<<<dim3(64), 256, 0, stream>>>(ids, pre, back, click, msk64);
  scores_fused<<<dim3(12, 64), 256, 0, stream>>>(qeb, kb, msk64, P);
  pv_mfma<<<dim3(12, 64), 256, 0, stream>>>(P, msgbT, neighb);

  proj_mfmaF<<<dim3(6, 32), 256, 0, stream>>>(neighb, Wa_bf, ba, rt);
  ln_kernel<<<dim3(1024), 256, 0, stream>>>(rt, centers, skip, gam, bet, out);
}

// Round 6
// 325.110 us; speedup vs baseline: 2.3564x; 1.1461x over previous
//
#include <hip/hip_runtime.h>
#include <cmath>

#define NEGV -1e10f

typedef __bf16 bf16_t;
typedef bf16_t bf16x8 __attribute__((ext_vector_type(8)));
typedef bf16_t bf16x4 __attribute__((ext_vector_type(4)));
typedef float f32x4 __attribute__((ext_vector_type(4)));

typedef const __attribute__((address_space(1))) void* gas1p;
typedef __attribute__((address_space(3))) void* las3p;

// ---------- fused fp32 -> bf16 casts for all 6 tensors, one launch ----------
__global__ __launch_bounds__(256)
void f2b6_kernel(const float* __restrict__ s0, bf16_t* __restrict__ d0,
                 const float* __restrict__ s1, bf16_t* __restrict__ d1,
                 const float* __restrict__ s2, bf16_t* __restrict__ d2,
                 const float* __restrict__ s3, bf16_t* __restrict__ d3,
                 const float* __restrict__ s4, bf16_t* __restrict__ d4,
                 const float* __restrict__ s5, bf16_t* __restrict__ d5) {
  const int N0=786432, N1=1572864, N2=147456, N3=294912, N4=294912, N5=147456;
  const int T = N0+N1+N2+N3+N4+N5;
  int i = blockIdx.x * 256 + threadIdx.x;
  const int stride = gridDim.x * 256;
  for (; i < T; i += stride) {
    const float* s; bf16_t* d; int j = i;
    if (j < N0) { s = s0; d = d0; }
    else { j -= N0; if (j < N1) { s = s1; d = d1; }
    else { j -= N1; if (j < N2) { s = s2; d = d2; }
    else { j -= N2; if (j < N3) { s = s3; d = d3; }
    else { j -= N3; if (j < N4) { s = s4; d = d4; }
    else { j -= N4; s = s5; d = d5; } } } } }
    float4 v = *(const float4*)(s + (size_t)j * 4);
    bf16x4 o = { (bf16_t)v.x, (bf16_t)v.y, (bf16_t)v.z, (bf16_t)v.w };
    *(bf16x4*)(d + (size_t)j * 4) = o;
  }
}

// ---------- fold ra (and pri/sqrt_dk) into Wq ----------
__global__ __launch_bounds__(256)
void fold_q(const bf16_t* __restrict__ Wqb, const float* __restrict__ bq,
            const float* __restrict__ ratt, const float* __restrict__ pri,
            bf16_t* __restrict__ Wqp, float* __restrict__ bqp) {
  const int eh = blockIdx.x; const int e = eh / 12, h = eh - e*12;
  const int re = (e==0) ? 0 : (e==1 ? 4 : 5);
  const float scale = pri[re*12 + h] * 0.125f;
  const int c0 = blockIdx.y * 256;
  __shared__ float raS[64][64];
  __shared__ bf16_t WS[64][256];
  const int tid = threadIdx.x;
  for (int i = 0; i < 16; ++i) {
    int idx = i*256 + tid;
    raS[idx>>6][idx&63] = ratt[((size_t)(re*12+h)*64 + (idx>>6))*64 + (idx&63)];
  }
  for (int i = 0; i < 8; ++i) {
    int idx = i*256 + tid; int f = idx>>5, c8 = (idx&31)*8;
    *(bf16x8*)&WS[f][c8] = *(const bf16x8*)(Wqb + (size_t)(h*64+f)*768 + c0 + c8);
  }
  __syncthreads();
  const int c = tid;
  for (int d = 0; d < 64; ++d) {
    float acc = 0.0f;
    for (int f = 0; f < 64; ++f) acc += raS[d][f] * (float)WS[f][c];
    Wqp[((size_t)(e*12+h)*64 + d)*768 + c0 + c] = (bf16_t)(scale * acc);
  }
  if (blockIdx.y == 0 && tid < 64) {
    float acc = 0.0f;
    for (int f = 0; f < 64; ++f) acc += raS[tid][f] * bq[h*64+f];
    bqp[(e*12+h)*64 + tid] = scale * acc;
  }
}

// ---------- MFMA GEMM, bf16 out: Y[M,NCOLS] = X[M,768] @ W[s-slice][768]^T + bias ----------
template<int NCOLS, int WSTRIDE, int BSTRIDE, int MHALF>
__global__ __launch_bounds__(256)
void proj_mfmaB(const bf16_t* __restrict__ X, const bf16_t* __restrict__ W,
                const float* __restrict__ bias, bf16_t* __restrict__ Y) {
  __shared__ bf16_t As[128 * 32];
  __shared__ bf16_t Bs[128 * 32];
  const int bn = blockIdx.x, bm = blockIdx.y;
  const int s = (MHALF && bm >= MHALF) ? 1 : 0;
  const int row0 = bm * 128, col0 = bn * 128;
  const int tid = threadIdx.x, wave = tid >> 6, lane = tid & 63;
  const int wr = wave >> 1, wc = wave & 1;
  f32x4 acc[4][4] = {};
  const int arow = wr * 64 + (lane & 15);
  const int bcol = wc * 64 + (lane & 15);
  const int koff = (lane >> 4) * 8;
  const bf16_t* Wb = W + (size_t)s * WSTRIDE;
  for (int k0 = 0; k0 < 768; k0 += 32) {
    __syncthreads();
    #pragma unroll
    for (int i = 0; i < 2; ++i) {
      int c = i * 256 + tid; int r = c >> 2; int c8 = (c & 3) * 8;
      __builtin_amdgcn_global_load_lds((gas1p)(X  + (size_t)(row0 + r) * 768 + k0 + c8),
                                       (las3p)(As + c * 8), 16, 0, 0);
      __builtin_amdgcn_global_load_lds((gas1p)(Wb + (size_t)(col0 + r) * 768 + k0 + c8),
                                       (las3p)(Bs + c * 8), 16, 0, 0);
    }
    __syncthreads();
    bf16x8 af[4], bfr[4];
    #pragma unroll
    for (int m = 0; m < 4; ++m) af[m]  = *(const bf16x8*)(As + (arow + m * 16) * 32 + koff);
    #pragma unroll
    for (int n = 0; n < 4; ++n) bfr[n] = *(const bf16x8*)(Bs + (bcol + n * 16) * 32 + koff);
    #pragma unroll
    for (int m = 0; m < 4; ++m)
      #pragma unroll
      for (int n = 0; n < 4; ++n)
        acc[m][n] = __builtin_amdgcn_mfma_f32_16x16x32_bf16(af[m], bfr[n], acc[m][n], 0, 0, 0);
  }
  const int ocol0 = col0 + wc * 64 + (lane & 15);
  const int orow0 = row0 + wr * 64 + (lane >> 4) * 4;
  #pragma unroll
  for (int n = 0; n < 4; ++n) {
    const int col = ocol0 + n * 16;
    const float bvl = bias[s * BSTRIDE + col];
    #pragma unroll
    for (int m = 0; m < 4; ++m)
      #pragma unroll
      for (int r = 0; r < 4; ++r)
        Y[(size_t)(orow0 + m * 16 + r) * NCOLS + col] = (bf16_t)(acc[m][n][r] + bvl);
  }
}

// ---------- MFMA GEMM, fp32 out (retype) ----------
__global__ __launch_bounds__(256)
void proj_mfmaF(const bf16_t* __restrict__ X, const bf16_t* __restrict__ W,
                const float* __restrict__ bias, float* __restrict__ Y) {
  __shared__ bf16_t As[128 * 32];
  __shared__ bf16_t Bs[128 * 32];
  const int bn = blockIdx.x, bm = blockIdx.y;
  const int row0 = bm * 128, col0 = bn * 128;
  const int tid = threadIdx.x, wave = tid >> 6, lane = tid & 63;
  const int wr = wave >> 1, wc = wave & 1;
  f32x4 acc[4][4] = {};
  const int arow = wr * 64 + (lane & 15);
  const int bcol = wc * 64 + (lane & 15);
  const int koff = (lane >> 4) * 8;
  for (int k0 = 0; k0 < 768; k0 += 32) {
    __syncthreads();
    #pragma unroll
    for (int i = 0; i < 2; ++i) {
      int c = i * 256 + tid; int r = c >> 2; int c8 = (c & 3) * 8;
      __builtin_amdgcn_global_load_lds((gas1p)(X + (size_t)(row0 + r) * 768 + k0 + c8),
                                       (las3p)(As + c * 8), 16, 0, 0);
      __builtin_amdgcn_global_load_lds((gas1p)(W + (size_t)(col0 + r) * 768 + k0 + c8),
                                       (las3p)(Bs + c * 8), 16, 0, 0);
    }
    __syncthreads();
    bf16x8 af[4], bfr[4];
    #pragma unroll
    for (int m = 0; m < 4; ++m) af[m]  = *(const bf16x8*)(As + (arow + m * 16) * 32 + koff);
    #pragma unroll
    for (int n = 0; n < 4; ++n) bfr[n] = *(const bf16x8*)(Bs + (bcol + n * 16) * 32 + koff);
    #pragma unroll
    for (int m = 0; m < 4; ++m)
      #pragma unroll
      for (int n = 0; n < 4; ++n)
        acc[m][n] = __builtin_amdgcn_mfma_f32_16x16x32_bf16(af[m], bfr[n], acc[m][n], 0, 0, 0);
  }
  const int ocol0 = col0 + wc * 64 + (lane & 15);
  const int orow0 = row0 + wr * 64 + (lane >> 4) * 4;
  #pragma unroll
  for (int n = 0; n < 4; ++n) {
    const int col = ocol0 + n * 16;
    const float bvl = bias[col];
    #pragma unroll
    for (int m = 0; m < 4; ++m)
      #pragma unroll
      for (int r = 0; r < 4; ++r)
        Y[(size_t)(orow0 + m * 16 + r) * 768 + col] = acc[m][n][r] + bvl;
  }
}

// ---------- projection with TRANSPOSED output: YT[col][token], token-major 8192 ----------
template<int WSTRIDE, int BSTRIDE>
__global__ __launch_bounds__(256)
void projT(const bf16_t* __restrict__ X, const bf16_t* __restrict__ W,
           const float* __restrict__ bias, bf16_t* __restrict__ YT) {
  __shared__ bf16_t As[128 * 32];
  __shared__ bf16_t Bs[128 * 32];
  __shared__ char tl[128 * 256];   // [col][token] bf16, byte=(c*256+t*2)^((c&7)<<4)
  const int bn = blockIdx.x, bm = blockIdx.y;
  const int s = (bm >= 32) ? 1 : 0;
  const int row0 = bm * 128, col0 = bn * 128;
  const int tid = threadIdx.x, wave = tid >> 6, lane = tid & 63;
  const int wr = wave >> 1, wc = wave & 1;
  f32x4 acc[4][4] = {};
  const int arow = wr * 64 + (lane & 15);
  const int bcol = wc * 64 + (lane & 15);
  const int koff = (lane >> 4) * 8;
  const bf16_t* Wb = W + (size_t)s * WSTRIDE;
  for (int k0 = 0; k0 < 768; k0 += 32) {
    __syncthreads();
    #pragma unroll
    for (int i = 0; i < 2; ++i) {
      int c = i * 256 + tid; int r = c >> 2; int c8 = (c & 3) * 8;
      __builtin_amdgcn_global_load_lds((gas1p)(X  + (size_t)(row0 + r) * 768 + k0 + c8),
                                       (las3p)(As + c * 8), 16, 0, 0);
      __builtin_amdgcn_global_load_lds((gas1p)(Wb + (size_t)(col0 + r) * 768 + k0 + c8),
                                       (las3p)(Bs + c * 8), 16, 0, 0);
    }
    __syncthreads();
    bf16x8 af[4], bfr[4];
    #pragma unroll
    for (int m = 0; m < 4; ++m) af[m]  = *(const bf16x8*)(As + (arow + m * 16) * 32 + koff);
    #pragma unroll
    for (int n = 0; n < 4; ++n) bfr[n] = *(const bf16x8*)(Bs + (bcol + n * 16) * 32 + koff);
    #pragma unroll
    for (int m = 0; m < 4; ++m)
      #pragma unroll
      for (int n = 0; n < 4; ++n)
        acc[m][n] = __builtin_amdgcn_mfma_f32_16x16x32_bf16(af[m], bfr[n], acc[m][n], 0, 0, 0);
  }
  __syncthreads();
  #pragma unroll
  for (int n = 0; n < 4; ++n) {
    const int cl = wc * 64 + n * 16 + (lane & 15);
    const float bvl = bias[s * BSTRIDE + col0 + cl];
    #pragma unroll
    for (int m = 0; m < 4; ++m)
      #pragma unroll
      for (int r = 0; r < 4; ++r) {
        const int rl = wr * 64 + m * 16 + (lane >> 4) * 4 + r;
        *(bf16_t*)(tl + ((cl * 256 + rl * 2) ^ ((cl & 7) << 4))) = (bf16_t)(acc[m][n][r] + bvl);
      }
  }
  __syncthreads();
  for (int i = 0; i < 8; ++i) {
    int idx = i * 256 + tid; int c = idx >> 4; int t0 = (idx & 15) * 8;
    bf16x8 v = *(const bf16x8*)(tl + ((c * 256 + t0 * 2) ^ ((c & 7) << 4)));
    *(bf16x8*)(YT + (size_t)(col0 + c) * 8192 + row0 + t0) = v;
  }
}

// ---------- mask closure -> packed 64-bit rowmasks ----------
__global__ __launch_bounds__(256)
void mask_kernel(const int* __restrict__ ids, const float* __restrict__ pre,
                 const float* __restrict__ back, const float* __restrict__ click,
                 unsigned long long* __restrict__ msk64) {
  const int b = blockIdx.x, tid = threadIdx.x;
  __shared__ float pm[64][68], bmm[64][68], cm[64][68];
  __shared__ unsigned long long sbits[64];
  __shared__ unsigned long long colbits[384];
  __shared__ int sid[64];
  __shared__ unsigned char srep[64];
  for (int r = 0; r < 4; ++r) {
    int idx = r*256 + tid; int row = idx >> 4; int c4 = (idx & 15) * 4;
    *(float4*)&pm[row][c4]  = *(const float4*)(pre   + (size_t)b*4096 + row*64 + c4);
    *(float4*)&bmm[row][c4] = *(const float4*)(back  + (size_t)b*4096 + row*64 + c4);
    *(float4*)&cm[row][c4]  = *(const float4*)(click + (size_t)b*4096 + row*64 + c4);
  }
  if (tid < 64) sid[tid] = ids[b*64 + tid];
  __syncthreads();
  if (tid < 64) {
    int myid = sid[tid];
    unsigned long long bits = 0ull; int rep = 0;
    for (int l = 0; l < 64; ++l) {
      bool eq = (sid[l] == myid);
      bits |= ((unsigned long long)eq) << l;
      rep |= (eq && (l < tid)) ? 1 : 0;
    }
    sbits[tid] = bits; srep[tid] = (unsigned char)rep;
  }
  for (int j = tid; j < 384; j += 256) {
    int e = j >> 7, t = j & 127;
    unsigned long long cb = 0ull;
    if (e == 0) {
      if (t >= 64) { int tt = t - 64; for (int l = 0; l < 64; ++l) cb |= ((unsigned long long)(cm[l][tt] > 0.0f)) << l; }
    } else if (e == 1) {
      if (t < 64) { for (int l = 0; l < 64; ++l) cb |= ((unsigned long long)(bmm[l][t] > 0.0f)) << l; }
    } else {
      if (t < 64) { for (int l = 0; l < 64; ++l) cb |= ((unsigned long long)(pm[l][t] > 0.0f)) << l; }
    }
    colbits[j] = cb;
  }
  __syncthreads();
  for (int idx = tid; idx < 384; idx += 256) {
    int l = idx / 6, w = idx - l*6;
    unsigned long long r = 0ull;
    if (!srep[l]) {
      unsigned long long sb = sbits[l];
      const int base = w*64;
      for (int jj = 0; jj < 64; ++jj)
        r |= (unsigned long long)((sb & colbits[base + jj]) != 0ull) << jj;
    }
    msk64[((size_t)(b*64) + l)*6 + w] = r;
  }
}

// ---------- fused scores + masked softmax -> P bf16 [hb*64+l][384] (te' = e*128 + t) ----------
__global__ __launch_bounds__(256)
void scores_fused(const bf16_t* __restrict__ qeb, const bf16_t* __restrict__ kb,
                  const unsigned long long* __restrict__ msk64, bf16_t* __restrict__ P) {
  const int h = blockIdx.x, b = blockIdx.y;
  __shared__ char kls[128 * 128];   // K[t][d] bf16, byte=(t*128+d*2)^((t&7)<<4)
  const int tid = threadIdx.x, wave = tid >> 6, lane = tid & 63;
  for (int i = 0; i < 4; ++i) {
    int idx = i*256 + tid;
    int t = idx >> 3, c8 = (idx & 7) * 8;
    int srow = (t >> 6)*4096 + b*64 + (t & 63);
    bf16x8 v = *(const bf16x8*)(kb + (size_t)srow*768 + h*64 + c8);
    *(bf16x8*)(kls + ((t*128 + c8*2) ^ ((t & 7) << 4))) = v;
  }
  const int band = wave * 16;
  bf16x8 af[3][2];
  #pragma unroll
  for (int e = 0; e < 3; ++e)
    #pragma unroll
    for (int ks = 0; ks < 2; ++ks)
      af[e][ks] = *(const bf16x8*)(qeb + (size_t)(b*64 + band + (lane & 15))*2304
                                   + (e*12 + h)*64 + ks*32 + (lane >> 4)*8);
  __syncthreads();
  f32x4 acc[3][8] = {};
  #pragma unroll
  for (int ks = 0; ks < 2; ++ks) {
    bf16x8 bfr[8];
    #pragma unroll
    for (int n = 0; n < 8; ++n) {
      int t = n*16 + (lane & 15);
      bfr[n] = *(const bf16x8*)(kls + ((t*128 + (ks*32 + (lane >> 4)*8)*2) ^ ((t & 7) << 4)));
    }
    #pragma unroll
    for (int e = 0; e < 3; ++e)
      #pragma unroll
      for (int n = 0; n < 8; ++n)
        acc[e][n] = __builtin_amdgcn_mfma_f32_16x16x32_bf16(af[e][ks], bfr[n], acc[e][n], 0, 0, 0);
  }
  const int colb = lane & 15;
  float mx[4], inv[4];
  #pragma unroll
  for (int r = 0; r < 4; ++r) {
    const int l = band + (lane >> 4)*4 + r;
    const unsigned long long* mr = msk64 + (size_t)(b*64 + l)*6;
    #pragma unroll
    for (int e = 0; e < 3; ++e) {
      unsigned long long w0 = mr[e*2], w1 = mr[e*2 + 1];
      #pragma unroll
      for (int n = 0; n < 8; ++n) {
        unsigned long long w = (n < 4) ? w0 : w1;
        int bitpos = (n*16 + colb) & 63;
        if (!((w >> bitpos) & 1ull)) acc[e][n][r] = NEGV;
      }
    }
  }
  #pragma unroll
  for (int r = 0; r < 4; ++r) {
    float m = NEGV;
    #pragma unroll
    for (int e = 0; e < 3; ++e)
      #pragma unroll
      for (int n = 0; n < 8; ++n) m = fmaxf(m, acc[e][n][r]);
    #pragma unroll
    for (int off = 1; off < 16; off <<= 1) m = fmaxf(m, __shfl_xor(m, off, 64));
    mx[r] = m;
  }
  #pragma unroll
  for (int r = 0; r < 4; ++r) {
    float s = 0.0f;
    #pragma unroll
    for (int e = 0; e < 3; ++e)
      #pragma unroll
      for (int n = 0; n < 8; ++n) {
        float v = __expf(acc[e][n][r] - mx[r]);
        acc[e][n][r] = v; s += v;
      }
    #pragma unroll
    for (int off = 1; off < 16; off <<= 1) s += __shfl_xor(s, off, 64);
    inv[r] = (mx[r] < -5e9f) ? 0.0f : 1.0f / s;
  }
  const size_t prow = ((size_t)(h*64 + b))*64;
  #pragma unroll
  for (int e = 0; e < 3; ++e)
    #pragma unroll
    for (int n = 0; n < 8; ++n)
      #pragma unroll
      for (int r = 0; r < 4; ++r) {
        int l = band + (lane >> 4)*4 + r;
        P[(prow + l)*384 + e*128 + n*16 + colb] = (bf16_t)(acc[e][n][r] * inv[r]);
      }
}

// ---------- PV v2: U_e = P_e @ V^T ; accN += U_e @ rm[e,h] ; gelu -> bf16 neigh ----------
__global__ __launch_bounds__(256)
void pv2_kernel(const bf16_t* __restrict__ P, const bf16_t* __restrict__ vT,
                const float* __restrict__ rmsg, bf16_t* __restrict__ neigh) {
  const int h = blockIdx.x, b = blockIdx.y;
  __shared__ char vls[64 * 256];        // V^T[f][t] bf16, byte=(f*256+t*2)^((f&7)<<4)
  __shared__ char pls[64 * 256];        // P_e[l][t]  bf16, same swizzle
  __shared__ char rmls[3][64 * 128];    // rm^T[dout][fv] bf16, byte=(d*128+f*2)^((d&7)<<4)
  __shared__ char us[64 * 128];         // U[l][fv] bf16, same swizzle
  const int tid = threadIdx.x, wave = tid >> 6, lane = tid & 63;
  const int band = wave * 16;
  // stage V^T rows f=0..63, cols t = s*64+tt (from vT[768][8192])
  for (int i = 0; i < 4; ++i) {
    int idx = i*256 + tid;              // 1024 chunks of 8 bf16
    int f = idx >> 4, t0 = (idx & 15) * 8;
    int s = t0 >> 6, tt0 = t0 & 63;
    bf16x8 v = *(const bf16x8*)(vT + (size_t)(h*64 + f)*8192 + s*4096 + b*64 + tt0);
    *(bf16x8*)(vls + ((f*256 + t0*2) ^ ((f & 7) << 4))) = v;
  }
  // stage rm^T (cast fp32->bf16, transposed): rmls[e][dout][fv] = rmsg[re,h,fv,dout]
  for (int i = 0; i < 48; ++i) {
    int idx = i*256 + tid;              // 12288
    int e = idx >> 12, rem = idx & 4095, fv = rem >> 6, dout = rem & 63;
    int re = (e==0) ? 0 : (e==1 ? 4 : 5);
    float x = rmsg[((size_t)(re*12 + h)*64 + fv)*64 + dout];
    *(bf16_t*)(rmls[e] + ((dout*128 + fv*2) ^ ((dout & 7) << 4))) = (bf16_t)x;
  }
  f32x4 accN[4] = {};
  const size_t prow = ((size_t)(h*64 + b))*64;
  for (int e = 0; e < 3; ++e) {
    __syncthreads();   // e=0: vls/rmls ready; e>0: prev gemm2's us reads done before pls/us reuse
    for (int i = 0; i < 4; ++i) {
      int idx = i*256 + tid;
      int l = idx >> 4, t0 = (idx & 15) * 8;
      bf16x8 v = *(const bf16x8*)(P + (prow + l)*384 + e*128 + t0);
      *(bf16x8*)(pls + ((l*256 + t0*2) ^ ((l & 7) << 4))) = v;
    }
    __syncthreads();
    // gemm1: U[l][f] = sum_t P_e[l][t] * V[t][f]
    f32x4 accU[4] = {};
    #pragma unroll
    for (int ks = 0; ks < 4; ++ks) {
      const int kb2 = (ks*32 + (lane >> 4)*8) * 2;
      const int la = band + (lane & 15);
      bf16x8 a = *(const bf16x8*)(pls + ((la*256 + kb2) ^ ((la & 7) << 4)));
      #pragma unroll
      for (int n = 0; n < 4; ++n) {
        int f = n*16 + (lane & 15);
        bf16x8 bv = *(const bf16x8*)(vls + ((f*256 + kb2) ^ ((f & 7) << 4)));
        accU[n] = __builtin_amdgcn_mfma_f32_16x16x32_bf16(a, bv, accU[n], 0, 0, 0);
      }
    }
    #pragma unroll
    for (int n = 0; n < 4; ++n)
      #pragma unroll
      for (int r = 0; r < 4; ++r) {
        int l = band + (lane >> 4)*4 + r;
        int f = n*16 + (lane & 15);
        *(bf16_t*)(us + ((l*128 + f*2) ^ ((l & 7) << 4))) = (bf16_t)accU[n][r];
      }
    __syncthreads();
    // gemm2: accN[l][dout] += sum_f U[l][f] * rm[f][dout]
    #pragma unroll
    for (int ks = 0; ks < 2; ++ks) {
      const int kb2 = (ks*32 + (lane >> 4)*8) * 2;
      const int la = band + (lane & 15);
      bf16x8 a2 = *(const bf16x8*)(us + ((la*128 + kb2) ^ ((la & 7) << 4)));
      #pragma unroll
      for (int n = 0; n < 4; ++n) {
        int d = n*16 + (lane & 15);
        bf16x8 brm = *(const bf16x8*)(rmls[e] + ((d*128 + kb2) ^ ((d & 7) << 4)));
        accN[n] = __builtin_amdgcn_mfma_f32_16x16x32_bf16(a2, brm, accN[n], 0, 0, 0);
      }
    }
  }
  #pragma unroll
  for (int n = 0; n < 4; ++n)
    #pragma unroll
    for (int r = 0; r < 4; ++r) {
      int l = band + (lane >> 4)*4 + r;
      int d = n*16 + (lane & 15);
      float x = accN[n][r];
      float g = 0.5f * x * (1.0f + erff(x * 0.70710678118654752f));
      neigh[(size_t)(b*64 + l)*768 + h*64 + d] = (bf16_t)g;
    }
}

// ---------- skip-mix + LayerNorm, one wave per row ----------
__global__ __launch_bounds__(256)
void ln_kernel(const float* __restrict__ rt, const float* __restrict__ centers,
               const float* __restrict__ skip, const float* __restrict__ gamma,
               const float* __restrict__ beta, float* __restrict__ out) {
  const int row  = blockIdx.x*4 + (threadIdx.x >> 6);
  const int lane = threadIdx.x & 63;
  const float alpha = 1.0f / (1.0f + expf(-skip[0]));
  const float* rp = rt + (size_t)row*768;
  const float* cp = centers + (size_t)row*768;
  float r[12];
  float sum = 0.0f;
  #pragma unroll
  for (int c = 0; c < 12; ++c) {
    int j = lane + 64*c;
    float x = alpha*rp[j] + (1.0f - alpha)*cp[j];
    r[c] = x; sum += x;
  }
  #pragma unroll
  for (int off = 1; off < 64; off <<= 1) sum += __shfl_xor(sum, off, 64);
  float mean = sum * (1.0f/768.0f);
  float vsum = 0.0f;
  #pragma unroll
  for (int c = 0; c < 12; ++c) { float d = r[c] - mean; vsum += d*d; }
  #pragma unroll
  for (int off = 1; off < 64; off <<= 1) vsum += __shfl_xor(vsum, off, 64);
  float inv = 1.0f / sqrtf(vsum * (1.0f/768.0f) + 1e-5f);
  #pragma unroll
  for (int c = 0; c < 12; ++c) {
    int j = lane + 64*c;
    out[(size_t)row*768 + j] = gamma[j]*(r[c] - mean)*inv + beta[j];
  }
}

extern "C" void kernel_launch(void* const* d_in, const int* in_sizes, int n_in,
                              void* d_out, int out_size, void* d_ws, size_t ws_size,
                              hipStream_t stream) {
  const int*   ids     = (const int*)  d_in[0];
  const float* centers = (const float*)d_in[1];
  const float* allemb  = (const float*)d_in[2];
  const float* pre     = (const float*)d_in[3];
  const float* back    = (const float*)d_in[4];
  const float* click   = (const float*)d_in[5];
  const float* Wq = (const float*)d_in[7];
  const float* bq = (const float*)d_in[8];
  const float* Wk = (const float*)d_in[9];
  const float* bk = (const float*)d_in[10];
  const float* Wv = (const float*)d_in[11];
  const float* bv = (const float*)d_in[12];
  const float* Wa = (const float*)d_in[13];
  const float* ba = (const float*)d_in[14];
  const float* pri  = (const float*)d_in[15];
  const float* ratt = (const float*)d_in[16];
  const float* rmsg = (const float*)d_in[17];
  const float* skip = (const float*)d_in[18];
  const float* gam  = (const float*)d_in[19];
  const float* bet  = (const float*)d_in[20];
  float* out = (float*)d_out;

  char* wp = (char*)d_ws;
  bf16_t* cen_bf = (bf16_t*)wp;  wp += 6291456;    // 4096*768
  bf16_t* all_bf = (bf16_t*)wp;  wp += 12582912;   // 8192*768
  bf16_t* Wq_bf  = (bf16_t*)wp;  wp += 1179648;    // 768*768
  bf16_t* Wk_bf  = (bf16_t*)wp;  wp += 2359296;    // 1536*768
  bf16_t* Wv_bf  = (bf16_t*)wp;  wp += 2359296;    // 1536*768
  bf16_t* Wa_bf  = (bf16_t*)wp;  wp += 1179648;    // 768*768 (type-0 slice)
  bf16_t* Wqp    = (bf16_t*)wp;  wp += 3538944;    // 2304*768
  float*  bqp    = (float*)wp;   wp += 9216;       // 2304
  bf16_t* qeb    = (bf16_t*)wp;  wp += 18874368;   // 4096*2304
  bf16_t* kb     = (bf16_t*)wp;  wp += 12582912;   // 8192*768
  bf16_t* vTb    = (bf16_t*)wp;  wp += 12582912;   // 768*8192
  unsigned long long* msk64 = (unsigned long long*)wp; wp += 196608;  // 4096*6
  bf16_t* P      = (bf16_t*)wp;  wp += 37748736;   // 768*64*384
  bf16_t* neighb = (bf16_t*)wp;  wp += 6291456;    // 4096*768 bf16
  float*  rt     = (float*)wp;   wp += 12582912;   // 4096*768

  f2b6_kernel<<<dim3(2048), 256, 0, stream>>>(centers, cen_bf, allemb, all_bf,
                                              Wq, Wq_bf, Wk, Wk_bf, Wv, Wv_bf, Wa, Wa_bf);

  fold_q<<<dim3(36, 3), 256, 0, stream>>>(Wq_bf, bq, ratt, pri, Wqp, bqp);

  proj_mfmaB<2304, 0, 0, 0>        <<<dim3(18, 32), 256, 0, stream>>>(cen_bf, Wqp, bqp, qeb);
  proj_mfmaB<768, 768*768, 768, 32><<<dim3(6, 64), 256, 0, stream>>>(all_bf, Wk_bf, bk, kb);
  projT<768*768, 768>              <<<dim3(6, 64), 256, 0, stream>>>(all_bf, Wv_bf, bv, vTb);

  mask_kernel<<<dim3(64), 256, 0, stream>>>(ids, pre, back, click, msk64);
  scores_fused<<<dim3(12, 64), 256, 0, stream>>>(qeb, kb, msk64, P);
  pv2_kernel<<<dim3(12, 64), 256, 0, stream>>>(P, vTb, rmsg, neighb);

  proj_mfmaF<<<dim3(6, 32), 256, 0, stream>>>(neighb, Wa_bf, ba, rt);
  ln_kernel<<<dim3(1024), 256, 0, stream>>>(rt, centers, skip, gam, bet, out);
}

// Round 7
// 271.041 us; speedup vs baseline: 2.8264x; 1.1995x over previous
//
#include <hip/hip_runtime.h>
#include <cmath>

#define NEGV -1e10f

typedef __bf16 bf16_t;
typedef bf16_t bf16x8 __attribute__((ext_vector_type(8)));
typedef bf16_t bf16x4 __attribute__((ext_vector_type(4)));
typedef float f32x4 __attribute__((ext_vector_type(4)));

typedef const __attribute__((address_space(1))) void* gas1p;
typedef __attribute__((address_space(3))) void* las3p;

// ---------- fused fp32 -> bf16 casts for all 6 tensors, one launch ----------
__global__ __launch_bounds__(256)
void f2b6_kernel(const float* __restrict__ s0, bf16_t* __restrict__ d0,
                 const float* __restrict__ s1, bf16_t* __restrict__ d1,
                 const float* __restrict__ s2, bf16_t* __restrict__ d2,
                 const float* __restrict__ s3, bf16_t* __restrict__ d3,
                 const float* __restrict__ s4, bf16_t* __restrict__ d4,
                 const float* __restrict__ s5, bf16_t* __restrict__ d5) {
  const int N0=786432, N1=1572864, N2=147456, N3=294912, N4=294912, N5=147456;
  const int T = N0+N1+N2+N3+N4+N5;
  int i = blockIdx.x * 256 + threadIdx.x;
  const int stride = gridDim.x * 256;
  for (; i < T; i += stride) {
    const float* s; bf16_t* d; int j = i;
    if (j < N0) { s = s0; d = d0; }
    else { j -= N0; if (j < N1) { s = s1; d = d1; }
    else { j -= N1; if (j < N2) { s = s2; d = d2; }
    else { j -= N2; if (j < N3) { s = s3; d = d3; }
    else { j -= N3; if (j < N4) { s = s4; d = d4; }
    else { j -= N4; s = s5; d = d5; } } } } }
    float4 v = *(const float4*)(s + (size_t)j * 4);
    bf16x4 o = { (bf16_t)v.x, (bf16_t)v.y, (bf16_t)v.z, (bf16_t)v.w };
    *(bf16x4*)(d + (size_t)j * 4) = o;
  }
}

// ---------- rm^T precompute: rmT[(e,h,d)][f] = rm[re,h,f,d] as bf16 ----------
__global__ __launch_bounds__(256)
void fold_rm(const float* __restrict__ rmsg, bf16_t* __restrict__ rmT) {
  const int eh = blockIdx.x;
  const int e = eh / 12, h = eh - e*12;
  const int re = (e==0) ? 0 : (e==1 ? 4 : 5);
  const int tid = threadIdx.x;
  for (int i = 0; i < 16; ++i) {
    int idx = i*256 + tid;             // 4096
    int d = idx >> 6, f = idx & 63;
    rmT[((size_t)(e*12 + h)*64 + d)*64 + f] =
        (bf16_t)rmsg[((size_t)(re*12 + h)*64 + f)*64 + d];
  }
}

// ---------- MFMA GEMM, bf16 out: Y[M,NCOLS] = X[M,768] @ W[s-slice][768]^T + bias ----------
template<int NCOLS, int WSTRIDE, int BSTRIDE, int MHALF>
__global__ __launch_bounds__(256)
void proj_mfmaB(const bf16_t* __restrict__ X, const bf16_t* __restrict__ W,
                const float* __restrict__ bias, bf16_t* __restrict__ Y) {
  __shared__ bf16_t As[128 * 32];
  __shared__ bf16_t Bs[128 * 32];
  const int bn = blockIdx.x, bm = blockIdx.y;
  const int s = (MHALF && bm >= MHALF) ? 1 : 0;
  const int row0 = bm * 128, col0 = bn * 128;
  const int tid = threadIdx.x, wave = tid >> 6, lane = tid & 63;
  const int wr = wave >> 1, wc = wave & 1;
  f32x4 acc[4][4] = {};
  const int arow = wr * 64 + (lane & 15);
  const int bcol = wc * 64 + (lane & 15);
  const int koff = (lane >> 4) * 8;
  const bf16_t* Wb = W + (size_t)s * WSTRIDE;
  for (int k0 = 0; k0 < 768; k0 += 32) {
    __syncthreads();
    #pragma unroll
    for (int i = 0; i < 2; ++i) {
      int c = i * 256 + tid; int r = c >> 2; int c8 = (c & 3) * 8;
      __builtin_amdgcn_global_load_lds((gas1p)(X  + (size_t)(row0 + r) * 768 + k0 + c8),
                                       (las3p)(As + c * 8), 16, 0, 0);
      __builtin_amdgcn_global_load_lds((gas1p)(Wb + (size_t)(col0 + r) * 768 + k0 + c8),
                                       (las3p)(Bs + c * 8), 16, 0, 0);
    }
    __syncthreads();
    bf16x8 af[4], bfr[4];
    #pragma unroll
    for (int m = 0; m < 4; ++m) af[m]  = *(const bf16x8*)(As + (arow + m * 16) * 32 + koff);
    #pragma unroll
    for (int n = 0; n < 4; ++n) bfr[n] = *(const bf16x8*)(Bs + (bcol + n * 16) * 32 + koff);
    #pragma unroll
    for (int m = 0; m < 4; ++m)
      #pragma unroll
      for (int n = 0; n < 4; ++n)
        acc[m][n] = __builtin_amdgcn_mfma_f32_16x16x32_bf16(af[m], bfr[n], acc[m][n], 0, 0, 0);
  }
  const int ocol0 = col0 + wc * 64 + (lane & 15);
  const int orow0 = row0 + wr * 64 + (lane >> 4) * 4;
  #pragma unroll
  for (int n = 0; n < 4; ++n) {
    const int col = ocol0 + n * 16;
    const float bvl = bias[s * BSTRIDE + col];
    #pragma unroll
    for (int m = 0; m < 4; ++m)
      #pragma unroll
      for (int r = 0; r < 4; ++r)
        Y[(size_t)(orow0 + m * 16 + r) * NCOLS + col] = (bf16_t)(acc[m][n][r] + bvl);
  }
}

// ---------- MFMA GEMM, fp32 out (retype) ----------
__global__ __launch_bounds__(256)
void proj_mfmaF(const bf16_t* __restrict__ X, const bf16_t* __restrict__ W,
                const float* __restrict__ bias, float* __restrict__ Y) {
  __shared__ bf16_t As[128 * 32];
  __shared__ bf16_t Bs[128 * 32];
  const int bn = blockIdx.x, bm = blockIdx.y;
  const int row0 = bm * 128, col0 = bn * 128;
  const int tid = threadIdx.x, wave = tid >> 6, lane = tid & 63;
  const int wr = wave >> 1, wc = wave & 1;
  f32x4 acc[4][4] = {};
  const int arow = wr * 64 + (lane & 15);
  const int bcol = wc * 64 + (lane & 15);
  const int koff = (lane >> 4) * 8;
  for (int k0 = 0; k0 < 768; k0 += 32) {
    __syncthreads();
    #pragma unroll
    for (int i = 0; i < 2; ++i) {
      int c = i * 256 + tid; int r = c >> 2; int c8 = (c & 3) * 8;
      __builtin_amdgcn_global_load_lds((gas1p)(X + (size_t)(row0 + r) * 768 + k0 + c8),
                                       (las3p)(As + c * 8), 16, 0, 0);
      __builtin_amdgcn_global_load_lds((gas1p)(W + (size_t)(col0 + r) * 768 + k0 + c8),
                                       (las3p)(Bs + c * 8), 16, 0, 0);
    }
    __syncthreads();
    bf16x8 af[4], bfr[4];
    #pragma unroll
    for (int m = 0; m < 4; ++m) af[m]  = *(const bf16x8*)(As + (arow + m * 16) * 32 + koff);
    #pragma unroll
    for (int n = 0; n < 4; ++n) bfr[n] = *(const bf16x8*)(Bs + (bcol + n * 16) * 32 + koff);
    #pragma unroll
    for (int m = 0; m < 4; ++m)
      #pragma unroll
      for (int n = 0; n < 4; ++n)
        acc[m][n] = __builtin_amdgcn_mfma_f32_16x16x32_bf16(af[m], bfr[n], acc[m][n], 0, 0, 0);
  }
  const int ocol0 = col0 + wc * 64 + (lane & 15);
  const int orow0 = row0 + wr * 64 + (lane >> 4) * 4;
  #pragma unroll
  for (int n = 0; n < 4; ++n) {
    const int col = ocol0 + n * 16;
    const float bvl = bias[col];
    #pragma unroll
    for (int m = 0; m < 4; ++m)
      #pragma unroll
      for (int r = 0; r < 4; ++r)
        Y[(size_t)(orow0 + m * 16 + r) * 768 + col] = acc[m][n][r] + bvl;
  }
}

// ---------- projection with TRANSPOSED output: YT[col][token], token-major 8192 ----------
template<int WSTRIDE, int BSTRIDE>
__global__ __launch_bounds__(256)
void projT(const bf16_t* __restrict__ X, const bf16_t* __restrict__ W,
           const float* __restrict__ bias, bf16_t* __restrict__ YT) {
  __shared__ bf16_t As[128 * 32];
  __shared__ bf16_t Bs[128 * 32];
  __shared__ char tl[128 * 256];   // [col][token] bf16, byte=(c*256+t*2)^((c&7)<<4)
  const int bn = blockIdx.x, bm = blockIdx.y;
  const int s = (bm >= 32) ? 1 : 0;
  const int row0 = bm * 128, col0 = bn * 128;
  const int tid = threadIdx.x, wave = tid >> 6, lane = tid & 63;
  const int wr = wave >> 1, wc = wave & 1;
  f32x4 acc[4][4] = {};
  const int arow = wr * 64 + (lane & 15);
  const int bcol = wc * 64 + (lane & 15);
  const int koff = (lane >> 4) * 8;
  const bf16_t* Wb = W + (size_t)s * WSTRIDE;
  for (int k0 = 0; k0 < 768; k0 += 32) {
    __syncthreads();
    #pragma unroll
    for (int i = 0; i < 2; ++i) {
      int c = i * 256 + tid; int r = c >> 2; int c8 = (c & 3) * 8;
      __builtin_amdgcn_global_load_lds((gas1p)(X  + (size_t)(row0 + r) * 768 + k0 + c8),
                                       (las3p)(As + c * 8), 16, 0, 0);
      __builtin_amdgcn_global_load_lds((gas1p)(Wb + (size_t)(col0 + r) * 768 + k0 + c8),
                                       (las3p)(Bs + c * 8), 16, 0, 0);
    }
    __syncthreads();
    bf16x8 af[4], bfr[4];
    #pragma unroll
    for (int m = 0; m < 4; ++m) af[m]  = *(const bf16x8*)(As + (arow + m * 16) * 32 + koff);
    #pragma unroll
    for (int n = 0; n < 4; ++n) bfr[n] = *(const bf16x8*)(Bs + (bcol + n * 16) * 32 + koff);
    #pragma unroll
    for (int m = 0; m < 4; ++m)
      #pragma unroll
      for (int n = 0; n < 4; ++n)
        acc[m][n] = __builtin_amdgcn_mfma_f32_16x16x32_bf16(af[m], bfr[n], acc[m][n], 0, 0, 0);
  }
  __syncthreads();
  #pragma unroll
  for (int n = 0; n < 4; ++n) {
    const int cl = wc * 64 + n * 16 + (lane & 15);
    const float bvl = bias[s * BSTRIDE + col0 + cl];
    #pragma unroll
    for (int m = 0; m < 4; ++m)
      #pragma unroll
      for (int r = 0; r < 4; ++r) {
        const int rl = wr * 64 + m * 16 + (lane >> 4) * 4 + r;
        *(bf16_t*)(tl + ((cl * 256 + rl * 2) ^ ((cl & 7) << 4))) = (bf16_t)(acc[m][n][r] + bvl);
      }
  }
  __syncthreads();
  for (int i = 0; i < 8; ++i) {
    int idx = i * 256 + tid; int c = idx >> 4; int t0 = (idx & 15) * 8;
    bf16x8 v = *(const bf16x8*)(tl + ((c * 256 + t0 * 2) ^ ((c & 7) << 4)));
    *(bf16x8*)(YT + (size_t)(col0 + c) * 8192 + row0 + t0) = v;
  }
}

// ---------- qe transform: qeb[row][(e,h,d)] = scale * sum_f qraw[row][h*64+f] * ra[re,h,d,f] ----------
__global__ __launch_bounds__(256)
void qtrans_kernel(const bf16_t* __restrict__ qraw, const float* __restrict__ ratt,
                   const float* __restrict__ pri, bf16_t* __restrict__ qeb) {
  const int eh = blockIdx.x;           // 36
  const int e = eh / 12, h = eh - e*12;
  const int re = (e==0) ? 0 : (e==1 ? 4 : 5);
  const int row0 = blockIdx.y * 128;
  const float scale = pri[re*12 + h] * 0.125f;
  __shared__ char qls[128 * 128];      // q[l][f] bf16 swz
  __shared__ char rals[64 * 128];      // ra[d][f] bf16 swz
  const int tid = threadIdx.x, wave = tid >> 6, lane = tid & 63;
  const int colb = lane & 15;
  for (int i = 0; i < 4; ++i) {
    int idx = i*256 + tid;             // 1024
    int l = idx >> 3, f0 = (idx & 7) * 8;
    bf16x8 v = *(const bf16x8*)(qraw + (size_t)(row0 + l)*768 + h*64 + f0);
    *(bf16x8*)(qls + ((l*128 + f0*2) ^ ((l & 7) << 4))) = v;
  }
  for (int i = 0; i < 4; ++i) {
    int idx = i*256 + tid;             // 1024
    int d = idx >> 4, f0 = (idx & 15) * 4;
    float4 v = *(const float4*)(ratt + ((size_t)(re*12 + h)*64 + d)*64 + f0);
    bf16x4 o = { (bf16_t)v.x, (bf16_t)v.y, (bf16_t)v.z, (bf16_t)v.w };
    *(bf16x4*)(rals + ((d*128 + f0*2) ^ ((d & 7) << 4))) = o;
  }
  __syncthreads();
  f32x4 acc[2][4] = {};
  #pragma unroll
  for (int ks = 0; ks < 2; ++ks) {
    const int kb2 = (ks*32 + (lane >> 4)*8) * 2;
    bf16x8 bfr[4];
    #pragma unroll
    for (int n = 0; n < 4; ++n) {
      int d = n*16 + colb;
      bfr[n] = *(const bf16x8*)(rals + ((d*128 + kb2) ^ ((d & 7) << 4)));
    }
    #pragma unroll
    for (int m = 0; m < 2; ++m) {
      int l = wave*32 + m*16 + colb;
      bf16x8 a = *(const bf16x8*)(qls + ((l*128 + kb2) ^ ((l & 7) << 4)));
      #pragma unroll
      for (int n = 0; n < 4; ++n)
        acc[m][n] = __builtin_amdgcn_mfma_f32_16x16x32_bf16(a, bfr[n], acc[m][n], 0, 0, 0);
    }
  }
  #pragma unroll
  for (int m = 0; m < 2; ++m)
    #pragma unroll
    for (int n = 0; n < 4; ++n)
      #pragma unroll
      for (int r = 0; r < 4; ++r) {
        int l = wave*32 + m*16 + (lane >> 4)*4 + r;
        int d = n*16 + colb;
        qeb[(size_t)(row0 + l)*2304 + (e*12 + h)*64 + d] = (bf16_t)(scale * acc[m][n][r]);
      }
}

// ---------- mask closure -> packed 64-bit rowmasks ----------
__global__ __launch_bounds__(256)
void mask_kernel(const int* __restrict__ ids, const float* __restrict__ pre,
                 const float* __restrict__ back, const float* __restrict__ click,
                 unsigned long long* __restrict__ msk64) {
  const int b = blockIdx.x, tid = threadIdx.x;
  __shared__ float pm[64][68], bmm[64][68], cm[64][68];
  __shared__ unsigned long long sbits[64];
  __shared__ unsigned long long colbits[384];
  __shared__ int sid[64];
  __shared__ unsigned char srep[64];
  for (int r = 0; r < 4; ++r) {
    int idx = r*256 + tid; int row = idx >> 4; int c4 = (idx & 15) * 4;
    *(float4*)&pm[row][c4]  = *(const float4*)(pre   + (size_t)b*4096 + row*64 + c4);
    *(float4*)&bmm[row][c4] = *(const float4*)(back  + (size_t)b*4096 + row*64 + c4);
    *(float4*)&cm[row][c4]  = *(const float4*)(click + (size_t)b*4096 + row*64 + c4);
  }
  if (tid < 64) sid[tid] = ids[b*64 + tid];
  __syncthreads();
  if (tid < 64) {
    int myid = sid[tid];
    unsigned long long bits = 0ull; int rep = 0;
    for (int l = 0; l < 64; ++l) {
      bool eq = (sid[l] == myid);
      bits |= ((unsigned long long)eq) << l;
      rep |= (eq && (l < tid)) ? 1 : 0;
    }
    sbits[tid] = bits; srep[tid] = (unsigned char)rep;
  }
  for (int j = tid; j < 384; j += 256) {
    int e = j >> 7, t = j & 127;
    unsigned long long cb = 0ull;
    if (e == 0) {
      if (t >= 64) { int tt = t - 64; for (int l = 0; l < 64; ++l) cb |= ((unsigned long long)(cm[l][tt] > 0.0f)) << l; }
    } else if (e == 1) {
      if (t < 64) { for (int l = 0; l < 64; ++l) cb |= ((unsigned long long)(bmm[l][t] > 0.0f)) << l; }
    } else {
      if (t < 64) { for (int l = 0; l < 64; ++l) cb |= ((unsigned long long)(pm[l][t] > 0.0f)) << l; }
    }
    colbits[j] = cb;
  }
  __syncthreads();
  for (int idx = tid; idx < 384; idx += 256) {
    int l = idx / 6, w = idx - l*6;
    unsigned long long r = 0ull;
    if (!srep[l]) {
      unsigned long long sb = sbits[l];
      const int base = w*64;
      for (int jj = 0; jj < 64; ++jj)
        r |= (unsigned long long)((sb & colbits[base + jj]) != 0ull) << jj;
    }
    msk64[((size_t)(b*64) + l)*6 + w] = r;
  }
}

// ---------- fused QK^T + masked softmax + PV + rm + gelu ----------
__global__ __launch_bounds__(256, 2)
void attn_fused(const bf16_t* __restrict__ qeb, const bf16_t* __restrict__ kb,
                const bf16_t* __restrict__ vT, const bf16_t* __restrict__ rmT,
                const unsigned long long* __restrict__ msk64,
                bf16_t* __restrict__ neigh) {
  const int h = blockIdx.x, b = blockIdx.y;
  __shared__ char kls[128 * 128];      // K[t][d]    16 KB
  __shared__ char vls[64 * 256];       // V^T[f][t]  16 KB
  __shared__ char rmls[3][64 * 128];   // rm^T[d][f] 24 KB
  __shared__ char pls[64 * 256];       // P_e[l][t]  16 KB (rolling per e)
  __shared__ char us[64 * 128];        // U[l][f]     8 KB
  const int tid = threadIdx.x, wave = tid >> 6, lane = tid & 63;
  const int band = wave * 16;
  const int colb = lane & 15;
  // stage K
  for (int i = 0; i < 4; ++i) {
    int idx = i*256 + tid;
    int t = idx >> 3, c8 = (idx & 7) * 8;
    int srow = (t >> 6)*4096 + b*64 + (t & 63);
    bf16x8 v = *(const bf16x8*)(kb + (size_t)srow*768 + h*64 + c8);
    *(bf16x8*)(kls + ((t*128 + c8*2) ^ ((t & 7) << 4))) = v;
  }
  // stage V^T
  for (int i = 0; i < 4; ++i) {
    int idx = i*256 + tid;
    int f = idx >> 4, t0 = (idx & 15) * 8;
    bf16x8 v = *(const bf16x8*)(vT + (size_t)(h*64 + f)*8192 + (t0 >> 6)*4096 + b*64 + (t0 & 63));
    *(bf16x8*)(vls + ((f*256 + t0*2) ^ ((f & 7) << 4))) = v;
  }
  // stage rm (vectorized from precomputed bf16 rmT)
  for (int i = 0; i < 6; ++i) {
    int idx = i*256 + tid;
    int e = idx >> 9, rem = idx & 511, d = rem >> 3, f0 = (rem & 7) * 8;
    bf16x8 v = *(const bf16x8*)(rmT + (size_t)((e*12 + h)*64 + d)*64 + f0);
    *(bf16x8*)(rmls[e] + ((d*128 + f0*2) ^ ((d & 7) << 4))) = v;
  }
  // Q fragments
  bf16x8 af[3][2];
  #pragma unroll
  for (int e = 0; e < 3; ++e)
    #pragma unroll
    for (int ks = 0; ks < 2; ++ks)
      af[e][ks] = *(const bf16x8*)(qeb + (size_t)(b*64 + band + colb)*2304
                                   + (e*12 + h)*64 + ks*32 + (lane >> 4)*8);
  __syncthreads();
  // QK^T
  f32x4 acc[3][8] = {};
  #pragma unroll
  for (int ks = 0; ks < 2; ++ks) {
    bf16x8 bfr[8];
    #pragma unroll
    for (int n = 0; n < 8; ++n) {
      int t = n*16 + colb;
      bfr[n] = *(const bf16x8*)(kls + ((t*128 + (ks*32 + (lane >> 4)*8)*2) ^ ((t & 7) << 4)));
    }
    #pragma unroll
    for (int e = 0; e < 3; ++e)
      #pragma unroll
      for (int n = 0; n < 8; ++n)
        acc[e][n] = __builtin_amdgcn_mfma_f32_16x16x32_bf16(af[e][ks], bfr[n], acc[e][n], 0, 0, 0);
  }
  // mask
  float mx[4], inv[4];
  #pragma unroll
  for (int r = 0; r < 4; ++r) {
    const int l = band + (lane >> 4)*4 + r;
    const unsigned long long* mr = msk64 + (size_t)(b*64 + l)*6;
    #pragma unroll
    for (int e = 0; e < 3; ++e) {
      unsigned long long w0 = mr[e*2], w1 = mr[e*2 + 1];
      #pragma unroll
      for (int n = 0; n < 8; ++n) {
        unsigned long long w = (n < 4) ? w0 : w1;
        int bitpos = (n*16 + colb) & 63;
        if (!((w >> bitpos) & 1ull)) acc[e][n][r] = NEGV;
      }
    }
  }
  // softmax (per-row reduce over 16 lanes)
  #pragma unroll
  for (int r = 0; r < 4; ++r) {
    float m = NEGV;
    #pragma unroll
    for (int e = 0; e < 3; ++e)
      #pragma unroll
      for (int n = 0; n < 8; ++n) m = fmaxf(m, acc[e][n][r]);
    #pragma unroll
    for (int off = 1; off < 16; off <<= 1) m = fmaxf(m, __shfl_xor(m, off, 64));
    mx[r] = m;
  }
  #pragma unroll
  for (int r = 0; r < 4; ++r) {
    float s = 0.0f;
    #pragma unroll
    for (int e = 0; e < 3; ++e)
      #pragma unroll
      for (int n = 0; n < 8; ++n) {
        float v = __expf(acc[e][n][r] - mx[r]);
        acc[e][n][r] = v; s += v;
      }
    #pragma unroll
    for (int off = 1; off < 16; off <<= 1) s += __shfl_xor(s, off, 64);
    inv[r] = (mx[r] < -5e9f) ? 0.0f : 1.0f / s;
  }
  // PV + rm, per edge type
  f32x4 accN[4] = {};
  #pragma unroll
  for (int e = 0; e < 3; ++e) {
    // write P_e to LDS
    #pragma unroll
    for (int n = 0; n < 8; ++n)
      #pragma unroll
      for (int r = 0; r < 4; ++r) {
        int l = band + (lane >> 4)*4 + r;
        int t = n*16 + colb;
        *(bf16_t*)(pls + ((l*256 + t*2) ^ ((l & 7) << 4))) = (bf16_t)(acc[e][n][r] * inv[r]);
      }
    __syncthreads();
    // gemm1: U[l][f] = sum_t P_e[l][t] V[t][f]
    f32x4 accU[4] = {};
    #pragma unroll
    for (int ks = 0; ks < 4; ++ks) {
      const int kb2 = (ks*32 + (lane >> 4)*8) * 2;
      const int la = band + colb;
      bf16x8 a = *(const bf16x8*)(pls + ((la*256 + kb2) ^ ((la & 7) << 4)));
      #pragma unroll
      for (int n = 0; n < 4; ++n) {
        int f = n*16 + colb;
        bf16x8 bv = *(const bf16x8*)(vls + ((f*256 + kb2) ^ ((f & 7) << 4)));
        accU[n] = __builtin_amdgcn_mfma_f32_16x16x32_bf16(a, bv, accU[n], 0, 0, 0);
      }
    }
    #pragma unroll
    for (int n = 0; n < 4; ++n)
      #pragma unroll
      for (int r = 0; r < 4; ++r) {
        int l = band + (lane >> 4)*4 + r;
        int f = n*16 + colb;
        *(bf16_t*)(us + ((l*128 + f*2) ^ ((l & 7) << 4))) = (bf16_t)accU[n][r];
      }
    __syncthreads();
    // gemm2: accN[l][d] += sum_f U[l][f] rm[f][d]
    #pragma unroll
    for (int ks = 0; ks < 2; ++ks) {
      const int kb2 = (ks*32 + (lane >> 4)*8) * 2;
      const int la = band + colb;
      bf16x8 a2 = *(const bf16x8*)(us + ((la*128 + kb2) ^ ((la & 7) << 4)));
      #pragma unroll
      for (int n = 0; n < 4; ++n) {
        int d = n*16 + colb;
        bf16x8 brm = *(const bf16x8*)(rmls[e] + ((d*128 + kb2) ^ ((d & 7) << 4)));
        accN[n] = __builtin_amdgcn_mfma_f32_16x16x32_bf16(a2, brm, accN[n], 0, 0, 0);
      }
    }
  }
  #pragma unroll
  for (int n = 0; n < 4; ++n)
    #pragma unroll
    for (int r = 0; r < 4; ++r) {
      int l = band + (lane >> 4)*4 + r;
      int d = n*16 + colb;
      float x = accN[n][r];
      float g = 0.5f * x * (1.0f + erff(x * 0.70710678118654752f));
      neigh[(size_t)(b*64 + l)*768 + h*64 + d] = (bf16_t)g;
    }
}

// ---------- skip-mix + LayerNorm, one wave per row ----------
__global__ __launch_bounds__(256)
void ln_kernel(const float* __restrict__ rt, const float* __restrict__ centers,
               const float* __restrict__ skip, const float* __restrict__ gamma,
               const float* __restrict__ beta, float* __restrict__ out) {
  const int row  = blockIdx.x*4 + (threadIdx.x >> 6);
  const int lane = threadIdx.x & 63;
  const float alpha = 1.0f / (1.0f + expf(-skip[0]));
  const float* rp = rt + (size_t)row*768;
  const float* cp = centers + (size_t)row*768;
  float r[12];
  float sum = 0.0f;
  #pragma unroll
  for (int c = 0; c < 12; ++c) {
    int j = lane + 64*c;
    float x = alpha*rp[j] + (1.0f - alpha)*cp[j];
    r[c] = x; sum += x;
  }
  #pragma unroll
  for (int off = 1; off < 64; off <<= 1) sum += __shfl_xor(sum, off, 64);
  float mean = sum * (1.0f/768.0f);
  float vsum = 0.0f;
  #pragma unroll
  for (int c = 0; c < 12; ++c) { float d = r[c] - mean; vsum += d*d; }
  #pragma unroll
  for (int off = 1; off < 64; off <<= 1) vsum += __shfl_xor(vsum, off, 64);
  float inv = 1.0f / sqrtf(vsum * (1.0f/768.0f) + 1e-5f);
  #pragma unroll
  for (int c = 0; c < 12; ++c) {
    int j = lane + 64*c;
    out[(size_t)row*768 + j] = gamma[j]*(r[c] - mean)*inv + beta[j];
  }
}

extern "C" void kernel_launch(void* const* d_in, const int* in_sizes, int n_in,
                              void* d_out, int out_size, void* d_ws, size_t ws_size,
                              hipStream_t stream) {
  const int*   ids     = (const int*)  d_in[0];
  const float* centers = (const float*)d_in[1];
  const float* allemb  = (const float*)d_in[2];
  const float* pre     = (const float*)d_in[3];
  const float* back    = (const float*)d_in[4];
  const float* click   = (const float*)d_in[5];
  const float* Wq = (const float*)d_in[7];
  const float* bq = (const float*)d_in[8];
  const float* Wk = (const float*)d_in[9];
  const float* bk = (const float*)d_in[10];
  const float* Wv = (const float*)d_in[11];
  const float* bv = (const float*)d_in[12];
  const float* Wa = (const float*)d_in[13];
  const float* ba = (const float*)d_in[14];
  const float* pri  = (const float*)d_in[15];
  const float* ratt = (const float*)d_in[16];
  const float* rmsg = (const float*)d_in[17];
  const float* skip = (const float*)d_in[18];
  const float* gam  = (const float*)d_in[19];
  const float* bet  = (const float*)d_in[20];
  float* out = (float*)d_out;

  char* wp = (char*)d_ws;
  bf16_t* cen_bf = (bf16_t*)wp;  wp += 6291456;    // 4096*768
  bf16_t* all_bf = (bf16_t*)wp;  wp += 12582912;   // 8192*768
  bf16_t* Wq_bf  = (bf16_t*)wp;  wp += 1179648;    // 768*768 (type-0 slice)
  bf16_t* Wk_bf  = (bf16_t*)wp;  wp += 2359296;    // 1536*768
  bf16_t* Wv_bf  = (bf16_t*)wp;  wp += 2359296;    // 1536*768
  bf16_t* Wa_bf  = (bf16_t*)wp;  wp += 1179648;    // 768*768 (type-0 slice)
  bf16_t* rmT    = (bf16_t*)wp;  wp += 294912;     // 3*12*64*64
  bf16_t* qraw   = (bf16_t*)wp;  wp += 6291456;    // 4096*768
  bf16_t* qeb    = (bf16_t*)wp;  wp += 18874368;   // 4096*2304
  bf16_t* kb     = (bf16_t*)wp;  wp += 12582912;   // 8192*768
  bf16_t* vTb    = (bf16_t*)wp;  wp += 12582912;   // 768*8192
  unsigned long long* msk64 = (unsigned long long*)wp; wp += 196608;  // 4096*6
  bf16_t* neighb = (bf16_t*)wp;  wp += 6291456;    // 4096*768 bf16
  float*  rt     = (float*)wp;   wp += 12582912;   // 4096*768

  f2b6_kernel<<<dim3(2048), 256, 0, stream>>>(centers, cen_bf, allemb, all_bf,
                                              Wq, Wq_bf, Wk, Wk_bf, Wv, Wv_bf, Wa, Wa_bf);
  fold_rm<<<dim3(36), 256, 0, stream>>>(rmsg, rmT);

  proj_mfmaB<768, 0, 0, 0>         <<<dim3(6, 32), 256, 0, stream>>>(cen_bf, Wq_bf, bq, qraw);
  qtrans_kernel                     <<<dim3(36, 32), 256, 0, stream>>>(qraw, ratt, pri, qeb);
  proj_mfmaB<768, 768*768, 768, 32><<<dim3(6, 64), 256, 0, stream>>>(all_bf, Wk_bf, bk, kb);
  projT<768*768, 768>              <<<dim3(6, 64), 256, 0, stream>>>(all_bf, Wv_bf, bv, vTb);

  mask_kernel<<<dim3(64), 256, 0, stream>>>(ids, pre, back, click, msk64);
  attn_fused<<<dim3(12, 64), 256, 0, stream>>>(qeb, kb, vTb, rmT, msk64, neighb);

  proj_mfmaF<<<dim3(6, 32), 256, 0, stream>>>(neighb, Wa_bf, ba, rt);
  ln_kernel<<<dim3(1024), 256, 0, stream>>>(rt, centers, skip, gam, bet, out);
}

// Round 8
// 266.840 us; speedup vs baseline: 2.8709x; 1.0157x over previous
//
#include <hip/hip_runtime.h>
#include <cmath>

#define NEGV -1e10f

typedef __bf16 bf16_t;
typedef bf16_t bf16x8 __attribute__((ext_vector_type(8)));
typedef bf16_t bf16x4 __attribute__((ext_vector_type(4)));
typedef float f32x4 __attribute__((ext_vector_type(4)));

typedef const __attribute__((address_space(1))) void* gas1p;
typedef __attribute__((address_space(3))) void* las3p;

#define MFMA __builtin_amdgcn_mfma_f32_16x16x32_bf16

// ---------- prep: mask closure (blocks 0-63) + rm/ra folds (64-99) + f32->bf16 casts (100+) ----------
__global__ __launch_bounds__(256)
void prep_kernel(const int* __restrict__ ids, const float* __restrict__ pre,
                 const float* __restrict__ back, const float* __restrict__ click,
                 unsigned long long* __restrict__ msk64,
                 const float* __restrict__ rmsg, const float* __restrict__ ratt,
                 const float* __restrict__ pri, bf16_t* __restrict__ rmT, bf16_t* __restrict__ raB,
                 const float* __restrict__ s0, bf16_t* __restrict__ d0,
                 const float* __restrict__ s1, bf16_t* __restrict__ d1,
                 const float* __restrict__ s2, bf16_t* __restrict__ d2,
                 const float* __restrict__ s3, bf16_t* __restrict__ d3,
                 const float* __restrict__ s4, bf16_t* __restrict__ d4,
                 const float* __restrict__ s5, bf16_t* __restrict__ d5) {
  const int bid = blockIdx.x, tid = threadIdx.x;
  __shared__ float pm[64][68], bmm[64][68], cm[64][68];
  __shared__ unsigned long long sbits[64];
  __shared__ unsigned long long colbits[384];
  __shared__ int sid[64];
  __shared__ unsigned char srep[64];
  if (bid < 64) {
    const int b = bid;
    for (int r = 0; r < 4; ++r) {
      int idx = r*256 + tid; int row = idx >> 4; int c4 = (idx & 15) * 4;
      *(float4*)&pm[row][c4]  = *(const float4*)(pre   + (size_t)b*4096 + row*64 + c4);
      *(float4*)&bmm[row][c4] = *(const float4*)(back  + (size_t)b*4096 + row*64 + c4);
      *(float4*)&cm[row][c4]  = *(const float4*)(click + (size_t)b*4096 + row*64 + c4);
    }
    if (tid < 64) sid[tid] = ids[b*64 + tid];
    __syncthreads();
    if (tid < 64) {
      int myid = sid[tid];
      unsigned long long bits = 0ull; int rep = 0;
      for (int l = 0; l < 64; ++l) {
        bool eq = (sid[l] == myid);
        bits |= ((unsigned long long)eq) << l;
        rep |= (eq && (l < tid)) ? 1 : 0;
      }
      sbits[tid] = bits; srep[tid] = (unsigned char)rep;
    }
    for (int j = tid; j < 384; j += 256) {
      int e = j >> 7, t = j & 127;
      unsigned long long cb = 0ull;
      if (e == 0) {
        if (t >= 64) { int tt = t - 64; for (int l = 0; l < 64; ++l) cb |= ((unsigned long long)(cm[l][tt] > 0.0f)) << l; }
      } else if (e == 1) {
        if (t < 64) { for (int l = 0; l < 64; ++l) cb |= ((unsigned long long)(bmm[l][t] > 0.0f)) << l; }
      } else {
        if (t < 64) { for (int l = 0; l < 64; ++l) cb |= ((unsigned long long)(pm[l][t] > 0.0f)) << l; }
      }
      colbits[j] = cb;
    }
    __syncthreads();
    for (int idx = tid; idx < 384; idx += 256) {
      int l = idx / 6, w = idx - l*6;
      unsigned long long r = 0ull;
      if (!srep[l]) {
        unsigned long long sb = sbits[l];
        const int base = w*64;
        for (int jj = 0; jj < 64; ++jj)
          r |= (unsigned long long)((sb & colbits[base + jj]) != 0ull) << jj;
      }
      msk64[((size_t)(b*64) + l)*6 + w] = r;
    }
    return;
  }
  if (bid < 100) {
    const int eh = bid - 64;           // 0..35
    const int e = eh / 12, h = eh - e*12;
    const int re = (e==0) ? 0 : (e==1 ? 4 : 5);
    const float scale = pri[re*12 + h] * 0.125f;
    for (int i = 0; i < 16; ++i) {
      int idx = i*256 + tid;           // 4096
      int d = idx >> 6, f = idx & 63;
      rmT[((size_t)(e*12 + h)*64 + d)*64 + f] =
          (bf16_t)rmsg[((size_t)(re*12 + h)*64 + f)*64 + d];
      raB[((size_t)(e*12 + h)*64 + d)*64 + f] =
          (bf16_t)(ratt[((size_t)(re*12 + h)*64 + d)*64 + f] * scale);
    }
    return;
  }
  // casts (in float4 units)
  const int N0=786432, N1=1572864, N2=147456, N3=294912, N4=294912, N5=147456;
  const int T = N0+N1+N2+N3+N4+N5;
  int i = (bid - 100) * 256 + tid;
  const int stride = (gridDim.x - 100) * 256;
  for (; i < T; i += stride) {
    const float* s; bf16_t* d; int j = i;
    if (j < N0) { s = s0; d = d0; }
    else { j -= N0; if (j < N1) { s = s1; d = d1; }
    else { j -= N1; if (j < N2) { s = s2; d = d2; }
    else { j -= N2; if (j < N3) { s = s3; d = d3; }
    else { j -= N3; if (j < N4) { s = s4; d = d4; }
    else { j -= N4; s = s5; d = d5; } } } } }
    float4 v = *(const float4*)(s + (size_t)j * 4);
    bf16x4 o = { (bf16_t)v.x, (bf16_t)v.y, (bf16_t)v.z, (bf16_t)v.w };
    *(bf16x4*)(d + (size_t)j * 4) = o;
  }
}

// ---------- MFMA GEMM, bf16 out: Y[M,768] = X[M,768] @ W[768]^T + bias (type-0 slice) ----------
__global__ __launch_bounds__(256)
void proj_mfmaB(const bf16_t* __restrict__ X, const bf16_t* __restrict__ W,
                const float* __restrict__ bias, bf16_t* __restrict__ Y) {
  __shared__ bf16_t As[128 * 32];
  __shared__ bf16_t Bs[128 * 32];
  const int bn = blockIdx.x, bm = blockIdx.y;
  const int row0 = bm * 128, col0 = bn * 128;
  const int tid = threadIdx.x, wave = tid >> 6, lane = tid & 63;
  const int wr = wave >> 1, wc = wave & 1;
  f32x4 acc[4][4] = {};
  const int arow = wr * 64 + (lane & 15);
  const int bcol = wc * 64 + (lane & 15);
  const int koff = (lane >> 4) * 8;
  for (int k0 = 0; k0 < 768; k0 += 32) {
    __syncthreads();
    #pragma unroll
    for (int i = 0; i < 2; ++i) {
      int c = i * 256 + tid; int r = c >> 2; int c8 = (c & 3) * 8;
      __builtin_amdgcn_global_load_lds((gas1p)(X + (size_t)(row0 + r) * 768 + k0 + c8),
                                       (las3p)(As + c * 8), 16, 0, 0);
      __builtin_amdgcn_global_load_lds((gas1p)(W + (size_t)(col0 + r) * 768 + k0 + c8),
                                       (las3p)(Bs + c * 8), 16, 0, 0);
    }
    __syncthreads();
    bf16x8 af[4], bfr[4];
    #pragma unroll
    for (int m = 0; m < 4; ++m) af[m]  = *(const bf16x8*)(As + (arow + m * 16) * 32 + koff);
    #pragma unroll
    for (int n = 0; n < 4; ++n) bfr[n] = *(const bf16x8*)(Bs + (bcol + n * 16) * 32 + koff);
    #pragma unroll
    for (int m = 0; m < 4; ++m)
      #pragma unroll
      for (int n = 0; n < 4; ++n)
        acc[m][n] = MFMA(af[m], bfr[n], acc[m][n], 0, 0, 0);
  }
  const int ocol0 = col0 + wc * 64 + (lane & 15);
  const int orow0 = row0 + wr * 64 + (lane >> 4) * 4;
  #pragma unroll
  for (int n = 0; n < 4; ++n) {
    const int col = ocol0 + n * 16;
    const float bvl = bias[col];
    #pragma unroll
    for (int m = 0; m < 4; ++m)
      #pragma unroll
      for (int r = 0; r < 4; ++r)
        Y[(size_t)(orow0 + m * 16 + r) * 768 + col] = (bf16_t)(acc[m][n][r] + bvl);
  }
}

// ---------- MFMA GEMM, fp32 out (retype) ----------
__global__ __launch_bounds__(256)
void proj_mfmaF(const bf16_t* __restrict__ X, const bf16_t* __restrict__ W,
                const float* __restrict__ bias, float* __restrict__ Y) {
  __shared__ bf16_t As[128 * 32];
  __shared__ bf16_t Bs[128 * 32];
  const int bn = blockIdx.x, bm = blockIdx.y;
  const int row0 = bm * 128, col0 = bn * 128;
  const int tid = threadIdx.x, wave = tid >> 6, lane = tid & 63;
  const int wr = wave >> 1, wc = wave & 1;
  f32x4 acc[4][4] = {};
  const int arow = wr * 64 + (lane & 15);
  const int bcol = wc * 64 + (lane & 15);
  const int koff = (lane >> 4) * 8;
  for (int k0 = 0; k0 < 768; k0 += 32) {
    __syncthreads();
    #pragma unroll
    for (int i = 0; i < 2; ++i) {
      int c = i * 256 + tid; int r = c >> 2; int c8 = (c & 3) * 8;
      __builtin_amdgcn_global_load_lds((gas1p)(X + (size_t)(row0 + r) * 768 + k0 + c8),
                                       (las3p)(As + c * 8), 16, 0, 0);
      __builtin_amdgcn_global_load_lds((gas1p)(W + (size_t)(col0 + r) * 768 + k0 + c8),
                                       (las3p)(Bs + c * 8), 16, 0, 0);
    }
    __syncthreads();
    bf16x8 af[4], bfr[4];
    #pragma unroll
    for (int m = 0; m < 4; ++m) af[m]  = *(const bf16x8*)(As + (arow + m * 16) * 32 + koff);
    #pragma unroll
    for (int n = 0; n < 4; ++n) bfr[n] = *(const bf16x8*)(Bs + (bcol + n * 16) * 32 + koff);
    #pragma unroll
    for (int m = 0; m < 4; ++m)
      #pragma unroll
      for (int n = 0; n < 4; ++n)
        acc[m][n] = MFMA(af[m], bfr[n], acc[m][n], 0, 0, 0);
  }
  const int ocol0 = col0 + wc * 64 + (lane & 15);
  const int orow0 = row0 + wr * 64 + (lane >> 4) * 4;
  #pragma unroll
  for (int n = 0; n < 4; ++n) {
    const int col = ocol0 + n * 16;
    const float bvl = bias[col];
    #pragma unroll
    for (int m = 0; m < 4; ++m)
      #pragma unroll
      for (int r = 0; r < 4; ++r)
        Y[(size_t)(orow0 + m * 16 + r) * 768 + col] = acc[m][n][r] + bvl;
  }
}

// ---------- fused K + V^T projection: one A-staging, two B tiles ----------
__global__ __launch_bounds__(256)
void kv_proj(const bf16_t* __restrict__ X, const bf16_t* __restrict__ Wk,
             const bf16_t* __restrict__ Wv, const float* __restrict__ bk,
             const float* __restrict__ bv, bf16_t* __restrict__ K, bf16_t* __restrict__ VT) {
  __shared__ bf16_t As[128 * 32];
  __shared__ bf16_t Bks[128 * 32];
  __shared__ bf16_t Bvs[128 * 32];
  __shared__ char tl[128 * 256];
  const int bn = blockIdx.x, bm = blockIdx.y;
  const int s = (bm >= 32) ? 1 : 0;
  const int row0 = bm * 128, col0 = bn * 128;
  const int tid = threadIdx.x, wave = tid >> 6, lane = tid & 63;
  const int wr = wave >> 1, wc = wave & 1;
  f32x4 acck[4][4] = {};
  f32x4 accv[4][4] = {};
  const int arow = wr * 64 + (lane & 15);
  const int bcol = wc * 64 + (lane & 15);
  const int koff = (lane >> 4) * 8;
  const bf16_t* Wkb = Wk + (size_t)s * 768 * 768;
  const bf16_t* Wvb = Wv + (size_t)s * 768 * 768;
  for (int k0 = 0; k0 < 768; k0 += 32) {
    __syncthreads();
    #pragma unroll
    for (int i = 0; i < 2; ++i) {
      int c = i * 256 + tid; int r = c >> 2; int c8 = (c & 3) * 8;
      __builtin_amdgcn_global_load_lds((gas1p)(X   + (size_t)(row0 + r) * 768 + k0 + c8),
                                       (las3p)(As  + c * 8), 16, 0, 0);
      __builtin_amdgcn_global_load_lds((gas1p)(Wkb + (size_t)(col0 + r) * 768 + k0 + c8),
                                       (las3p)(Bks + c * 8), 16, 0, 0);
      __builtin_amdgcn_global_load_lds((gas1p)(Wvb + (size_t)(col0 + r) * 768 + k0 + c8),
                                       (las3p)(Bvs + c * 8), 16, 0, 0);
    }
    __syncthreads();
    bf16x8 af[4], bk_[4], bv_[4];
    #pragma unroll
    for (int m = 0; m < 4; ++m) af[m]  = *(const bf16x8*)(As  + (arow + m * 16) * 32 + koff);
    #pragma unroll
    for (int n = 0; n < 4; ++n) { bk_[n] = *(const bf16x8*)(Bks + (bcol + n * 16) * 32 + koff);
                                  bv_[n] = *(const bf16x8*)(Bvs + (bcol + n * 16) * 32 + koff); }
    #pragma unroll
    for (int m = 0; m < 4; ++m)
      #pragma unroll
      for (int n = 0; n < 4; ++n) {
        acck[m][n] = MFMA(af[m], bk_[n], acck[m][n], 0, 0, 0);
        accv[m][n] = MFMA(af[m], bv_[n], accv[m][n], 0, 0, 0);
      }
  }
  // K epilogue (row-major)
  const int ocol0 = col0 + wc * 64 + (lane & 15);
  const int orow0 = row0 + wr * 64 + (lane >> 4) * 4;
  #pragma unroll
  for (int n = 0; n < 4; ++n) {
    const int col = ocol0 + n * 16;
    const float bvl = bk[s * 768 + col];
    #pragma unroll
    for (int m = 0; m < 4; ++m)
      #pragma unroll
      for (int r = 0; r < 4; ++r)
        K[(size_t)(orow0 + m * 16 + r) * 768 + col] = (bf16_t)(acck[m][n][r] + bvl);
  }
  // V^T epilogue via LDS transpose
  #pragma unroll
  for (int n = 0; n < 4; ++n) {
    const int cl = wc * 64 + n * 16 + (lane & 15);
    const float bvl = bv[s * 768 + col0 + cl];
    #pragma unroll
    for (int m = 0; m < 4; ++m)
      #pragma unroll
      for (int r = 0; r < 4; ++r) {
        const int rl = wr * 64 + m * 16 + (lane >> 4) * 4 + r;
        *(bf16_t*)(tl + ((cl * 256 + rl * 2) ^ ((cl & 7) << 4))) = (bf16_t)(accv[m][n][r] + bvl);
      }
  }
  __syncthreads();
  for (int i = 0; i < 8; ++i) {
    int idx = i * 256 + tid; int c = idx >> 4; int t0 = (idx & 15) * 8;
    bf16x8 v = *(const bf16x8*)(tl + ((c * 256 + t0 * 2) ^ ((c & 7) << 4)));
    *(bf16x8*)(VT + (size_t)(col0 + c) * 8192 + row0 + t0) = v;
  }
}

// ---------- fused qe-transform + QK^T + masked softmax + PV + rm + gelu ----------
__global__ __launch_bounds__(256, 2)
void attn_fused2(const bf16_t* __restrict__ qraw, const bf16_t* __restrict__ kb,
                 const bf16_t* __restrict__ vT, const bf16_t* __restrict__ rmT,
                 const bf16_t* __restrict__ raB,
                 const unsigned long long* __restrict__ msk64,
                 bf16_t* __restrict__ neigh) {
  const int h = blockIdx.x, b = blockIdx.y;
  __shared__ char lds[81920];
  char* const QLS  = lds;             // A: q[64][64]      [0,8K)
  char* const RALS = lds + 8192;      // A: ra 3x[64][64]  [8K,32K)
  char* const QELS = lds + 32768;     // A: qe 3x[64][64]  [32K,56K)
  char* const VLS  = lds;             // B: V^T[64][128]   [0,16K)
  char* const PLS  = lds + 16384;     // B: P[64][128]     [16K,32K)
  char* const KLS  = lds + 32768;     // B: K[128][64]     [32K,48K)
  char* const RMLS = lds + 49152;     // B: rm 3x[64][64]  [48K,72K)
  char* const USS  = lds + 73728;     // B: U[64][64]      [72K,80K)
  const int tid = threadIdx.x, wave = tid >> 6, lane = tid & 63;
  const int band = wave * 16, colb = lane & 15;

  // T14: issue all global loads to registers up front
  bf16x8 qreg[2], rareg[6], kreg[4], vreg[4], rmreg[6];
  #pragma unroll
  for (int i = 0; i < 2; ++i) { int idx = i*256 + tid; int l = idx >> 3, f0 = (idx & 7) * 8;
    qreg[i] = *(const bf16x8*)(qraw + (size_t)(b*64 + l)*768 + h*64 + f0); }
  #pragma unroll
  for (int i = 0; i < 6; ++i) { int idx = i*256 + tid; int e = idx >> 9, rem = idx & 511, d = rem >> 3, f0 = (rem & 7) * 8;
    rareg[i] = *(const bf16x8*)(raB + (size_t)((e*12 + h)*64 + d)*64 + f0); }
  #pragma unroll
  for (int i = 0; i < 4; ++i) { int idx = i*256 + tid; int t = idx >> 3, c8 = (idx & 7) * 8;
    int srow = (t >> 6)*4096 + b*64 + (t & 63);
    kreg[i] = *(const bf16x8*)(kb + (size_t)srow*768 + h*64 + c8); }
  #pragma unroll
  for (int i = 0; i < 4; ++i) { int idx = i*256 + tid; int f = idx >> 4, t0 = (idx & 15) * 8;
    vreg[i] = *(const bf16x8*)(vT + (size_t)(h*64 + f)*8192 + (t0 >> 6)*4096 + b*64 + (t0 & 63)); }
  #pragma unroll
  for (int i = 0; i < 6; ++i) { int idx = i*256 + tid; int e = idx >> 9, rem = idx & 511, d = rem >> 3, f0 = (rem & 7) * 8;
    rmreg[i] = *(const bf16x8*)(rmT + (size_t)((e*12 + h)*64 + d)*64 + f0); }

  // Phase A: q and ra tiles
  #pragma unroll
  for (int i = 0; i < 2; ++i) { int idx = i*256 + tid; int l = idx >> 3, f0 = (idx & 7) * 8;
    *(bf16x8*)(QLS + ((l*128 + f0*2) ^ ((l & 7) << 4))) = qreg[i]; }
  #pragma unroll
  for (int i = 0; i < 6; ++i) { int idx = i*256 + tid; int e = idx >> 9, rem = idx & 511, d = rem >> 3, f0 = (rem & 7) * 8;
    *(bf16x8*)(RALS + e*8192 + ((d*128 + f0*2) ^ ((d & 7) << 4))) = rareg[i]; }
  __syncthreads();                                   // B0
  // qe = q @ ra^T   (pri/sqrt_dk prescaled into raB)
  f32x4 accq[3][4] = {};
  #pragma unroll
  for (int ks = 0; ks < 2; ++ks) {
    const int kb2 = (ks*32 + (lane >> 4)*8) * 2;
    const int la = band + colb;
    bf16x8 a = *(const bf16x8*)(QLS + ((la*128 + kb2) ^ ((la & 7) << 4)));
    #pragma unroll
    for (int e = 0; e < 3; ++e)
      #pragma unroll
      for (int n = 0; n < 4; ++n) {
        int d = n*16 + colb;
        bf16x8 bf = *(const bf16x8*)(RALS + e*8192 + ((d*128 + kb2) ^ ((d & 7) << 4)));
        accq[e][n] = MFMA(a, bf, accq[e][n], 0, 0, 0);
      }
  }
  #pragma unroll
  for (int e = 0; e < 3; ++e)
    #pragma unroll
    for (int n = 0; n < 4; ++n)
      #pragma unroll
      for (int r = 0; r < 4; ++r) {
        int l = band + (lane >> 4)*4 + r, d = n*16 + colb;
        *(bf16_t*)(QELS + e*8192 + ((l*128 + d*2) ^ ((l & 7) << 4))) = (bf16_t)accq[e][n][r];
      }
  __syncthreads();                                   // B1
  bf16x8 af[3][2];
  #pragma unroll
  for (int e = 0; e < 3; ++e)
    #pragma unroll
    for (int ks = 0; ks < 2; ++ks) {
      int la = band + colb, kd2 = (ks*32 + (lane >> 4)*8) * 2;
      af[e][ks] = *(const bf16x8*)(QELS + e*8192 + ((la*128 + kd2) ^ ((la & 7) << 4)));
    }
  __syncthreads();                                   // B2: af reads done before overwrite
  // Phase B stages (from held regs)
  #pragma unroll
  for (int i = 0; i < 4; ++i) { int idx = i*256 + tid; int t = idx >> 3, c8 = (idx & 7) * 8;
    *(bf16x8*)(KLS + ((t*128 + c8*2) ^ ((t & 7) << 4))) = kreg[i]; }
  #pragma unroll
  for (int i = 0; i < 4; ++i) { int idx = i*256 + tid; int f = idx >> 4, t0 = (idx & 15) * 8;
    *(bf16x8*)(VLS + ((f*256 + t0*2) ^ ((f & 7) << 4))) = vreg[i]; }
  #pragma unroll
  for (int i = 0; i < 6; ++i) { int idx = i*256 + tid; int e = idx >> 9, rem = idx & 511, d = rem >> 3, f0 = (rem & 7) * 8;
    *(bf16x8*)(RMLS + e*8192 + ((d*128 + f0*2) ^ ((d & 7) << 4))) = rmreg[i]; }
  __syncthreads();                                   // B3
  // QK^T
  f32x4 acc[3][8] = {};
  #pragma unroll
  for (int ks = 0; ks < 2; ++ks) {
    bf16x8 bfr[8];
    #pragma unroll
    for (int n = 0; n < 8; ++n) {
      int t = n*16 + colb;
      bfr[n] = *(const bf16x8*)(KLS + ((t*128 + (ks*32 + (lane >> 4)*8)*2) ^ ((t & 7) << 4)));
    }
    #pragma unroll
    for (int e = 0; e < 3; ++e)
      #pragma unroll
      for (int n = 0; n < 8; ++n)
        acc[e][n] = MFMA(af[e][ks], bfr[n], acc[e][n], 0, 0, 0);
  }
  // mask
  float mx[4], inv[4];
  #pragma unroll
  for (int r = 0; r < 4; ++r) {
    const int l = band + (lane >> 4)*4 + r;
    const unsigned long long* mr = msk64 + (size_t)(b*64 + l)*6;
    #pragma unroll
    for (int e = 0; e < 3; ++e) {
      unsigned long long w0 = mr[e*2], w1 = mr[e*2 + 1];
      #pragma unroll
      for (int n = 0; n < 8; ++n) {
        unsigned long long w = (n < 4) ? w0 : w1;
        int bitpos = (n*16 + colb) & 63;
        if (!((w >> bitpos) & 1ull)) acc[e][n][r] = NEGV;
      }
    }
  }
  // softmax over 16-lane row groups
  #pragma unroll
  for (int r = 0; r < 4; ++r) {
    float m = NEGV;
    #pragma unroll
    for (int e = 0; e < 3; ++e)
      #pragma unroll
      for (int n = 0; n < 8; ++n) m = fmaxf(m, acc[e][n][r]);
    #pragma unroll
    for (int off = 1; off < 16; off <<= 1) m = fmaxf(m, __shfl_xor(m, off, 64));
    mx[r] = m;
  }
  #pragma unroll
  for (int r = 0; r < 4; ++r) {
    float s = 0.0f;
    #pragma unroll
    for (int e = 0; e < 3; ++e)
      #pragma unroll
      for (int n = 0; n < 8; ++n) {
        float v = __expf(acc[e][n][r] - mx[r]);
        acc[e][n][r] = v; s += v;
      }
    #pragma unroll
    for (int off = 1; off < 16; off <<= 1) s += __shfl_xor(s, off, 64);
    inv[r] = (mx[r] < -5e9f) ? 0.0f : 1.0f / s;
  }
  // PV + rm per edge
  f32x4 accN[4] = {};
  #pragma unroll
  for (int e = 0; e < 3; ++e) {
    #pragma unroll
    for (int n = 0; n < 8; ++n)
      #pragma unroll
      for (int r = 0; r < 4; ++r) {
        int l = band + (lane >> 4)*4 + r;
        int t = n*16 + colb;
        *(bf16_t*)(PLS + ((l*256 + t*2) ^ ((l & 7) << 4))) = (bf16_t)(acc[e][n][r] * inv[r]);
      }
    __syncthreads();
    f32x4 accU[4] = {};
    #pragma unroll
    for (int ks = 0; ks < 4; ++ks) {
      const int kb2 = (ks*32 + (lane >> 4)*8) * 2;
      const int la = band + colb;
      bf16x8 a = *(const bf16x8*)(PLS + ((la*256 + kb2) ^ ((la & 7) << 4)));
      #pragma unroll
      for (int n = 0; n < 4; ++n) {
        int f = n*16 + colb;
        bf16x8 bv = *(const bf16x8*)(VLS + ((f*256 + kb2) ^ ((f & 7) << 4)));
        accU[n] = MFMA(a, bv, accU[n], 0, 0, 0);
      }
    }
    #pragma unroll
    for (int n = 0; n < 4; ++n)
      #pragma unroll
      for (int r = 0; r < 4; ++r) {
        int l = band + (lane >> 4)*4 + r;
        int f = n*16 + colb;
        *(bf16_t*)(USS + ((l*128 + f*2) ^ ((l & 7) << 4))) = (bf16_t)accU[n][r];
      }
    __syncthreads();
    #pragma unroll
    for (int ks = 0; ks < 2; ++ks) {
      const int kb2 = (ks*32 + (lane >> 4)*8) * 2;
      const int la = band + colb;
      bf16x8 a2 = *(const bf16x8*)(USS + ((la*128 + kb2) ^ ((la & 7) << 4)));
      #pragma unroll
      for (int n = 0; n < 4; ++n) {
        int d = n*16 + colb;
        bf16x8 brm = *(const bf16x8*)(RMLS + e*8192 + ((d*128 + kb2) ^ ((d & 7) << 4)));
        accN[n] = MFMA(a2, brm, accN[n], 0, 0, 0);
      }
    }
  }
  #pragma unroll
  for (int n = 0; n < 4; ++n)
    #pragma unroll
    for (int r = 0; r < 4; ++r) {
      int l = band + (lane >> 4)*4 + r;
      int d = n*16 + colb;
      float x = accN[n][r];
      float g = 0.5f * x * (1.0f + erff(x * 0.70710678118654752f));
      neigh[(size_t)(b*64 + l)*768 + h*64 + d] = (bf16_t)g;
    }
}

// ---------- skip-mix + LayerNorm, one wave per row ----------
__global__ __launch_bounds__(256)
void ln_kernel(const float* __restrict__ rt, const float* __restrict__ centers,
               const float* __restrict__ skip, const float* __restrict__ gamma,
               const float* __restrict__ beta, float* __restrict__ out) {
  const int row  = blockIdx.x*4 + (threadIdx.x >> 6);
  const int lane = threadIdx.x & 63;
  const float alpha = 1.0f / (1.0f + expf(-skip[0]));
  const float* rp = rt + (size_t)row*768;
  const float* cp = centers + (size_t)row*768;
  float r[12];
  float sum = 0.0f;
  #pragma unroll
  for (int c = 0; c < 12; ++c) {
    int j = lane + 64*c;
    float x = alpha*rp[j] + (1.0f - alpha)*cp[j];
    r[c] = x; sum += x;
  }
  #pragma unroll
  for (int off = 1; off < 64; off <<= 1) sum += __shfl_xor(sum, off, 64);
  float mean = sum * (1.0f/768.0f);
  float vsum = 0.0f;
  #pragma unroll
  for (int c = 0; c < 12; ++c) { float d = r[c] - mean; vsum += d*d; }
  #pragma unroll
  for (int off = 1; off < 64; off <<= 1) vsum += __shfl_xor(vsum, off, 64);
  float inv = 1.0f / sqrtf(vsum * (1.0f/768.0f) + 1e-5f);
  #pragma unroll
  for (int c = 0; c < 12; ++c) {
    int j = lane + 64*c;
    out[(size_t)row*768 + j] = gamma[j]*(r[c] - mean)*inv + beta[j];
  }
}

extern "C" void kernel_launch(void* const* d_in, const int* in_sizes, int n_in,
                              void* d_out, int out_size, void* d_ws, size_t ws_size,
                              hipStream_t stream) {
  const int*   ids     = (const int*)  d_in[0];
  const float* centers = (const float*)d_in[1];
  const float* allemb  = (const float*)d_in[2];
  const float* pre     = (const float*)d_in[3];
  const float* back    = (const float*)d_in[4];
  const float* click   = (const float*)d_in[5];
  const float* Wq = (const float*)d_in[7];
  const float* bq = (const float*)d_in[8];
  const float* Wk = (const float*)d_in[9];
  const float* bk = (const float*)d_in[10];
  const float* Wv = (const float*)d_in[11];
  const float* bv = (const float*)d_in[12];
  const float* Wa = (const float*)d_in[13];
  const float* ba = (const float*)d_in[14];
  const float* pri  = (const float*)d_in[15];
  const float* ratt = (const float*)d_in[16];
  const float* rmsg = (const float*)d_in[17];
  const float* skip = (const float*)d_in[18];
  const float* gam  = (const float*)d_in[19];
  const float* bet  = (const float*)d_in[20];
  float* out = (float*)d_out;

  char* wp = (char*)d_ws;
  bf16_t* cen_bf = (bf16_t*)wp;  wp += 6291456;    // 4096*768
  bf16_t* all_bf = (bf16_t*)wp;  wp += 12582912;   // 8192*768
  bf16_t* Wq_bf  = (bf16_t*)wp;  wp += 1179648;    // 768*768 (type-0 slice)
  bf16_t* Wk_bf  = (bf16_t*)wp;  wp += 2359296;    // 1536*768
  bf16_t* Wv_bf  = (bf16_t*)wp;  wp += 2359296;    // 1536*768
  bf16_t* Wa_bf  = (bf16_t*)wp;  wp += 1179648;    // 768*768 (type-0 slice)
  bf16_t* rmT    = (bf16_t*)wp;  wp += 294912;     // 3*12*64*64
  bf16_t* raB    = (bf16_t*)wp;  wp += 294912;     // 3*12*64*64 (pri/8 prescaled)
  bf16_t* qraw   = (bf16_t*)wp;  wp += 6291456;    // 4096*768
  bf16_t* kb     = (bf16_t*)wp;  wp += 12582912;   // 8192*768
  bf16_t* vTb    = (bf16_t*)wp;  wp += 12582912;   // 768*8192
  unsigned long long* msk64 = (unsigned long long*)wp; wp += 196608;  // 4096*6
  bf16_t* neighb = (bf16_t*)wp;  wp += 6291456;    // 4096*768 bf16
  float*  rt     = (float*)wp;   wp += 12582912;   // 4096*768

  prep_kernel<<<dim3(2048), 256, 0, stream>>>(
      ids, pre, back, click, msk64, rmsg, ratt, pri, rmT, raB,
      centers, cen_bf, allemb, all_bf, Wq, Wq_bf, Wk, Wk_bf, Wv, Wv_bf, Wa, Wa_bf);

  proj_mfmaB<<<dim3(6, 32), 256, 0, stream>>>(cen_bf, Wq_bf, bq, qraw);
  kv_proj   <<<dim3(6, 64), 256, 0, stream>>>(all_bf, Wk_bf, Wv_bf, bk, bv, kb, vTb);

  attn_fused2<<<dim3(12, 64), 256, 0, stream>>>(qraw, kb, vTb, rmT, raB, msk64, neighb);

  proj_mfmaF<<<dim3(6, 32), 256, 0, stream>>>(neighb, Wa_bf, ba, rt);
  ln_kernel<<<dim3(1024), 256, 0, stream>>>(rt, centers, skip, gam, bet, out);
}

// Round 10
// 248.874 us; speedup vs baseline: 3.0782x; 1.0722x over previous
//
#include <hip/hip_runtime.h>
#include <cmath>

#define NEGV -1e10f

typedef __bf16 bf16_t;
typedef bf16_t bf16x8 __attribute__((ext_vector_type(8)));
typedef bf16_t bf16x4 __attribute__((ext_vector_type(4)));
typedef float f32x4 __attribute__((ext_vector_type(4)));

typedef const __attribute__((address_space(1))) void* gas1p;
typedef __attribute__((address_space(3))) void* las3p;

#define MFMA __builtin_amdgcn_mfma_f32_16x16x32_bf16

// ---------- prep: mask closure (blocks 0-63) + rm/ra folds (64-99) + f32->bf16 casts (100+) ----------
__global__ __launch_bounds__(256)
void prep_kernel(const int* __restrict__ ids, const float* __restrict__ pre,
                 const float* __restrict__ back, const float* __restrict__ click,
                 unsigned long long* __restrict__ msk64,
                 const float* __restrict__ rmsg, const float* __restrict__ ratt,
                 const float* __restrict__ pri, bf16_t* __restrict__ rmT, bf16_t* __restrict__ raB,
                 const float* __restrict__ s0, bf16_t* __restrict__ d0,
                 const float* __restrict__ s1, bf16_t* __restrict__ d1,
                 const float* __restrict__ s2, bf16_t* __restrict__ d2,
                 const float* __restrict__ s3, bf16_t* __restrict__ d3,
                 const float* __restrict__ s4, bf16_t* __restrict__ d4,
                 const float* __restrict__ s5, bf16_t* __restrict__ d5) {
  const int bid = blockIdx.x, tid = threadIdx.x;
  __shared__ float pm[64][68], bmm[64][68], cm[64][68];
  __shared__ unsigned long long sbits[64];
  __shared__ unsigned long long colbits[384];
  __shared__ int sid[64];
  __shared__ unsigned char srep[64];
  if (bid < 64) {
    const int b = bid;
    for (int r = 0; r < 4; ++r) {
      int idx = r*256 + tid; int row = idx >> 4; int c4 = (idx & 15) * 4;
      *(float4*)&pm[row][c4]  = *(const float4*)(pre   + (size_t)b*4096 + row*64 + c4);
      *(float4*)&bmm[row][c4] = *(const float4*)(back  + (size_t)b*4096 + row*64 + c4);
      *(float4*)&cm[row][c4]  = *(const float4*)(click + (size_t)b*4096 + row*64 + c4);
    }
    if (tid < 64) sid[tid] = ids[b*64 + tid];
    __syncthreads();
    if (tid < 64) {
      int myid = sid[tid];
      unsigned long long bits = 0ull; int rep = 0;
      for (int l = 0; l < 64; ++l) {
        bool eq = (sid[l] == myid);
        bits |= ((unsigned long long)eq) << l;
        rep |= (eq && (l < tid)) ? 1 : 0;
      }
      sbits[tid] = bits; srep[tid] = (unsigned char)rep;
    }
    for (int j = tid; j < 384; j += 256) {
      int e = j >> 7, t = j & 127;
      unsigned long long cb = 0ull;
      if (e == 0) {
        if (t >= 64) { int tt = t - 64; for (int l = 0; l < 64; ++l) cb |= ((unsigned long long)(cm[l][tt] > 0.0f)) << l; }
      } else if (e == 1) {
        if (t < 64) { for (int l = 0; l < 64; ++l) cb |= ((unsigned long long)(bmm[l][t] > 0.0f)) << l; }
      } else {
        if (t < 64) { for (int l = 0; l < 64; ++l) cb |= ((unsigned long long)(pm[l][t] > 0.0f)) << l; }
      }
      colbits[j] = cb;
    }
    __syncthreads();
    for (int idx = tid; idx < 384; idx += 256) {
      int l = idx / 6, w = idx - l*6;
      unsigned long long r = 0ull;
      if (!srep[l]) {
        unsigned long long sb = sbits[l];
        const int base = w*64;
        for (int jj = 0; jj < 64; ++jj)
          r |= (unsigned long long)((sb & colbits[base + jj]) != 0ull) << jj;
      }
      msk64[((size_t)(b*64) + l)*6 + w] = r;
    }
    return;
  }
  if (bid < 100) {
    const int eh = bid - 64;           // 0..35
    const int e = eh / 12, h = eh - e*12;
    const int re = (e==0) ? 0 : (e==1 ? 4 : 5);
    const float scale = pri[re*12 + h] * 0.125f;
    for (int i = 0; i < 16; ++i) {
      int idx = i*256 + tid;           // 4096
      int d = idx >> 6, f = idx & 63;
      rmT[((size_t)(e*12 + h)*64 + d)*64 + f] =
          (bf16_t)rmsg[((size_t)(re*12 + h)*64 + f)*64 + d];
      raB[((size_t)(e*12 + h)*64 + d)*64 + f] =
          (bf16_t)(ratt[((size_t)(re*12 + h)*64 + d)*64 + f] * scale);
    }
    return;
  }
  // casts (in float4 units)
  const int N0=786432, N1=1572864, N2=147456, N3=294912, N4=294912, N5=147456;
  const int T = N0+N1+N2+N3+N4+N5;
  int i = (bid - 100) * 256 + tid;
  const int stride = (gridDim.x - 100) * 256;
  for (; i < T; i += stride) {
    const float* s; bf16_t* d; int j = i;
    if (j < N0) { s = s0; d = d0; }
    else { j -= N0; if (j < N1) { s = s1; d = d1; }
    else { j -= N1; if (j < N2) { s = s2; d = d2; }
    else { j -= N2; if (j < N3) { s = s3; d = d3; }
    else { j -= N3; if (j < N4) { s = s4; d = d4; }
    else { j -= N4; s = s5; d = d5; } } } } }
    float4 v = *(const float4*)(s + (size_t)j * 4);
    bf16x4 o = { (bf16_t)v.x, (bf16_t)v.y, (bf16_t)v.z, (bf16_t)v.w };
    *(bf16x4*)(d + (size_t)j * 4) = o;
  }
}

// ---------- unified Q/K/V projection, 2-phase double-buffered staging ----------
// grid (6, 96): by<32 -> q-mode (centers @ Wq -> Q);  by>=32 -> kv-mode (allemb @ Wk,Wv -> K, V^T)
__global__ __launch_bounds__(256)
void qkv_proj(const bf16_t* __restrict__ cen, const bf16_t* __restrict__ allb,
              const bf16_t* __restrict__ Wq, const bf16_t* __restrict__ Wk,
              const bf16_t* __restrict__ Wv,
              const float* __restrict__ bq, const float* __restrict__ bk,
              const float* __restrict__ bv,
              bf16_t* __restrict__ Q, bf16_t* __restrict__ K, bf16_t* __restrict__ VT) {
  __shared__ char lds[49152];          // 2 x 24KB staging; tl [16K,48K) aliased post-loop
  const int bn = blockIdx.x, by = blockIdx.y;
  const bool qmode = (by < 32);
  const int bm = qmode ? by : (by - 32);
  const int s = (!qmode && bm >= 32) ? 1 : 0;
  const int row0 = bm * 128, col0 = bn * 128;
  const bf16_t* X  = qmode ? cen : allb;
  const bf16_t* WA = qmode ? Wq : (Wk + (size_t)s * 768 * 768);
  const bf16_t* WB = Wv + (size_t)s * 768 * 768;
  const int tid = threadIdx.x, wave = tid >> 6, lane = tid & 63;
  const int wr = wave >> 1, wc = wave & 1;
  const int arow = wr * 64 + (lane & 15);
  const int bcol = wc * 64 + (lane & 15);
  const int koff = (lane >> 4) * 8;
  f32x4 acck[4][4] = {};
  f32x4 accv[4][4] = {};

  // prologue stage k0=0 into buf0
  {
    bf16_t* As  = (bf16_t*)(lds);
    bf16_t* Bks = As + 4096;
    bf16_t* Bvs = As + 8192;
    #pragma unroll
    for (int i = 0; i < 2; ++i) {
      int c = i * 256 + tid; int r = c >> 2; int c8 = (c & 3) * 8;
      __builtin_amdgcn_global_load_lds((gas1p)(X  + (size_t)(row0 + r) * 768 + c8),
                                       (las3p)(As + c * 8), 16, 0, 0);
      __builtin_amdgcn_global_load_lds((gas1p)(WA + (size_t)(col0 + r) * 768 + c8),
                                       (las3p)(Bks + c * 8), 16, 0, 0);
      if (!qmode)
        __builtin_amdgcn_global_load_lds((gas1p)(WB + (size_t)(col0 + r) * 768 + c8),
                                         (las3p)(Bvs + c * 8), 16, 0, 0);
    }
  }
  __syncthreads();

  for (int k = 0; k < 24; ++k) {
    // issue next-tile loads (overlap with current MFMA)
    if (k < 23) {
      const int k0 = (k + 1) * 32;
      bf16_t* As  = (bf16_t*)(lds + ((k + 1) & 1) * 24576);
      bf16_t* Bks = As + 4096;
      bf16_t* Bvs = As + 8192;
      #pragma unroll
      for (int i = 0; i < 2; ++i) {
        int c = i * 256 + tid; int r = c >> 2; int c8 = (c & 3) * 8;
        __builtin_amdgcn_global_load_lds((gas1p)(X  + (size_t)(row0 + r) * 768 + k0 + c8),
                                         (las3p)(As + c * 8), 16, 0, 0);
        __builtin_amdgcn_global_load_lds((gas1p)(WA + (size_t)(col0 + r) * 768 + k0 + c8),
                                         (las3p)(Bks + c * 8), 16, 0, 0);
        if (!qmode)
          __builtin_amdgcn_global_load_lds((gas1p)(WB + (size_t)(col0 + r) * 768 + k0 + c8),
                                           (las3p)(Bvs + c * 8), 16, 0, 0);
      }
    }
    // compute current buffer
    {
      bf16_t* As  = (bf16_t*)(lds + (k & 1) * 24576);
      bf16_t* Bks = As + 4096;
      bf16_t* Bvs = As + 8192;
      bf16x8 af[4], bk_[4], bv_[4];
      #pragma unroll
      for (int m = 0; m < 4; ++m) af[m]  = *(const bf16x8*)(As  + (arow + m * 16) * 32 + koff);
      #pragma unroll
      for (int n = 0; n < 4; ++n) bk_[n] = *(const bf16x8*)(Bks + (bcol + n * 16) * 32 + koff);
      if (!qmode) {
        #pragma unroll
        for (int n = 0; n < 4; ++n) bv_[n] = *(const bf16x8*)(Bvs + (bcol + n * 16) * 32 + koff);
      }
      #pragma unroll
      for (int m = 0; m < 4; ++m)
        #pragma unroll
        for (int n = 0; n < 4; ++n)
          acck[m][n] = MFMA(af[m], bk_[n], acck[m][n], 0, 0, 0);
      if (!qmode) {
        #pragma unroll
        for (int m = 0; m < 4; ++m)
          #pragma unroll
          for (int n = 0; n < 4; ++n)
            accv[m][n] = MFMA(af[m], bv_[n], accv[m][n], 0, 0, 0);
      }
    }
    __syncthreads();   // drains next-tile loads (implicit vmcnt(0)) + syncs waves
  }

  // Q/K epilogue (row-major)
  const int ocol0 = col0 + wc * 64 + (lane & 15);
  const int orow0 = row0 + wr * 64 + (lane >> 4) * 4;
  if (qmode) {
    #pragma unroll
    for (int n = 0; n < 4; ++n) {
      const int col = ocol0 + n * 16;
      const float bvl = bq[col];
      #pragma unroll
      for (int m = 0; m < 4; ++m)
        #pragma unroll
        for (int r = 0; r < 4; ++r)
          Q[(size_t)(orow0 + m * 16 + r) * 768 + col] = (bf16_t)(acck[m][n][r] + bvl);
    }
    return;
  }
  #pragma unroll
  for (int n = 0; n < 4; ++n) {
    const int col = ocol0 + n * 16;
    const float bvl = bk[s * 768 + col];
    #pragma unroll
    for (int m = 0; m < 4; ++m)
      #pragma unroll
      for (int r = 0; r < 4; ++r)
        K[(size_t)(orow0 + m * 16 + r) * 768 + col] = (bf16_t)(acck[m][n][r] + bvl);
  }
  // V^T epilogue via aliased LDS transpose
  char* const tl = lds + 16384;
  #pragma unroll
  for (int n = 0; n < 4; ++n) {
    const int cl = wc * 64 + n * 16 + (lane & 15);
    const float bvl = bv[s * 768 + col0 + cl];
    #pragma unroll
    for (int m = 0; m < 4; ++m)
      #pragma unroll
      for (int r = 0; r < 4; ++r) {
        const int rl = wr * 64 + m * 16 + (lane >> 4) * 4 + r;
        *(bf16_t*)(tl + ((cl * 256 + rl * 2) ^ ((cl & 7) << 4))) = (bf16_t)(accv[m][n][r] + bvl);
      }
  }
  __syncthreads();
  for (int i = 0; i < 8; ++i) {
    int idx = i * 256 + tid; int c = idx >> 4; int t0 = (idx & 15) * 8;
    bf16x8 v = *(const bf16x8*)(tl + ((c * 256 + t0 * 2) ^ ((c & 7) << 4)));
    *(bf16x8*)(VT + (size_t)(col0 + c) * 8192 + row0 + t0) = v;
  }
}

// ---------- MFMA GEMM, fp32 out (retype) ----------
__global__ __launch_bounds__(256)
void proj_mfmaF(const bf16_t* __restrict__ X, const bf16_t* __restrict__ W,
                const float* __restrict__ bias, float* __restrict__ Y) {
  __shared__ bf16_t As[128 * 32];
  __shared__ bf16_t Bs[128 * 32];
  const int bn = blockIdx.x, bm = blockIdx.y;
  const int row0 = bm * 128, col0 = bn * 128;
  const int tid = threadIdx.x, wave = tid >> 6, lane = tid & 63;
  const int wr = wave >> 1, wc = wave & 1;
  f32x4 acc[4][4] = {};
  const int arow = wr * 64 + (lane & 15);
  const int bcol = wc * 64 + (lane & 15);
  const int koff = (lane >> 4) * 8;
  for (int k0 = 0; k0 < 768; k0 += 32) {
    __syncthreads();
    #pragma unroll
    for (int i = 0; i < 2; ++i) {
      int c = i * 256 + tid; int r = c >> 2; int c8 = (c & 3) * 8;
      __builtin_amdgcn_global_load_lds((gas1p)(X + (size_t)(row0 + r) * 768 + k0 + c8),
                                       (las3p)(As + c * 8), 16, 0, 0);
      __builtin_amdgcn_global_load_lds((gas1p)(W + (size_t)(col0 + r) * 768 + k0 + c8),
                                       (las3p)(Bs + c * 8), 16, 0, 0);
    }
    __syncthreads();
    bf16x8 af[4], bfr[4];
    #pragma unroll
    for (int m = 0; m < 4; ++m) af[m]  = *(const bf16x8*)(As + (arow + m * 16) * 32 + koff);
    #pragma unroll
    for (int n = 0; n < 4; ++n) bfr[n] = *(const bf16x8*)(Bs + (bcol + n * 16) * 32 + koff);
    #pragma unroll
    for (int m = 0; m < 4; ++m)
      #pragma unroll
      for (int n = 0; n < 4; ++n)
        acc[m][n] = MFMA(af[m], bfr[n], acc[m][n], 0, 0, 0);
  }
  const int ocol0 = col0 + wc * 64 + (lane & 15);
  const int orow0 = row0 + wr * 64 + (lane >> 4) * 4;
  #pragma unroll
  for (int n = 0; n < 4; ++n) {
    const int col = ocol0 + n * 16;
    const float bvl = bias[col];
    #pragma unroll
    for (int m = 0; m < 4; ++m)
      #pragma unroll
      for (int r = 0; r < 4; ++r)
        Y[(size_t)(orow0 + m * 16 + r) * 768 + col] = acc[m][n][r] + bvl;
  }
}

// ---------- fused qe-transform + QK^T + masked softmax + PV + rm + gelu ----------
__global__ __launch_bounds__(256, 2)
void attn_fused2(const bf16_t* __restrict__ qraw, const bf16_t* __restrict__ kb,
                 const bf16_t* __restrict__ vT, const bf16_t* __restrict__ rmT,
                 const bf16_t* __restrict__ raB,
                 const unsigned long long* __restrict__ msk64,
                 bf16_t* __restrict__ neigh) {
  const int h = blockIdx.x, b = blockIdx.y;
  __shared__ char lds[81920];
  char* const QLS  = lds;             // A: q[64][64]      [0,8K)
  char* const RALS = lds + 8192;      // A: ra 3x[64][64]  [8K,32K)
  char* const QELS = lds + 32768;     // A: qe 3x[64][64]  [32K,56K)
  char* const VLS  = lds;             // B: V^T[64][128]   [0,16K)
  char* const PLS  = lds + 16384;     // B: P[64][128]     [16K,32K)
  char* const KLS  = lds + 32768;     // B: K[128][64]     [32K,48K)
  char* const RMLS = lds + 49152;     // B: rm 3x[64][64]  [48K,72K)
  char* const USS  = lds + 73728;     // B: U[64][64]      [72K,80K)
  const int tid = threadIdx.x, wave = tid >> 6, lane = tid & 63;
  const int band = wave * 16, colb = lane & 15;

  bf16x8 qreg[2], rareg[6], kreg[4], vreg[4], rmreg[6];
  #pragma unroll
  for (int i = 0; i < 2; ++i) { int idx = i*256 + tid; int l = idx >> 3, f0 = (idx & 7) * 8;
    qreg[i] = *(const bf16x8*)(qraw + (size_t)(b*64 + l)*768 + h*64 + f0); }
  #pragma unroll
  for (int i = 0; i < 6; ++i) { int idx = i*256 + tid; int e = idx >> 9, rem = idx & 511, d = rem >> 3, f0 = (rem & 7) * 8;
    rareg[i] = *(const bf16x8*)(raB + (size_t)((e*12 + h)*64 + d)*64 + f0); }
  #pragma unroll
  for (int i = 0; i < 4; ++i) { int idx = i*256 + tid; int t = idx >> 3, c8 = (idx & 7) * 8;
    int srow = (t >> 6)*4096 + b*64 + (t & 63);
    kreg[i] = *(const bf16x8*)(kb + (size_t)srow*768 + h*64 + c8); }
  #pragma unroll
  for (int i = 0; i < 4; ++i) { int idx = i*256 + tid; int f = idx >> 4, t0 = (idx & 15) * 8;
    vreg[i] = *(const bf16x8*)(vT + (size_t)(h*64 + f)*8192 + (t0 >> 6)*4096 + b*64 + (t0 & 63)); }
  #pragma unroll
  for (int i = 0; i < 6; ++i) { int idx = i*256 + tid; int e = idx >> 9, rem = idx & 511, d = rem >> 3, f0 = (rem & 7) * 8;
    rmreg[i] = *(const bf16x8*)(rmT + (size_t)((e*12 + h)*64 + d)*64 + f0); }

  #pragma unroll
  for (int i = 0; i < 2; ++i) { int idx = i*256 + tid; int l = idx >> 3, f0 = (idx & 7) * 8;
    *(bf16x8*)(QLS + ((l*128 + f0*2) ^ ((l & 7) << 4))) = qreg[i]; }
  #pragma unroll
  for (int i = 0; i < 6; ++i) { int idx = i*256 + tid; int e = idx >> 9, rem = idx & 511, d = rem >> 3, f0 = (rem & 7) * 8;
    *(bf16x8*)(RALS + e*8192 + ((d*128 + f0*2) ^ ((d & 7) << 4))) = rareg[i]; }
  __syncthreads();                                   // B0
  f32x4 accq[3][4] = {};
  #pragma unroll
  for (int ks = 0; ks < 2; ++ks) {
    const int kb2 = (ks*32 + (lane >> 4)*8) * 2;
    const int la = band + colb;
    bf16x8 a = *(const bf16x8*)(QLS + ((la*128 + kb2) ^ ((la & 7) << 4)));
    #pragma unroll
    for (int e = 0; e < 3; ++e)
      #pragma unroll
      for (int n = 0; n < 4; ++n) {
        int d = n*16 + colb;
        bf16x8 bf = *(const bf16x8*)(RALS + e*8192 + ((d*128 + kb2) ^ ((d & 7) << 4)));
        accq[e][n] = MFMA(a, bf, accq[e][n], 0, 0, 0);
      }
  }
  #pragma unroll
  for (int e = 0; e < 3; ++e)
    #pragma unroll
    for (int n = 0; n < 4; ++n)
      #pragma unroll
      for (int r = 0; r < 4; ++r) {
        int l = band + (lane >> 4)*4 + r, d = n*16 + colb;
        *(bf16_t*)(QELS + e*8192 + ((l*128 + d*2) ^ ((l & 7) << 4))) = (bf16_t)accq[e][n][r];
      }
  __syncthreads();                                   // B1
  bf16x8 af[3][2];
  #pragma unroll
  for (int e = 0; e < 3; ++e)
    #pragma unroll
    for (int ks = 0; ks < 2; ++ks) {
      int la = band + colb, kd2 = (ks*32 + (lane >> 4)*8) * 2;
      af[e][ks] = *(const bf16x8*)(QELS + e*8192 + ((la*128 + kd2) ^ ((la & 7) << 4)));
    }
  __syncthreads();                                   // B2
  #pragma unroll
  for (int i = 0; i < 4; ++i) { int idx = i*256 + tid; int t = idx >> 3, c8 = (idx & 7) * 8;
    *(bf16x8*)(KLS + ((t*128 + c8*2) ^ ((t & 7) << 4))) = kreg[i]; }
  #pragma unroll
  for (int i = 0; i < 4; ++i) { int idx = i*256 + tid; int f = idx >> 4, t0 = (idx & 15) * 8;
    *(bf16x8*)(VLS + ((f*256 + t0*2) ^ ((f & 7) << 4))) = vreg[i]; }
  #pragma unroll
  for (int i = 0; i < 6; ++i) { int idx = i*256 + tid; int e = idx >> 9, rem = idx & 511, d = rem >> 3, f0 = (rem & 7) * 8;
    *(bf16x8*)(RMLS + e*8192 + ((d*128 + f0*2) ^ ((d & 7) << 4))) = rmreg[i]; }
  __syncthreads();                                   // B3
  f32x4 acc[3][8] = {};
  #pragma unroll
  for (int ks = 0; ks < 2; ++ks) {
    bf16x8 bfr[8];
    #pragma unroll
    for (int n = 0; n < 8; ++n) {
      int t = n*16 + colb;
      bfr[n] = *(const bf16x8*)(KLS + ((t*128 + (ks*32 + (lane >> 4)*8)*2) ^ ((t & 7) << 4)));
    }
    #pragma unroll
    for (int e = 0; e < 3; ++e)
      #pragma unroll
      for (int n = 0; n < 8; ++n)
        acc[e][n] = MFMA(af[e][ks], bfr[n], acc[e][n], 0, 0, 0);
  }
  float mx[4], inv[4];
  #pragma unroll
  for (int r = 0; r < 4; ++r) {
    const int l = band + (lane >> 4)*4 + r;
    const unsigned long long* mr = msk64 + (size_t)(b*64 + l)*6;
    #pragma unroll
    for (int e = 0; e < 3; ++e) {
      unsigned long long w0 = mr[e*2], w1 = mr[e*2 + 1];
      #pragma unroll
      for (int n = 0; n < 8; ++n) {
        unsigned long long w = (n < 4) ? w0 : w1;
        int bitpos = (n*16 + colb) & 63;
        if (!((w >> bitpos) & 1ull)) acc[e][n][r] = NEGV;
      }
    }
  }
  #pragma unroll
  for (int r = 0; r < 4; ++r) {
    float m = NEGV;
    #pragma unroll
    for (int e = 0; e < 3; ++e)
      #pragma unroll
      for (int n = 0; n < 8; ++n) m = fmaxf(m, acc[e][n][r]);
    #pragma unroll
    for (int off = 1; off < 16; off <<= 1) m = fmaxf(m, __shfl_xor(m, off, 64));
    mx[r] = m;
  }
  #pragma unroll
  for (int r = 0; r < 4; ++r) {
    float s = 0.0f;
    #pragma unroll
    for (int e = 0; e < 3; ++e)
      #pragma unroll
      for (int n = 0; n < 8; ++n) {
        float v = __expf(acc[e][n][r] - mx[r]);
        acc[e][n][r] = v; s += v;
      }
    #pragma unroll
    for (int off = 1; off < 16; off <<= 1) s += __shfl_xor(s, off, 64);
    inv[r] = (mx[r] < -5e9f) ? 0.0f : 1.0f / s;
  }
  f32x4 accN[4] = {};
  #pragma unroll
  for (int e = 0; e < 3; ++e) {
    #pragma unroll
    for (int n = 0; n < 8; ++n)
      #pragma unroll
      for (int r = 0; r < 4; ++r) {
        int l = band + (lane >> 4)*4 + r;
        int t = n*16 + colb;
        *(bf16_t*)(PLS + ((l*256 + t*2) ^ ((l & 7) << 4))) = (bf16_t)(acc[e][n][r] * inv[r]);
      }
    __syncthreads();
    f32x4 accU[4] = {};
    #pragma unroll
    for (int ks = 0; ks < 4; ++ks) {
      const int kb2 = (ks*32 + (lane >> 4)*8) * 2;
      const int la = band + colb;
      bf16x8 a = *(const bf16x8*)(PLS + ((la*256 + kb2) ^ ((la & 7) << 4)));
      #pragma unroll
      for (int n = 0; n < 4; ++n) {
        int f = n*16 + colb;
        bf16x8 bv = *(const bf16x8*)(VLS + ((f*256 + kb2) ^ ((f & 7) << 4)));
        accU[n] = MFMA(a, bv, accU[n], 0, 0, 0);
      }
    }
    #pragma unroll
    for (int n = 0; n < 4; ++n)
      #pragma unroll
      for (int r = 0; r < 4; ++r) {
        int l = band + (lane >> 4)*4 + r;
        int f = n*16 + colb;
        *(bf16_t*)(USS + ((l*128 + f*2) ^ ((l & 7) << 4))) = (bf16_t)accU[n][r];
      }
    __syncthreads();
    #pragma unroll
    for (int ks = 0; ks < 2; ++ks) {
      const int kb2 = (ks*32 + (lane >> 4)*8) * 2;
      const int la = band + colb;
      bf16x8 a2 = *(const bf16x8*)(USS + ((la*128 + kb2) ^ ((la & 7) << 4)));
      #pragma unroll
      for (int n = 0; n < 4; ++n) {
        int d = n*16 + colb;
        bf16x8 brm = *(const bf16x8*)(RMLS + e*8192 + ((d*128 + kb2) ^ ((d & 7) << 4)));
        accN[n] = MFMA(a2, brm, accN[n], 0, 0, 0);
      }
    }
  }
  #pragma unroll
  for (int n = 0; n < 4; ++n)
    #pragma unroll
    for (int r = 0; r < 4; ++r) {
      int l = band + (lane >> 4)*4 + r;
      int d = n*16 + colb;
      float x = accN[n][r];
      float g = 0.5f * x * (1.0f + erff(x * 0.70710678118654752f));
      neigh[(size_t)(b*64 + l)*768 + h*64 + d] = (bf16_t)g;
    }
}

// ---------- skip-mix + LayerNorm, one wave per row ----------
__global__ __launch_bounds__(256)
void ln_kernel(const float* __restrict__ rt, const float* __restrict__ centers,
               const float* __restrict__ skip, const float* __restrict__ gamma,
               const float* __restrict__ beta, float* __restrict__ out) {
  const int row  = blockIdx.x*4 + (threadIdx.x >> 6);
  const int lane = threadIdx.x & 63;
  const float alpha = 1.0f / (1.0f + expf(-skip[0]));
  const float* rp = rt + (size_t)row*768;
  const float* cp = centers + (size_t)row*768;
  float r[12];
  float sum = 0.0f;
  #pragma unroll
  for (int c = 0; c < 12; ++c) {
    int j = lane + 64*c;
    float x = alpha*rp[j] + (1.0f - alpha)*cp[j];
    r[c] = x; sum += x;
  }
  #pragma unroll
  for (int off = 1; off < 64; off <<= 1) sum += __shfl_xor(sum, off, 64);
  float mean = sum * (1.0f/768.0f);
  float vsum = 0.0f;
  #pragma unroll
  for (int c = 0; c < 12; ++c) { float d = r[c] - mean; vsum += d*d; }
  #pragma unroll
  for (int off = 1; off < 64; off <<= 1) vsum += __shfl_xor(vsum, off, 64);
  float inv = 1.0f / sqrtf(vsum * (1.0f/768.0f) + 1e-5f);
  #pragma unroll
  for (int c = 0; c < 12; ++c) {
    int j = lane + 64*c;
    out[(size_t)row*768 + j] = gamma[j]*(r[c] - mean)*inv + beta[j];
  }
}

extern "C" void kernel_launch(void* const* d_in, const int* in_sizes, int n_in,
                              void* d_out, int out_size, void* d_ws, size_t ws_size,
                              hipStream_t stream) {
  const int*   ids     = (const int*)  d_in[0];
  const float* centers = (const float*)d_in[1];
  const float* allemb  = (const float*)d_in[2];
  const float* pre     = (const float*)d_in[3];
  const float* back    = (const float*)d_in[4];
  const float* click   = (const float*)d_in[5];
  const float* Wq = (const float*)d_in[7];
  const float* bq = (const float*)d_in[8];
  const float* Wk = (const float*)d_in[9];
  const float* bk = (const float*)d_in[10];
  const float* Wv = (const float*)d_in[11];
  const float* bv = (const float*)d_in[12];
  const float* Wa = (const float*)d_in[13];
  const float* ba = (const float*)d_in[14];
  const float* pri  = (const float*)d_in[15];
  const float* ratt = (const float*)d_in[16];
  const float* rmsg = (const float*)d_in[17];
  const float* skip = (const float*)d_in[18];
  const float* gam  = (const float*)d_in[19];
  const float* bet  = (const float*)d_in[20];
  float* out = (float*)d_out;

  char* wp = (char*)d_ws;
  bf16_t* cen_bf = (bf16_t*)wp;  wp += 6291456;    // 4096*768
  bf16_t* all_bf = (bf16_t*)wp;  wp += 12582912;   // 8192*768
  bf16_t* Wq_bf  = (bf16_t*)wp;  wp += 1179648;    // 768*768 (type-0 slice)
  bf16_t* Wk_bf  = (bf16_t*)wp;  wp += 2359296;    // 1536*768
  bf16_t* Wv_bf  = (bf16_t*)wp;  wp += 2359296;    // 1536*768
  bf16_t* Wa_bf  = (bf16_t*)wp;  wp += 1179648;    // 768*768 (type-0 slice)
  bf16_t* rmT    = (bf16_t*)wp;  wp += 294912;     // 3*12*64*64
  bf16_t* raB    = (bf16_t*)wp;  wp += 294912;     // 3*12*64*64 (pri/8 prescaled)
  bf16_t* qraw   = (bf16_t*)wp;  wp += 6291456;    // 4096*768
  bf16_t* kb     = (bf16_t*)wp;  wp += 12582912;   // 8192*768
  bf16_t* vTb    = (bf16_t*)wp;  wp += 12582912;   // 768*8192
  unsigned long long* msk64 = (unsigned long long*)wp; wp += 196608;  // 4096*6
  bf16_t* neighb = (bf16_t*)wp;  wp += 6291456;    // 4096*768 bf16
  float*  rt     = (float*)wp;   wp += 12582912;   // 4096*768

  prep_kernel<<<dim3(2048), 256, 0, stream>>>(
      ids, pre, back, click, msk64, rmsg, ratt, pri, rmT, raB,
      centers, cen_bf, allemb, all_bf, Wq, Wq_bf, Wk, Wk_bf, Wv, Wv_bf, Wa, Wa_bf);

  qkv_proj<<<dim3(6, 96), 256, 0, stream>>>(cen_bf, all_bf, Wq_bf, Wk_bf, Wv_bf,
                                            bq, bk, bv, qraw, kb, vTb);

  attn_fused2<<<dim3(12, 64), 256, 0, stream>>>(qraw, kb, vTb, rmT, raB, msk64, neighb);

  proj_mfmaF<<<dim3(6, 32), 256, 0, stream>>>(neighb, Wa_bf, ba, rt);
  ln_kernel<<<dim3(1024), 256, 0, stream>>>(rt, centers, skip, gam, bet, out);
}